// Round 3
// baseline (7737.414 us; speedup 1.0000x reference)
//
#include <hip/hip_runtime.h>
#include <hip/hip_bf16.h>
#include <cstdint>
#include <cstddef>

typedef short s16x8 __attribute__((ext_vector_type(8)));
typedef float f32x4 __attribute__((ext_vector_type(4)));

__device__ __forceinline__ unsigned short f2bf(float f) {
    unsigned int u = __float_as_uint(f);
    unsigned int r = (u + 0x7FFFu + ((u >> 16) & 1u)) >> 16;
    return (unsigned short)r;
}
__device__ __forceinline__ float bf2f(unsigned short s) {
    return __uint_as_float(((unsigned int)s) << 16);
}
__device__ __forceinline__ void splitbf(float v, unsigned short& hi, unsigned short& lo) {
    hi = f2bf(v);
    lo = f2bf(v - bf2f(hi));
}
__device__ __forceinline__ float swishf(float x) {
    return x / (1.0f + __expf(-x));
}

// ---------------- init: h = emb[atomic[z]] ----------------
__global__ void init_nodes(const int* __restrict__ z, const float* __restrict__ emb,
                           float* __restrict__ hf, unsigned short* __restrict__ hhi,
                           unsigned short* __restrict__ hlo, int N) {
    int tid = blockIdx.x * 256 + threadIdx.x;
    int n = tid >> 7, f = tid & 127;
    int zv = z[n];
    int idx5 = (zv == 1) ? 0 : (zv - 5);
    float v = emb[idx5 * 128 + f];
    hf[tid] = v;
    unsigned short hi, lo;
    splitbf(v, hi, lo);
    hhi[tid] = hi;
    hlo[tid] = lo;
}

// ---------------- norm2 per edge ----------------
__global__ void norm2_kernel(const float* __restrict__ pos, const int* __restrict__ src,
                             const int* __restrict__ dst, float* __restrict__ n2, int E) {
    int e = blockIdx.x * 256 + threadIdx.x;
    int si = src[e], di = dst[e];
    float dx = pos[si * 3 + 0] - pos[di * 3 + 0];
    float dy = pos[si * 3 + 1] - pos[di * 3 + 1];
    float dz = pos[si * 3 + 2] - pos[di * 3 + 2];
    n2[e] = dx * dx + dy * dy + dz * dz;
}

// ---------------- pack W_msg1 + W_msg2 for layer l (hi/lo) ----------------
__global__ void pack_msg1(const float* __restrict__ Wm1l, const float* __restrict__ bm1l,
                          const float* __restrict__ Wm2l,
                          unsigned short* __restrict__ Bp1h, unsigned short* __restrict__ Bp1l,
                          float* __restrict__ bias1088, float* __restrict__ w1cf,
                          unsigned short* __restrict__ W2ph, unsigned short* __restrict__ W2pl) {
    int t = blockIdx.x * 256 + threadIdx.x;
    int i = t & 7;
    int lane = (t >> 3) & 63;
    int rest = t >> 9;
    int cb = rest % 68;
    int ks = rest / 68;
    int k = ks * 32 + ((lane >> 4) << 3) + i;  // 0..127
    int ch = cb * 16 + (lane & 15);            // 0..1087
    float val;
    if (ch < 544) {
        val = (ch < 514) ? Wm1l[k * 514 + ch] : 0.f;
    } else {
        int c = ch - 544;
        val = (c < 514) ? Wm1l[(128 + k) * 514 + c] : 0.f;
    }
    unsigned short hi, lo;
    splitbf(val, hi, lo);
    Bp1h[t] = hi;
    Bp1l[t] = lo;
    if (t < 1088) bias1088[t] = (t < 514) ? bm1l[t] : 0.f;
    if (t < 544) w1cf[t] = (t < 514) ? Wm1l[256 * 514 + t] : 0.f;
    if (t < 8704) {
        int i2 = t & 7, lane2 = (t >> 3) & 63, ks2 = t >> 9;
        int k2 = ks2 * 32 + ((lane2 >> 4) << 3) + i2;
        int c2 = lane2 & 15;
        float v2 = (k2 < 514) ? Wm2l[k2 * 16 + c2] : 0.f;
        unsigned short h2, l2;
        splitbf(v2, h2, l2);
        W2ph[t] = h2;
        W2pl[t] = l2;
    }
}

// ---------------- generic B packer: W[K][Nc] fp32 -> frag layout hi/lo ----------------
__global__ void pack_generic(const float* __restrict__ W, int K, int Nc,
                             unsigned short* __restrict__ Bph, unsigned short* __restrict__ Bpl) {
    int t = blockIdx.x * 256 + threadIdx.x;
    int i = t & 7;
    int lane = (t >> 3) & 63;
    int rest = t >> 9;
    int CB = Nc >> 4;
    int cb = rest % CB;
    int ks = rest / CB;
    int k = ks * 32 + ((lane >> 4) << 3) + i;
    int c = cb * 16 + (lane & 15);
    float val = (k < K) ? W[(size_t)k * Nc + c] : 0.f;
    unsigned short hi, lo;
    splitbf(val, hi, lo);
    Bph[t] = hi;
    Bpl[t] = lo;
}

// ---------------- pack x = [agg(16) | h(128) | 0(16)] hi/lo ----------------
__global__ void pack_x(const float* __restrict__ agg, const float* __restrict__ hf,
                       unsigned short* __restrict__ xhi, unsigned short* __restrict__ xlo, int N) {
    int t = blockIdx.x * 256 + threadIdx.x;
    int n = t / 160, c = t % 160;
    float val;
    if (c < 16) val = agg[n * 16 + c];
    else if (c < 144) val = hf[n * 128 + (c - 16)];
    else val = 0.f;
    unsigned short hi, lo;
    splitbf(val, hi, lo);
    xhi[t] = hi;
    xlo[t] = lo;
}

// ---------------- generic 16x16x32 MFMA GEMM, split precision ----------------
// acc = Ahi@Bhi + Alo@Bhi + Ahi@Blo
// mode 0: outB = bf16(acc+bias)
// mode 1: swish(acc+bias) -> outB (hi), outB2 (lo)
// mode 2: h = acc+bias+resid; outF=h (f32), outB/outB2 = hi/lo
// mode 3: atomicAdd(pooled[batch[row]*128+col], acc+bias)
__global__ __launch_bounds__(256) void gemm16(
    const unsigned short* __restrict__ Ahi, const unsigned short* __restrict__ Alo, int lda,
    const unsigned short* __restrict__ Bph, const unsigned short* __restrict__ Bpl,
    const float* __restrict__ bias,
    int ksteps, int CB, int mode,
    unsigned short* __restrict__ outB, unsigned short* __restrict__ outB2, int ldoB,
    float* __restrict__ outF, int ldoF, const float* __restrict__ resid,
    const int* __restrict__ batch, float* __restrict__ pooled) {
    int lane = threadIdx.x & 63;
    int w = threadIdx.x >> 6;
    int row0 = blockIdx.x * 16;
    int cb = blockIdx.y * 4 + w;
    int col0 = cb * 16;
    const size_t arow = (size_t)(row0 + (lane & 15)) * lda;
    const int ak = (lane >> 4) * 8;
    f32x4 acc = {0.f, 0.f, 0.f, 0.f};
    for (int ks = 0; ks < ksteps; ++ks) {
        s16x8 ah = *(const s16x8*)(Ahi + arow + ks * 32 + ak);
        s16x8 al = *(const s16x8*)(Alo + arow + ks * 32 + ak);
        size_t bidx = ((size_t)(ks * CB + cb) * 64 + lane) * 8;
        s16x8 bh = *(const s16x8*)(Bph + bidx);
        s16x8 bl = *(const s16x8*)(Bpl + bidx);
        acc = __builtin_amdgcn_mfma_f32_16x16x32_bf16(ah, bh, acc, 0, 0, 0);
        acc = __builtin_amdgcn_mfma_f32_16x16x32_bf16(al, bh, acc, 0, 0, 0);
        acc = __builtin_amdgcn_mfma_f32_16x16x32_bf16(ah, bl, acc, 0, 0, 0);
    }
    int col = col0 + (lane & 15);
    float bv = bias[col];
    int rb = (lane >> 4) * 4;
#pragma unroll
    for (int i = 0; i < 4; ++i) {
        int row = row0 + rb + i;
        float v = acc[i] + bv;
        if (mode == 0) {
            outB[(size_t)row * ldoB + col] = f2bf(v);
        } else if (mode == 1) {
            float s = swishf(v);
            unsigned short hi, lo;
            splitbf(s, hi, lo);
            outB[(size_t)row * ldoB + col] = hi;
            outB2[(size_t)row * ldoB + col] = lo;
        } else if (mode == 2) {
            float h = v + resid[(size_t)row * ldoF + col];
            outF[(size_t)row * ldoF + col] = h;
            unsigned short hi, lo;
            splitbf(h, hi, lo);
            outB[(size_t)row * ldoB + col] = hi;
            outB2[(size_t)row * ldoB + col] = lo;
        } else {
            unsafeAtomicAdd(&pooled[(size_t)batch[row] * 128 + col], v);
        }
    }
}

// ---------------- edge kernel ----------------
__global__ __launch_bounds__(128) void edge_kernel(
    const unsigned short* __restrict__ TAB, const float* __restrict__ w1cf,
    const unsigned short* __restrict__ W2ph, const unsigned short* __restrict__ W2pl,
    const float* __restrict__ bm2l,
    const int* __restrict__ src, const int* __restrict__ dst,
    const float* __restrict__ norm2, float* __restrict__ agg) {
    __shared__ unsigned short s_tile[32][560];
    int lane = threadIdx.x & 63;
    int wid = threadIdx.x >> 6;
    int ebase = blockIdx.x * 32 + wid * 16;

    for (int i = 0; i < 16; ++i) {
        int e = ebase + i;
        int di = dst[e], si = src[e];
        float n2 = norm2[e];
        const unsigned short* ha = TAB + (size_t)di * 1088;
        const unsigned short* hbp = TAB + (size_t)si * 1088 + 544;
        for (int c = lane; c < 68; c += 64) {
            s16x8 va = *(const s16x8*)(ha + c * 8);
            s16x8 vb = *(const s16x8*)(hbp + c * 8);
            f32x4 c0 = *(const f32x4*)(w1cf + c * 8);
            f32x4 c1 = *(const f32x4*)(w1cf + c * 8 + 4);
            s16x8 o;
#pragma unroll
            for (int j = 0; j < 8; ++j) {
                float wc = (j < 4) ? c0[j] : c1[j - 4];
                float v = bf2f((unsigned short)va[j]) + bf2f((unsigned short)vb[j]) + n2 * wc;
                o[j] = (short)f2bf(swishf(v));
            }
            *(s16x8*)(&s_tile[wid * 16 + i][c * 8]) = o;
        }
    }

    f32x4 acc = {0.f, 0.f, 0.f, 0.f};
    int arow = wid * 16 + (lane & 15);
    int ak = (lane >> 4) * 8;
#pragma unroll
    for (int ks = 0; ks < 17; ++ks) {
        s16x8 a = *(const s16x8*)(&s_tile[arow][ks * 32 + ak]);
        s16x8 bh = *(const s16x8*)(W2ph + (ks * 64 + lane) * 8);
        s16x8 bl = *(const s16x8*)(W2pl + (ks * 64 + lane) * 8);
        acc = __builtin_amdgcn_mfma_f32_16x16x32_bf16(a, bh, acc, 0, 0, 0);
        acc = __builtin_amdgcn_mfma_f32_16x16x32_bf16(a, bl, acc, 0, 0, 0);
    }

    int col = lane & 15;
    float b2 = bm2l[col];
#pragma unroll
    for (int i = 0; i < 4; ++i) {
        int e = ebase + (lane >> 4) * 4 + i;
        float v = swishf(acc[i] + b2);
        unsafeAtomicAdd(&agg[(size_t)dst[e] * 16 + col], v);
    }
}

// ---------------- readout ----------------
__global__ void readout(const float* __restrict__ pooled, const float* __restrict__ Wr1,
                        const float* __restrict__ br1, const float* __restrict__ Wr2,
                        const float* __restrict__ br2, float* __restrict__ out) {
    __shared__ float row[128];
    __shared__ float tt[128];
    int g = blockIdx.x;
    int t = threadIdx.x;
    row[t] = pooled[g * 128 + t];
    __syncthreads();
    float s = br1[t];
    for (int k = 0; k < 128; ++k) s += row[k] * Wr1[k * 128 + t];
    tt[t] = swishf(s);
    __syncthreads();
    if (t < 12) {
        float o = br2[t];
        for (int j = 0; j < 128; ++j) o += tt[j] * Wr2[j * 12 + t];
        out[g * 12 + t] = o;
    }
}

extern "C" void kernel_launch(void* const* d_in, const int* in_sizes, int n_in,
                              void* d_out, int out_size, void* d_ws, size_t ws_size,
                              hipStream_t stream) {
    const float* pos = (const float*)d_in[0];
    const int* z = (const int*)d_in[1];
    const int* ei = (const int*)d_in[2];
    const int* batch = (const int*)d_in[3];
    const float* emb = (const float*)d_in[4];
    const float* Wm1 = (const float*)d_in[5];
    const float* bm1 = (const float*)d_in[6];
    const float* Wm2 = (const float*)d_in[7];
    const float* bm2 = (const float*)d_in[8];
    const float* Wu1 = (const float*)d_in[9];
    const float* bu1 = (const float*)d_in[10];
    const float* Wu2 = (const float*)d_in[11];
    const float* bu2 = (const float*)d_in[12];
    const float* Wp1 = (const float*)d_in[13];
    const float* bp1v = (const float*)d_in[14];
    const float* Wp2 = (const float*)d_in[15];
    const float* bp2v = (const float*)d_in[16];
    const float* Wr1 = (const float*)d_in[17];
    const float* br1 = (const float*)d_in[18];
    const float* Wr2 = (const float*)d_in[19];
    const float* br2 = (const float*)d_in[20];

    const int N = in_sizes[0] / 3;   // 50000
    const int E = in_sizes[2] / 2;   // 800000
    const int G = out_size / 12;     // 1000
    const int* src = ei;
    const int* dstp = ei + E;

    char* ws = (char*)d_ws;
    size_t off = 0;
    auto alloc = [&](size_t bytes) -> char* {
        char* p = ws + off;
        off += (bytes + 255) & ~(size_t)255;
        return p;
    };
    // TAB region: 108.8 MB; mid-layer temporaries x, u (and post-loop t1) alias into it,
    // since TAB is dead between edge_kernel and the next layer's table-GEMM.
    unsigned short* TAB = (unsigned short*)alloc((size_t)N * 1088 * 2);
    float* hf = (float*)alloc((size_t)N * 128 * 4);
    unsigned short* hhi = (unsigned short*)alloc((size_t)N * 128 * 2);
    unsigned short* hlo = (unsigned short*)alloc((size_t)N * 128 * 2);
    float* n2 = (float*)alloc((size_t)E * 4);
    float* agg = (float*)alloc((size_t)N * 16 * 4);
    float* pooled = (float*)alloc((size_t)G * 128 * 4);
    unsigned short* Bp1h = (unsigned short*)alloc(139264 * 2);
    unsigned short* Bp1l = (unsigned short*)alloc(139264 * 2);
    float* bias1088 = (float*)alloc(1088 * 4);
    float* w1cf = (float*)alloc(544 * 4);
    unsigned short* W2ph = (unsigned short*)alloc(8704 * 2);
    unsigned short* W2pl = (unsigned short*)alloc(8704 * 2);
    unsigned short* BpU1h = (unsigned short*)alloc(40960 * 2);
    unsigned short* BpU1l = (unsigned short*)alloc(40960 * 2);
    unsigned short* BpU2h = (unsigned short*)alloc(32768 * 2);
    unsigned short* BpU2l = (unsigned short*)alloc(32768 * 2);
    unsigned short* BpP1h = (unsigned short*)alloc(16384 * 2);
    unsigned short* BpP1l = (unsigned short*)alloc(16384 * 2);
    unsigned short* BpP2h = (unsigned short*)alloc(16384 * 2);
    unsigned short* BpP2l = (unsigned short*)alloc(16384 * 2);

    // Aliases inside the TAB region (all offsets 256B-aligned):
    unsigned short* xhi = TAB;                               // N*160 elems
    unsigned short* xlo = TAB + (size_t)N * 160;             // N*160 elems -> ends at N*320
    unsigned short* uhi = TAB + (size_t)N * 320;             // N*256 elems
    unsigned short* ulo = TAB + (size_t)N * 576;             // N*256 elems -> ends at N*832 <= N*1088
    unsigned short* t1hi = TAB;                              // N*128 elems (post-loop)
    unsigned short* t1lo = TAB + (size_t)N * 128;            // N*128 elems

    init_nodes<<<(N * 128) / 256, 256, 0, stream>>>(z, emb, hf, hhi, hlo, N);
    norm2_kernel<<<E / 256, 256, 0, stream>>>(pos, src, dstp, n2, E);

    for (int l = 0; l < 7; ++l) {
        pack_msg1<<<139264 / 256, 256, 0, stream>>>(
            Wm1 + (size_t)l * 257 * 514, bm1 + (size_t)l * 514, Wm2 + (size_t)l * 514 * 16,
            Bp1h, Bp1l, bias1088, w1cf, W2ph, W2pl);
        gemm16<<<dim3(N / 16, 17), 256, 0, stream>>>(
            hhi, hlo, 128, Bp1h, Bp1l, bias1088, 4, 68, 0,
            TAB, nullptr, 1088, nullptr, 0, nullptr, nullptr, nullptr);
        hipMemsetAsync(agg, 0, (size_t)N * 16 * 4, stream);
        edge_kernel<<<E / 32, 128, 0, stream>>>(TAB, w1cf, W2ph, W2pl, bm2 + l * 16,
                                                src, dstp, n2, agg);
        pack_x<<<(N * 160) / 256, 256, 0, stream>>>(agg, hf, xhi, xlo, N);
        pack_generic<<<(160 * 256) / 256, 256, 0, stream>>>(
            Wu1 + (size_t)l * 144 * 256, 144, 256, BpU1h, BpU1l);
        gemm16<<<dim3(N / 16, 4), 256, 0, stream>>>(
            xhi, xlo, 160, BpU1h, BpU1l, bu1 + l * 256, 5, 16, 1,
            uhi, ulo, 256, nullptr, 0, nullptr, nullptr, nullptr);
        pack_generic<<<(256 * 128) / 256, 256, 0, stream>>>(
            Wu2 + (size_t)l * 256 * 128, 256, 128, BpU2h, BpU2l);
        gemm16<<<dim3(N / 16, 2), 256, 0, stream>>>(
            uhi, ulo, 256, BpU2h, BpU2l, bu2 + l * 128, 8, 8, 2,
            hhi, hlo, 128, hf, 128, hf, nullptr, nullptr);
    }

    pack_generic<<<(128 * 128) / 256, 256, 0, stream>>>(Wp1, 128, 128, BpP1h, BpP1l);
    gemm16<<<dim3(N / 16, 2), 256, 0, stream>>>(
        hhi, hlo, 128, BpP1h, BpP1l, bp1v, 4, 8, 1,
        t1hi, t1lo, 128, nullptr, 0, nullptr, nullptr, nullptr);
    pack_generic<<<(128 * 128) / 256, 256, 0, stream>>>(Wp2, 128, 128, BpP2h, BpP2l);
    hipMemsetAsync(pooled, 0, (size_t)G * 128 * 4, stream);
    gemm16<<<dim3(N / 16, 2), 256, 0, stream>>>(
        t1hi, t1lo, 128, BpP2h, BpP2l, bp2v, 4, 8, 3,
        nullptr, nullptr, 0, nullptr, 0, nullptr, batch, pooled);
    readout<<<G, 128, 0, stream>>>(pooled, Wr1, br1, Wr2, br2, (float*)d_out);
}

// Round 5
// 4464.135 us; speedup vs baseline: 1.7332x; 1.7332x over previous
//
#include <hip/hip_runtime.h>
#include <hip/hip_bf16.h>
#include <cstdint>
#include <cstddef>

typedef short s16x8 __attribute__((ext_vector_type(8)));
typedef float f32x4 __attribute__((ext_vector_type(4)));
typedef unsigned int u32x4 __attribute__((ext_vector_type(4)));

__device__ __forceinline__ unsigned short f2bf(float f) {
    unsigned int u = __float_as_uint(f);
    unsigned int r = (u + 0x7FFFu + ((u >> 16) & 1u)) >> 16;
    return (unsigned short)r;
}
__device__ __forceinline__ float bf2f(unsigned short s) {
    return __uint_as_float(((unsigned int)s) << 16);
}
__device__ __forceinline__ void splitbf(float v, unsigned short& hi, unsigned short& lo) {
    hi = f2bf(v);
    lo = f2bf(v - bf2f(hi));
}
__device__ __forceinline__ float swishf(float x) {
    return x / (1.0f + __expf(-x));
}

// ---------------- init: h = emb[atomic[z]] ----------------
__global__ void init_nodes(const int* __restrict__ z, const float* __restrict__ emb,
                           float* __restrict__ hf, unsigned short* __restrict__ hhi,
                           unsigned short* __restrict__ hlo, int N) {
    int tid = blockIdx.x * 256 + threadIdx.x;
    int n = tid >> 7, f = tid & 127;
    int zv = z[n];
    int idx5 = (zv == 1) ? 0 : (zv - 5);
    float v = emb[idx5 * 128 + f];
    hf[tid] = v;
    unsigned short hi, lo;
    splitbf(v, hi, lo);
    hhi[tid] = hi;
    hlo[tid] = lo;
}

// ---------------- edge preprocessing: counting sort by dst ----------------
__global__ void hist_kernel(const int* __restrict__ dst, int* __restrict__ hist, int E) {
    int e = blockIdx.x * 256 + threadIdx.x;
    if (e < E) atomicAdd(&hist[dst[e]], 1);
}

__global__ void scan_kernel(const int* __restrict__ hist, int* __restrict__ cursor, int N) {
    __shared__ int part[256];
    int t = threadIdx.x;
    int chunk = (N + 255) / 256;
    int base = t * chunk;
    int s = 0;
    for (int i = 0; i < chunk; ++i) {
        int idx = base + i;
        if (idx < N) s += hist[idx];
    }
    part[t] = s;
    __syncthreads();
    for (int d = 1; d < 256; d <<= 1) {
        int v = 0;
        if (t >= d) v = part[t - d];
        __syncthreads();
        part[t] += v;
        __syncthreads();
    }
    int run = part[t] - s;  // exclusive prefix of this thread's chunk
    for (int i = 0; i < chunk; ++i) {
        int idx = base + i;
        if (idx < N) {
            cursor[idx] = run;
            run += hist[idx];
        }
    }
}

__global__ void scatter_kernel(const int* __restrict__ dst, int* __restrict__ cursor,
                               int* __restrict__ perm, int E) {
    int e = blockIdx.x * 256 + threadIdx.x;
    if (e < E) {
        int p = atomicAdd(&cursor[dst[e]], 1);
        perm[p] = e;
    }
}

__global__ void reorder_kernel(const int* __restrict__ perm, const int* __restrict__ src,
                               const int* __restrict__ dst, const float* __restrict__ pos,
                               int* __restrict__ srcS, int* __restrict__ dstS,
                               float* __restrict__ n2S, int E) {
    int i = blockIdx.x * 256 + threadIdx.x;
    if (i >= E) return;
    int e = perm[i];
    int si = src[e], di = dst[e];
    srcS[i] = si;
    dstS[i] = di;
    float dx = pos[si * 3 + 0] - pos[di * 3 + 0];
    float dy = pos[si * 3 + 1] - pos[di * 3 + 1];
    float dz = pos[si * 3 + 2] - pos[di * 3 + 2];
    n2S[i] = dx * dx + dy * dy + dz * dz;
}

// ---------------- pack W_msg1 + W_msg2 for layer l (hi/lo) ----------------
__global__ void pack_msg1(const float* __restrict__ Wm1l, const float* __restrict__ bm1l,
                          const float* __restrict__ Wm2l,
                          unsigned short* __restrict__ Bp1h, unsigned short* __restrict__ Bp1l,
                          float* __restrict__ bias1088, float* __restrict__ w1cf,
                          unsigned short* __restrict__ W2ph, unsigned short* __restrict__ W2pl) {
    int t = blockIdx.x * 256 + threadIdx.x;
    int i = t & 7;
    int lane = (t >> 3) & 63;
    int rest = t >> 9;
    int cb = rest % 68;
    int ks = rest / 68;
    int k = ks * 32 + ((lane >> 4) << 3) + i;  // 0..127
    int ch = cb * 16 + (lane & 15);            // 0..1087
    float val;
    if (ch < 544) {
        val = (ch < 514) ? Wm1l[k * 514 + ch] : 0.f;
    } else {
        int c = ch - 544;
        val = (c < 514) ? Wm1l[(128 + k) * 514 + c] : 0.f;
    }
    unsigned short hi, lo;
    splitbf(val, hi, lo);
    Bp1h[t] = hi;
    Bp1l[t] = lo;
    if (t < 1088) bias1088[t] = (t < 514) ? bm1l[t] : 0.f;
    if (t < 544) w1cf[t] = (t < 514) ? Wm1l[256 * 514 + t] : 0.f;
    if (t < 8704) {
        int i2 = t & 7, lane2 = (t >> 3) & 63, ks2 = t >> 9;
        int k2 = ks2 * 32 + ((lane2 >> 4) << 3) + i2;
        int c2 = lane2 & 15;
        float v2 = (k2 < 514) ? Wm2l[k2 * 16 + c2] : 0.f;
        unsigned short h2, l2;
        splitbf(v2, h2, l2);
        W2ph[t] = h2;
        W2pl[t] = l2;
    }
}

// ---------------- generic B packer: W[K][Nc] fp32 -> frag layout hi/lo ----------------
__global__ void pack_generic(const float* __restrict__ W, int K, int Nc,
                             unsigned short* __restrict__ Bph, unsigned short* __restrict__ Bpl) {
    int t = blockIdx.x * 256 + threadIdx.x;
    int i = t & 7;
    int lane = (t >> 3) & 63;
    int rest = t >> 9;
    int CB = Nc >> 4;
    int cb = rest % CB;
    int ks = rest / CB;
    int k = ks * 32 + ((lane >> 4) << 3) + i;
    int c = cb * 16 + (lane & 15);
    float val = (k < K) ? W[(size_t)k * Nc + c] : 0.f;
    unsigned short hi, lo;
    splitbf(val, hi, lo);
    Bph[t] = hi;
    Bpl[t] = lo;
}

// ---------------- pack x = [agg(16) | h(128) | 0(16)] hi/lo ----------------
__global__ void pack_x(const float* __restrict__ agg, const float* __restrict__ hf,
                       unsigned short* __restrict__ xhi, unsigned short* __restrict__ xlo, int N) {
    int t = blockIdx.x * 256 + threadIdx.x;
    int n = t / 160, c = t % 160;
    float val;
    if (c < 16) val = agg[n * 16 + c];
    else if (c < 144) val = hf[n * 128 + (c - 16)];
    else val = 0.f;
    unsigned short hi, lo;
    splitbf(val, hi, lo);
    xhi[t] = hi;
    xlo[t] = lo;
}

// ---------------- specialized table GEMM: A(K=128) in regs, loop 68 col-blocks ----------------
__global__ __launch_bounds__(256) void tab_gemm(
    const unsigned short* __restrict__ Ahi, const unsigned short* __restrict__ Alo,
    const unsigned short* __restrict__ Bph, const unsigned short* __restrict__ Bpl,
    const float* __restrict__ bias, unsigned short* __restrict__ TAB, int N) {
    int lane = threadIdx.x & 63;
    int wid = threadIdx.x >> 6;
    int row0 = blockIdx.x * 64 + wid * 16;
    if (row0 >= N) return;
    const size_t arow = (size_t)(row0 + (lane & 15)) * 128;
    const int ak = (lane >> 4) * 8;
    s16x8 ah[4], al[4];
#pragma unroll
    for (int ks = 0; ks < 4; ++ks) {
        ah[ks] = *(const s16x8*)(Ahi + arow + ks * 32 + ak);
        al[ks] = *(const s16x8*)(Alo + arow + ks * 32 + ak);
    }
    int col16 = lane & 15;
    int rb = (lane >> 4) * 4;
    for (int cb = 0; cb < 68; ++cb) {
        f32x4 acc = {0.f, 0.f, 0.f, 0.f};
#pragma unroll
        for (int ks = 0; ks < 4; ++ks) {
            size_t bidx = ((size_t)(ks * 68 + cb) * 64 + lane) * 8;
            s16x8 bh = *(const s16x8*)(Bph + bidx);
            s16x8 bl = *(const s16x8*)(Bpl + bidx);
            acc = __builtin_amdgcn_mfma_f32_16x16x32_bf16(ah[ks], bh, acc, 0, 0, 0);
            acc = __builtin_amdgcn_mfma_f32_16x16x32_bf16(al[ks], bh, acc, 0, 0, 0);
            acc = __builtin_amdgcn_mfma_f32_16x16x32_bf16(ah[ks], bl, acc, 0, 0, 0);
        }
        float bv = bias[cb * 16 + col16];
#pragma unroll
        for (int i = 0; i < 4; ++i) {
            TAB[(size_t)(row0 + rb + i) * 1088 + cb * 16 + col16] = f2bf(acc[i] + bv);
        }
    }
}

// ---------------- generic 16x16x32 MFMA GEMM, split precision ----------------
// mode 1: swish(acc+bias) -> outB (hi), outB2 (lo)
// mode 2: h = acc+bias+resid; outF=h (f32), outB/outB2 = hi/lo
// mode 3: atomicAdd(pooled[batch[row]*128+col], acc+bias)
__global__ __launch_bounds__(256) void gemm16(
    const unsigned short* __restrict__ Ahi, const unsigned short* __restrict__ Alo, int lda,
    const unsigned short* __restrict__ Bph, const unsigned short* __restrict__ Bpl,
    const float* __restrict__ bias,
    int ksteps, int CB, int mode,
    unsigned short* __restrict__ outB, unsigned short* __restrict__ outB2, int ldoB,
    float* __restrict__ outF, int ldoF, const float* __restrict__ resid,
    const int* __restrict__ batch, float* __restrict__ pooled) {
    int lane = threadIdx.x & 63;
    int w = threadIdx.x >> 6;
    int row0 = blockIdx.x * 16;
    int cb = blockIdx.y * 4 + w;
    int col0 = cb * 16;
    const size_t arow = (size_t)(row0 + (lane & 15)) * lda;
    const int ak = (lane >> 4) * 8;
    f32x4 acc = {0.f, 0.f, 0.f, 0.f};
    for (int ks = 0; ks < ksteps; ++ks) {
        s16x8 ah = *(const s16x8*)(Ahi + arow + ks * 32 + ak);
        s16x8 al = *(const s16x8*)(Alo + arow + ks * 32 + ak);
        size_t bidx = ((size_t)(ks * CB + cb) * 64 + lane) * 8;
        s16x8 bh = *(const s16x8*)(Bph + bidx);
        s16x8 bl = *(const s16x8*)(Bpl + bidx);
        acc = __builtin_amdgcn_mfma_f32_16x16x32_bf16(ah, bh, acc, 0, 0, 0);
        acc = __builtin_amdgcn_mfma_f32_16x16x32_bf16(al, bh, acc, 0, 0, 0);
        acc = __builtin_amdgcn_mfma_f32_16x16x32_bf16(ah, bl, acc, 0, 0, 0);
    }
    int col = col0 + (lane & 15);
    float bv = bias[col];
    int rb = (lane >> 4) * 4;
#pragma unroll
    for (int i = 0; i < 4; ++i) {
        int row = row0 + rb + i;
        float v = acc[i] + bv;
        if (mode == 1) {
            float s = swishf(v);
            unsigned short hi, lo;
            splitbf(s, hi, lo);
            outB[(size_t)row * ldoB + col] = hi;
            outB2[(size_t)row * ldoB + col] = lo;
        } else if (mode == 2) {
            float h = v + resid[(size_t)row * ldoF + col];
            outF[(size_t)row * ldoF + col] = h;
            unsigned short hi, lo;
            splitbf(h, hi, lo);
            outB[(size_t)row * ldoB + col] = hi;
            outB2[(size_t)row * ldoB + col] = lo;
        } else {
            unsafeAtomicAdd(&pooled[(size_t)batch[row] * 128 + col], v);
        }
    }
}

// ---------------- edge kernel: LDS-free gather, direct MFMA ----------------
// Each wave: 16 edges. lane = (r, g): edge r = ebase+(lane&15), k-chunk g = lane>>4.
// Lane gathers its own 16B A-fragment pieces from TAB, computes swish in-reg,
// feeds MFMA directly. W2 hi/lo frags + w1c staged in LDS per block.
__global__ __launch_bounds__(256) void edge_kernel(
    const unsigned short* __restrict__ TAB, const float* __restrict__ w1cf,
    const unsigned short* __restrict__ W2ph, const unsigned short* __restrict__ W2pl,
    const float* __restrict__ bm2l,
    const int* __restrict__ srcS, const int* __restrict__ dstS,
    const float* __restrict__ n2S, float* __restrict__ agg) {
    __shared__ unsigned short sWh[8704];
    __shared__ unsigned short sWl[8704];
    __shared__ float sw1[544];
    for (int t = threadIdx.x; t < 1088; t += 256) {
        ((s16x8*)sWh)[t] = ((const s16x8*)W2ph)[t];
        ((s16x8*)sWl)[t] = ((const s16x8*)W2pl)[t];
    }
    for (int t = threadIdx.x; t < 544; t += 256) sw1[t] = w1cf[t];
    __syncthreads();

    int lane = threadIdx.x & 63;
    int wid = threadIdx.x >> 6;
    int ebase = blockIdx.x * 64 + wid * 16;
    int er = ebase + (lane & 15);
    int di = dstS[er], si = srcS[er];
    float n2v = n2S[er];
    const int ak = (lane >> 4) * 8;
    const unsigned short* pa = TAB + (size_t)di * 1088 + ak;
    const unsigned short* pb = TAB + (size_t)si * 1088 + 544 + ak;

    f32x4 acc = {0.f, 0.f, 0.f, 0.f};
    for (int ks = 0; ks < 17; ++ks) {
        s16x8 va = *(const s16x8*)(pa + ks * 32);
        s16x8 vb = *(const s16x8*)(pb + ks * 32);
        f32x4 c0 = *(const f32x4*)(sw1 + ks * 32 + ak);
        f32x4 c1 = *(const f32x4*)(sw1 + ks * 32 + ak + 4);
        u32x4 mu;
#pragma unroll
        for (int jj = 0; jj < 4; ++jj) {
            float w0 = (jj < 2) ? c0[2 * jj] : c1[2 * jj - 4];
            float w1 = (jj < 2) ? c0[2 * jj + 1] : c1[2 * jj - 3];
            float x0 = bf2f((unsigned short)va[2 * jj]) + bf2f((unsigned short)vb[2 * jj]) + n2v * w0;
            float x1 = bf2f((unsigned short)va[2 * jj + 1]) + bf2f((unsigned short)vb[2 * jj + 1]) + n2v * w1;
            unsigned int p0 = f2bf(swishf(x0));
            unsigned int p1 = f2bf(swishf(x1));
            mu[jj] = p0 | (p1 << 16);
        }
        s16x8 m = __builtin_bit_cast(s16x8, mu);
        s16x8 bh = *(const s16x8*)(sWh + (ks * 64 + lane) * 8);
        s16x8 bl = *(const s16x8*)(sWl + (ks * 64 + lane) * 8);
        acc = __builtin_amdgcn_mfma_f32_16x16x32_bf16(m, bh, acc, 0, 0, 0);
        acc = __builtin_amdgcn_mfma_f32_16x16x32_bf16(m, bl, acc, 0, 0, 0);
    }

    int col = lane & 15;
    float b2 = bm2l[col];
#pragma unroll
    for (int i = 0; i < 4; ++i) {
        int e = ebase + (lane >> 4) * 4 + i;
        float v = swishf(acc[i] + b2);
        unsafeAtomicAdd(&agg[(size_t)dstS[e] * 16 + col], v);
    }
}

// ---------------- readout ----------------
__global__ void readout(const float* __restrict__ pooled, const float* __restrict__ Wr1,
                        const float* __restrict__ br1, const float* __restrict__ Wr2,
                        const float* __restrict__ br2, float* __restrict__ out) {
    __shared__ float row[128];
    __shared__ float tt[128];
    int g = blockIdx.x;
    int t = threadIdx.x;
    row[t] = pooled[g * 128 + t];
    __syncthreads();
    float s = br1[t];
    for (int k = 0; k < 128; ++k) s += row[k] * Wr1[k * 128 + t];
    tt[t] = swishf(s);
    __syncthreads();
    if (t < 12) {
        float o = br2[t];
        for (int j = 0; j < 128; ++j) o += tt[j] * Wr2[j * 12 + t];
        out[g * 12 + t] = o;
    }
}

extern "C" void kernel_launch(void* const* d_in, const int* in_sizes, int n_in,
                              void* d_out, int out_size, void* d_ws, size_t ws_size,
                              hipStream_t stream) {
    const float* pos = (const float*)d_in[0];
    const int* z = (const int*)d_in[1];
    const int* ei = (const int*)d_in[2];
    const int* batch = (const int*)d_in[3];
    const float* emb = (const float*)d_in[4];
    const float* Wm1 = (const float*)d_in[5];
    const float* bm1 = (const float*)d_in[6];
    const float* Wm2 = (const float*)d_in[7];
    const float* bm2 = (const float*)d_in[8];
    const float* Wu1 = (const float*)d_in[9];
    const float* bu1 = (const float*)d_in[10];
    const float* Wu2 = (const float*)d_in[11];
    const float* bu2 = (const float*)d_in[12];
    const float* Wp1 = (const float*)d_in[13];
    const float* bp1v = (const float*)d_in[14];
    const float* Wp2 = (const float*)d_in[15];
    const float* bp2v = (const float*)d_in[16];
    const float* Wr1 = (const float*)d_in[17];
    const float* br1 = (const float*)d_in[18];
    const float* Wr2 = (const float*)d_in[19];
    const float* br2 = (const float*)d_in[20];

    const int N = in_sizes[0] / 3;   // 50000
    const int E = in_sizes[2] / 2;   // 800000
    const int G = out_size / 12;     // 1000
    const int* src = ei;
    const int* dstp = ei + E;

    char* ws = (char*)d_ws;
    size_t off = 0;
    auto alloc = [&](size_t bytes) -> char* {
        char* p = ws + off;
        off += (bytes + 255) & ~(size_t)255;
        return p;
    };
    unsigned short* TAB = (unsigned short*)alloc((size_t)N * 1088 * 2);
    float* hf = (float*)alloc((size_t)N * 128 * 4);
    unsigned short* hhi = (unsigned short*)alloc((size_t)N * 128 * 2);
    unsigned short* hlo = (unsigned short*)alloc((size_t)N * 128 * 2);
    float* agg = (float*)alloc((size_t)N * 16 * 4);
    float* pooled = (float*)alloc((size_t)G * 128 * 4);
    int* hist = (int*)alloc((size_t)N * 4);
    int* cursor = (int*)alloc((size_t)N * 4);
    int* perm = (int*)alloc((size_t)E * 4);
    int* srcS = (int*)alloc((size_t)E * 4);
    int* dstS = (int*)alloc((size_t)E * 4);
    float* n2S = (float*)alloc((size_t)E * 4);
    unsigned short* Bp1h = (unsigned short*)alloc(139264 * 2);
    unsigned short* Bp1l = (unsigned short*)alloc(139264 * 2);
    float* bias1088 = (float*)alloc(1088 * 4);
    float* w1cf = (float*)alloc(544 * 4);
    unsigned short* W2ph = (unsigned short*)alloc(8704 * 2);
    unsigned short* W2pl = (unsigned short*)alloc(8704 * 2);
    unsigned short* BpU1h = (unsigned short*)alloc(40960 * 2);
    unsigned short* BpU1l = (unsigned short*)alloc(40960 * 2);
    unsigned short* BpU2h = (unsigned short*)alloc(32768 * 2);
    unsigned short* BpU2l = (unsigned short*)alloc(32768 * 2);
    unsigned short* BpP1h = (unsigned short*)alloc(16384 * 2);
    unsigned short* BpP1l = (unsigned short*)alloc(16384 * 2);
    unsigned short* BpP2h = (unsigned short*)alloc(16384 * 2);
    unsigned short* BpP2l = (unsigned short*)alloc(16384 * 2);

    // Aliases inside the TAB region (dead between edge_kernel and next table GEMM):
    unsigned short* xhi = TAB;
    unsigned short* xlo = TAB + (size_t)N * 160;
    unsigned short* uhi = TAB + (size_t)N * 320;
    unsigned short* ulo = TAB + (size_t)N * 576;
    unsigned short* t1hi = TAB;
    unsigned short* t1lo = TAB + (size_t)N * 128;

    init_nodes<<<(N * 128) / 256, 256, 0, stream>>>(z, emb, hf, hhi, hlo, N);

    // one-time: counting sort of edges by dst
    hipMemsetAsync(hist, 0, (size_t)N * 4, stream);
    hist_kernel<<<(E + 255) / 256, 256, 0, stream>>>(dstp, hist, E);
    scan_kernel<<<1, 256, 0, stream>>>(hist, cursor, N);
    scatter_kernel<<<(E + 255) / 256, 256, 0, stream>>>(dstp, cursor, perm, E);
    reorder_kernel<<<(E + 255) / 256, 256, 0, stream>>>(perm, src, dstp, pos, srcS, dstS, n2S, E);

    for (int l = 0; l < 7; ++l) {
        pack_msg1<<<139264 / 256, 256, 0, stream>>>(
            Wm1 + (size_t)l * 257 * 514, bm1 + (size_t)l * 514, Wm2 + (size_t)l * 514 * 16,
            Bp1h, Bp1l, bias1088, w1cf, W2ph, W2pl);
        tab_gemm<<<(N / 16 + 3) / 4, 256, 0, stream>>>(
            hhi, hlo, Bp1h, Bp1l, bias1088, TAB, N);
        hipMemsetAsync(agg, 0, (size_t)N * 16 * 4, stream);
        edge_kernel<<<E / 64, 256, 0, stream>>>(TAB, w1cf, W2ph, W2pl, bm2 + l * 16,
                                                srcS, dstS, n2S, agg);
        pack_x<<<(N * 160) / 256, 256, 0, stream>>>(agg, hf, xhi, xlo, N);
        pack_generic<<<(160 * 256) / 256, 256, 0, stream>>>(
            Wu1 + (size_t)l * 144 * 256, 144, 256, BpU1h, BpU1l);
        gemm16<<<dim3(N / 16, 4), 256, 0, stream>>>(
            xhi, xlo, 160, BpU1h, BpU1l, bu1 + l * 256, 5, 16, 1,
            uhi, ulo, 256, nullptr, 0, nullptr, nullptr, nullptr);
        pack_generic<<<(256 * 128) / 256, 256, 0, stream>>>(
            Wu2 + (size_t)l * 256 * 128, 256, 128, BpU2h, BpU2l);
        gemm16<<<dim3(N / 16, 2), 256, 0, stream>>>(
            uhi, ulo, 256, BpU2h, BpU2l, bu2 + l * 128, 8, 8, 2,
            hhi, hlo, 128, hf, 128, hf, nullptr, nullptr);
    }

    pack_generic<<<(128 * 128) / 256, 256, 0, stream>>>(Wp1, 128, 128, BpP1h, BpP1l);
    gemm16<<<dim3(N / 16, 2), 256, 0, stream>>>(
        hhi, hlo, 128, BpP1h, BpP1l, bp1v, 4, 8, 1,
        t1hi, t1lo, 128, nullptr, 0, nullptr, nullptr, nullptr);
    pack_generic<<<(128 * 128) / 256, 256, 0, stream>>>(Wp2, 128, 128, BpP2h, BpP2l);
    hipMemsetAsync(pooled, 0, (size_t)G * 128 * 4, stream);
    gemm16<<<dim3(N / 16, 2), 256, 0, stream>>>(
        t1hi, t1lo, 128, BpP2h, BpP2l, bp2v, 4, 8, 3,
        nullptr, nullptr, 0, nullptr, 0, nullptr, batch, pooled);
    readout<<<G, 128, 0, stream>>>(pooled, Wr1, br1, Wr2, br2, (float*)d_out);
}

// Round 6
// 4223.708 us; speedup vs baseline: 1.8319x; 1.0569x over previous
//
#include <hip/hip_runtime.h>
#include <hip/hip_bf16.h>
#include <cstdint>
#include <cstddef>

typedef short s16x8 __attribute__((ext_vector_type(8)));
typedef float f32x4 __attribute__((ext_vector_type(4)));
typedef unsigned int u32x4 __attribute__((ext_vector_type(4)));

__device__ __forceinline__ unsigned short f2bf(float f) {
    unsigned int u = __float_as_uint(f);
    unsigned int r = (u + 0x7FFFu + ((u >> 16) & 1u)) >> 16;
    return (unsigned short)r;
}
__device__ __forceinline__ float bf2f(unsigned short s) {
    return __uint_as_float(((unsigned int)s) << 16);
}
__device__ __forceinline__ void splitbf(float v, unsigned short& hi, unsigned short& lo) {
    hi = f2bf(v);
    lo = f2bf(v - bf2f(hi));
}
// fast swish: x * rcp(1+exp(-x)); v_rcp_f32 rel-err ~1e-7 << bf16 ulp
__device__ __forceinline__ float swish_fast(float x) {
    float e = __expf(-x);
    return x * __builtin_amdgcn_rcpf(1.0f + e);
}
// pack 2 f32 -> 2 bf16 (RNE) in one instruction
__device__ __forceinline__ unsigned int cvt_pk_bf16(float lo, float hi) {
    unsigned int r;
    asm("v_cvt_pk_bf16_f32 %0, %1, %2" : "=v"(r) : "v"(lo), "v"(hi));
    return r;
}

// ---------------- init: h = emb[atomic[z]] ----------------
__global__ void init_nodes(const int* __restrict__ z, const float* __restrict__ emb,
                           float* __restrict__ hf, unsigned short* __restrict__ hhi,
                           unsigned short* __restrict__ hlo, int N) {
    int tid = blockIdx.x * 256 + threadIdx.x;
    int n = tid >> 7, f = tid & 127;
    int zv = z[n];
    int idx5 = (zv == 1) ? 0 : (zv - 5);
    float v = emb[idx5 * 128 + f];
    hf[tid] = v;
    unsigned short hi, lo;
    splitbf(v, hi, lo);
    hhi[tid] = hi;
    hlo[tid] = lo;
}

// ---------------- edge preprocessing: counting sort by dst ----------------
__global__ void hist_kernel(const int* __restrict__ dst, int* __restrict__ hist, int E) {
    int e = blockIdx.x * 256 + threadIdx.x;
    if (e < E) atomicAdd(&hist[dst[e]], 1);
}

__global__ void scan_kernel(const int* __restrict__ hist, int* __restrict__ cursor, int N) {
    __shared__ int part[256];
    int t = threadIdx.x;
    int chunk = (N + 255) / 256;
    int base = t * chunk;
    int s = 0;
    for (int i = 0; i < chunk; ++i) {
        int idx = base + i;
        if (idx < N) s += hist[idx];
    }
    part[t] = s;
    __syncthreads();
    for (int d = 1; d < 256; d <<= 1) {
        int v = 0;
        if (t >= d) v = part[t - d];
        __syncthreads();
        part[t] += v;
        __syncthreads();
    }
    int run = part[t] - s;  // exclusive prefix of this thread's chunk
    for (int i = 0; i < chunk; ++i) {
        int idx = base + i;
        if (idx < N) {
            cursor[idx] = run;
            run += hist[idx];
        }
    }
}

__global__ void scatter_kernel(const int* __restrict__ dst, int* __restrict__ cursor,
                               int* __restrict__ perm, int E) {
    int e = blockIdx.x * 256 + threadIdx.x;
    if (e < E) {
        int p = atomicAdd(&cursor[dst[e]], 1);
        perm[p] = e;
    }
}

__global__ void reorder_kernel(const int* __restrict__ perm, const int* __restrict__ src,
                               const int* __restrict__ dst, const float* __restrict__ pos,
                               int* __restrict__ srcS, int* __restrict__ dstS,
                               float* __restrict__ n2S, int E) {
    int i = blockIdx.x * 256 + threadIdx.x;
    if (i >= E) return;
    int e = perm[i];
    int si = src[e], di = dst[e];
    srcS[i] = si;
    dstS[i] = di;
    float dx = pos[si * 3 + 0] - pos[di * 3 + 0];
    float dy = pos[si * 3 + 1] - pos[di * 3 + 1];
    float dz = pos[si * 3 + 2] - pos[di * 3 + 2];
    n2S[i] = dx * dx + dy * dy + dz * dz;
}

// ---------------- pack W_msg1 + W_msg2 for layer l (hi/lo) ----------------
__global__ void pack_msg1(const float* __restrict__ Wm1l, const float* __restrict__ bm1l,
                          const float* __restrict__ Wm2l,
                          unsigned short* __restrict__ Bp1h, unsigned short* __restrict__ Bp1l,
                          float* __restrict__ bias1088, float* __restrict__ w1cf,
                          unsigned short* __restrict__ W2ph, unsigned short* __restrict__ W2pl) {
    int t = blockIdx.x * 256 + threadIdx.x;
    int i = t & 7;
    int lane = (t >> 3) & 63;
    int rest = t >> 9;
    int cb = rest % 68;
    int ks = rest / 68;
    int k = ks * 32 + ((lane >> 4) << 3) + i;  // 0..127
    int ch = cb * 16 + (lane & 15);            // 0..1087
    float val;
    if (ch < 544) {
        val = (ch < 514) ? Wm1l[k * 514 + ch] : 0.f;
    } else {
        int c = ch - 544;
        val = (c < 514) ? Wm1l[(128 + k) * 514 + c] : 0.f;
    }
    unsigned short hi, lo;
    splitbf(val, hi, lo);
    Bp1h[t] = hi;
    Bp1l[t] = lo;
    if (t < 1088) bias1088[t] = (t < 514) ? bm1l[t] : 0.f;
    if (t < 544) w1cf[t] = (t < 514) ? Wm1l[256 * 514 + t] : 0.f;
    if (t < 8704) {
        int i2 = t & 7, lane2 = (t >> 3) & 63, ks2 = t >> 9;
        int k2 = ks2 * 32 + ((lane2 >> 4) << 3) + i2;
        int c2 = lane2 & 15;
        float v2 = (k2 < 514) ? Wm2l[k2 * 16 + c2] : 0.f;
        unsigned short h2, l2;
        splitbf(v2, h2, l2);
        W2ph[t] = h2;
        W2pl[t] = l2;
    }
}

// ---------------- generic B packer: W[K][Nc] fp32 -> frag layout hi/lo ----------------
__global__ void pack_generic(const float* __restrict__ W, int K, int Nc,
                             unsigned short* __restrict__ Bph, unsigned short* __restrict__ Bpl) {
    int t = blockIdx.x * 256 + threadIdx.x;
    int i = t & 7;
    int lane = (t >> 3) & 63;
    int rest = t >> 9;
    int CB = Nc >> 4;
    int cb = rest % CB;
    int ks = rest / CB;
    int k = ks * 32 + ((lane >> 4) << 3) + i;
    int c = cb * 16 + (lane & 15);
    float val = (k < K) ? W[(size_t)k * Nc + c] : 0.f;
    unsigned short hi, lo;
    splitbf(val, hi, lo);
    Bph[t] = hi;
    Bpl[t] = lo;
}

// ---------------- pack x = [agg(16) | h(128) | 0(16)] hi/lo ----------------
__global__ void pack_x(const float* __restrict__ agg, const float* __restrict__ hf,
                       unsigned short* __restrict__ xhi, unsigned short* __restrict__ xlo, int N) {
    int t = blockIdx.x * 256 + threadIdx.x;
    int n = t / 160, c = t % 160;
    float val;
    if (c < 16) val = agg[n * 16 + c];
    else if (c < 144) val = hf[n * 128 + (c - 16)];
    else val = 0.f;
    unsigned short hi, lo;
    splitbf(val, hi, lo);
    xhi[t] = hi;
    xlo[t] = lo;
}

// ---------------- specialized table GEMM: A(K=128) in regs, loop 68 col-blocks ----------------
__global__ __launch_bounds__(256) void tab_gemm(
    const unsigned short* __restrict__ Ahi, const unsigned short* __restrict__ Alo,
    const unsigned short* __restrict__ Bph, const unsigned short* __restrict__ Bpl,
    const float* __restrict__ bias, unsigned short* __restrict__ TAB, int N) {
    int lane = threadIdx.x & 63;
    int wid = threadIdx.x >> 6;
    int row0 = blockIdx.x * 64 + wid * 16;
    if (row0 >= N) return;
    const size_t arow = (size_t)(row0 + (lane & 15)) * 128;
    const int ak = (lane >> 4) * 8;
    s16x8 ah[4], al[4];
#pragma unroll
    for (int ks = 0; ks < 4; ++ks) {
        ah[ks] = *(const s16x8*)(Ahi + arow + ks * 32 + ak);
        al[ks] = *(const s16x8*)(Alo + arow + ks * 32 + ak);
    }
    int col16 = lane & 15;
    int rb = (lane >> 4) * 4;
    for (int cb = 0; cb < 68; ++cb) {
        f32x4 acc = {0.f, 0.f, 0.f, 0.f};
#pragma unroll
        for (int ks = 0; ks < 4; ++ks) {
            size_t bidx = ((size_t)(ks * 68 + cb) * 64 + lane) * 8;
            s16x8 bh = *(const s16x8*)(Bph + bidx);
            s16x8 bl = *(const s16x8*)(Bpl + bidx);
            acc = __builtin_amdgcn_mfma_f32_16x16x32_bf16(ah[ks], bh, acc, 0, 0, 0);
            acc = __builtin_amdgcn_mfma_f32_16x16x32_bf16(al[ks], bh, acc, 0, 0, 0);
            acc = __builtin_amdgcn_mfma_f32_16x16x32_bf16(ah[ks], bl, acc, 0, 0, 0);
        }
        float bv = bias[cb * 16 + col16];
#pragma unroll
        for (int i = 0; i < 4; ++i) {
            TAB[(size_t)(row0 + rb + i) * 1088 + cb * 16 + col16] = f2bf(acc[i] + bv);
        }
    }
}

// ---------------- generic 16x16x32 MFMA GEMM, split precision ----------------
// mode 1: swish(acc+bias) -> outB (hi), outB2 (lo)
// mode 2: h = acc+bias+resid; outF=h (f32), outB/outB2 = hi/lo
// mode 3: atomicAdd(pooled[batch[row]*128+col], acc+bias)
__global__ __launch_bounds__(256) void gemm16(
    const unsigned short* __restrict__ Ahi, const unsigned short* __restrict__ Alo, int lda,
    const unsigned short* __restrict__ Bph, const unsigned short* __restrict__ Bpl,
    const float* __restrict__ bias,
    int ksteps, int CB, int mode,
    unsigned short* __restrict__ outB, unsigned short* __restrict__ outB2, int ldoB,
    float* __restrict__ outF, int ldoF, const float* __restrict__ resid,
    const int* __restrict__ batch, float* __restrict__ pooled) {
    int lane = threadIdx.x & 63;
    int w = threadIdx.x >> 6;
    int row0 = blockIdx.x * 16;
    int cb = blockIdx.y * 4 + w;
    int col0 = cb * 16;
    const size_t arow = (size_t)(row0 + (lane & 15)) * lda;
    const int ak = (lane >> 4) * 8;
    f32x4 acc = {0.f, 0.f, 0.f, 0.f};
    for (int ks = 0; ks < ksteps; ++ks) {
        s16x8 ah = *(const s16x8*)(Ahi + arow + ks * 32 + ak);
        s16x8 al = *(const s16x8*)(Alo + arow + ks * 32 + ak);
        size_t bidx = ((size_t)(ks * CB + cb) * 64 + lane) * 8;
        s16x8 bh = *(const s16x8*)(Bph + bidx);
        s16x8 bl = *(const s16x8*)(Bpl + bidx);
        acc = __builtin_amdgcn_mfma_f32_16x16x32_bf16(ah, bh, acc, 0, 0, 0);
        acc = __builtin_amdgcn_mfma_f32_16x16x32_bf16(al, bh, acc, 0, 0, 0);
        acc = __builtin_amdgcn_mfma_f32_16x16x32_bf16(ah, bl, acc, 0, 0, 0);
    }
    int col = col0 + (lane & 15);
    float bv = bias[col];
    int rb = (lane >> 4) * 4;
#pragma unroll
    for (int i = 0; i < 4; ++i) {
        int row = row0 + rb + i;
        float v = acc[i] + bv;
        if (mode == 1) {
            float s = swish_fast(v);
            unsigned short hi, lo;
            splitbf(s, hi, lo);
            outB[(size_t)row * ldoB + col] = hi;
            outB2[(size_t)row * ldoB + col] = lo;
        } else if (mode == 2) {
            float h = v + resid[(size_t)row * ldoF + col];
            outF[(size_t)row * ldoF + col] = h;
            unsigned short hi, lo;
            splitbf(h, hi, lo);
            outB[(size_t)row * ldoB + col] = hi;
            outB2[(size_t)row * ldoB + col] = lo;
        } else {
            unsafeAtomicAdd(&pooled[(size_t)batch[row] * 128 + col], v);
        }
    }
}

// ---------------- edge kernel: LDS-free gather, direct MFMA ----------------
__global__ __launch_bounds__(256) void edge_kernel(
    const unsigned short* __restrict__ TAB, const float* __restrict__ w1cf,
    const unsigned short* __restrict__ W2ph, const unsigned short* __restrict__ W2pl,
    const float* __restrict__ bm2l,
    const int* __restrict__ srcS, const int* __restrict__ dstS,
    const float* __restrict__ n2S, float* __restrict__ agg) {
    __shared__ unsigned short sWh[8704];
    __shared__ unsigned short sWl[8704];
    __shared__ float sw1[544];
    for (int t = threadIdx.x; t < 1088; t += 256) {
        ((s16x8*)sWh)[t] = ((const s16x8*)W2ph)[t];
        ((s16x8*)sWl)[t] = ((const s16x8*)W2pl)[t];
    }
    for (int t = threadIdx.x; t < 544; t += 256) sw1[t] = w1cf[t];
    __syncthreads();

    int lane = threadIdx.x & 63;
    int wid = threadIdx.x >> 6;
    int ebase = blockIdx.x * 64 + wid * 16;
    int er = ebase + (lane & 15);
    int di = dstS[er], si = srcS[er];
    float n2v = n2S[er];
    const int ak = (lane >> 4) * 8;
    const unsigned short* pa = TAB + (size_t)di * 1088 + ak;
    const unsigned short* pb = TAB + (size_t)si * 1088 + 544 + ak;

    f32x4 acc = {0.f, 0.f, 0.f, 0.f};
    for (int ks = 0; ks < 17; ++ks) {
        s16x8 va = *(const s16x8*)(pa + ks * 32);
        s16x8 vb = *(const s16x8*)(pb + ks * 32);
        f32x4 c0 = *(const f32x4*)(sw1 + ks * 32 + ak);
        f32x4 c1 = *(const f32x4*)(sw1 + ks * 32 + ak + 4);
        u32x4 mu;
#pragma unroll
        for (int jj = 0; jj < 4; ++jj) {
            float w0 = (jj < 2) ? c0[2 * jj] : c1[2 * jj - 4];
            float w1 = (jj < 2) ? c0[2 * jj + 1] : c1[2 * jj - 3];
            float x0 = bf2f((unsigned short)va[2 * jj]) + bf2f((unsigned short)vb[2 * jj]) + n2v * w0;
            float x1 = bf2f((unsigned short)va[2 * jj + 1]) + bf2f((unsigned short)vb[2 * jj + 1]) + n2v * w1;
            mu[jj] = cvt_pk_bf16(swish_fast(x0), swish_fast(x1));
        }
        s16x8 m = __builtin_bit_cast(s16x8, mu);
        s16x8 bh = *(const s16x8*)(sWh + (ks * 64 + lane) * 8);
        s16x8 bl = *(const s16x8*)(sWl + (ks * 64 + lane) * 8);
        acc = __builtin_amdgcn_mfma_f32_16x16x32_bf16(m, bh, acc, 0, 0, 0);
        acc = __builtin_amdgcn_mfma_f32_16x16x32_bf16(m, bl, acc, 0, 0, 0);
    }

    int col = lane & 15;
    float b2 = bm2l[col];
#pragma unroll
    for (int i = 0; i < 4; ++i) {
        int e = ebase + (lane >> 4) * 4 + i;
        float v = swish_fast(acc[i] + b2);
        unsafeAtomicAdd(&agg[(size_t)dstS[e] * 16 + col], v);
    }
}

// ---------------- readout ----------------
__global__ void readout(const float* __restrict__ pooled, const float* __restrict__ Wr1,
                        const float* __restrict__ br1, const float* __restrict__ Wr2,
                        const float* __restrict__ br2, float* __restrict__ out) {
    __shared__ float row[128];
    __shared__ float tt[128];
    int g = blockIdx.x;
    int t = threadIdx.x;
    row[t] = pooled[g * 128 + t];
    __syncthreads();
    float s = br1[t];
    for (int k = 0; k < 128; ++k) s += row[k] * Wr1[k * 128 + t];
    tt[t] = swish_fast(s);
    __syncthreads();
    if (t < 12) {
        float o = br2[t];
        for (int j = 0; j < 128; ++j) o += tt[j] * Wr2[j * 12 + t];
        out[g * 12 + t] = o;
    }
}

extern "C" void kernel_launch(void* const* d_in, const int* in_sizes, int n_in,
                              void* d_out, int out_size, void* d_ws, size_t ws_size,
                              hipStream_t stream) {
    const float* pos = (const float*)d_in[0];
    const int* z = (const int*)d_in[1];
    const int* ei = (const int*)d_in[2];
    const int* batch = (const int*)d_in[3];
    const float* emb = (const float*)d_in[4];
    const float* Wm1 = (const float*)d_in[5];
    const float* bm1 = (const float*)d_in[6];
    const float* Wm2 = (const float*)d_in[7];
    const float* bm2 = (const float*)d_in[8];
    const float* Wu1 = (const float*)d_in[9];
    const float* bu1 = (const float*)d_in[10];
    const float* Wu2 = (const float*)d_in[11];
    const float* bu2 = (const float*)d_in[12];
    const float* Wp1 = (const float*)d_in[13];
    const float* bp1v = (const float*)d_in[14];
    const float* Wp2 = (const float*)d_in[15];
    const float* bp2v = (const float*)d_in[16];
    const float* Wr1 = (const float*)d_in[17];
    const float* br1 = (const float*)d_in[18];
    const float* Wr2 = (const float*)d_in[19];
    const float* br2 = (const float*)d_in[20];

    const int N = in_sizes[0] / 3;   // 50000
    const int E = in_sizes[2] / 2;   // 800000
    const int G = out_size / 12;     // 1000
    const int* src = ei;
    const int* dstp = ei + E;

    char* ws = (char*)d_ws;
    size_t off = 0;
    auto alloc = [&](size_t bytes) -> char* {
        char* p = ws + off;
        off += (bytes + 255) & ~(size_t)255;
        return p;
    };
    unsigned short* TAB = (unsigned short*)alloc((size_t)N * 1088 * 2);
    float* hf = (float*)alloc((size_t)N * 128 * 4);
    unsigned short* hhi = (unsigned short*)alloc((size_t)N * 128 * 2);
    unsigned short* hlo = (unsigned short*)alloc((size_t)N * 128 * 2);
    float* agg = (float*)alloc((size_t)N * 16 * 4);
    float* pooled = (float*)alloc((size_t)G * 128 * 4);
    int* hist = (int*)alloc((size_t)N * 4);
    int* cursor = (int*)alloc((size_t)N * 4);
    int* perm = (int*)alloc((size_t)E * 4);
    int* srcS = (int*)alloc((size_t)E * 4);
    int* dstS = (int*)alloc((size_t)E * 4);
    float* n2S = (float*)alloc((size_t)E * 4);
    unsigned short* Bp1h = (unsigned short*)alloc(139264 * 2);
    unsigned short* Bp1l = (unsigned short*)alloc(139264 * 2);
    float* bias1088 = (float*)alloc(1088 * 4);
    float* w1cf = (float*)alloc(544 * 4);
    unsigned short* W2ph = (unsigned short*)alloc(8704 * 2);
    unsigned short* W2pl = (unsigned short*)alloc(8704 * 2);
    unsigned short* BpU1h = (unsigned short*)alloc(40960 * 2);
    unsigned short* BpU1l = (unsigned short*)alloc(40960 * 2);
    unsigned short* BpU2h = (unsigned short*)alloc(32768 * 2);
    unsigned short* BpU2l = (unsigned short*)alloc(32768 * 2);
    unsigned short* BpP1h = (unsigned short*)alloc(16384 * 2);
    unsigned short* BpP1l = (unsigned short*)alloc(16384 * 2);
    unsigned short* BpP2h = (unsigned short*)alloc(16384 * 2);
    unsigned short* BpP2l = (unsigned short*)alloc(16384 * 2);

    // Aliases inside the TAB region (dead between edge_kernel and next table GEMM):
    unsigned short* xhi = TAB;
    unsigned short* xlo = TAB + (size_t)N * 160;
    unsigned short* uhi = TAB + (size_t)N * 320;
    unsigned short* ulo = TAB + (size_t)N * 576;
    unsigned short* t1hi = TAB;
    unsigned short* t1lo = TAB + (size_t)N * 128;

    init_nodes<<<(N * 128) / 256, 256, 0, stream>>>(z, emb, hf, hhi, hlo, N);

    // one-time: counting sort of edges by dst
    hipMemsetAsync(hist, 0, (size_t)N * 4, stream);
    hist_kernel<<<(E + 255) / 256, 256, 0, stream>>>(dstp, hist, E);
    scan_kernel<<<1, 256, 0, stream>>>(hist, cursor, N);
    scatter_kernel<<<(E + 255) / 256, 256, 0, stream>>>(dstp, cursor, perm, E);
    reorder_kernel<<<(E + 255) / 256, 256, 0, stream>>>(perm, src, dstp, pos, srcS, dstS, n2S, E);

    for (int l = 0; l < 7; ++l) {
        pack_msg1<<<139264 / 256, 256, 0, stream>>>(
            Wm1 + (size_t)l * 257 * 514, bm1 + (size_t)l * 514, Wm2 + (size_t)l * 514 * 16,
            Bp1h, Bp1l, bias1088, w1cf, W2ph, W2pl);
        tab_gemm<<<(N / 16 + 3) / 4, 256, 0, stream>>>(
            hhi, hlo, Bp1h, Bp1l, bias1088, TAB, N);
        hipMemsetAsync(agg, 0, (size_t)N * 16 * 4, stream);
        edge_kernel<<<E / 64, 256, 0, stream>>>(TAB, w1cf, W2ph, W2pl, bm2 + l * 16,
                                                srcS, dstS, n2S, agg);
        pack_x<<<(N * 160) / 256, 256, 0, stream>>>(agg, hf, xhi, xlo, N);
        pack_generic<<<(160 * 256) / 256, 256, 0, stream>>>(
            Wu1 + (size_t)l * 144 * 256, 144, 256, BpU1h, BpU1l);
        gemm16<<<dim3(N / 16, 4), 256, 0, stream>>>(
            xhi, xlo, 160, BpU1h, BpU1l, bu1 + l * 256, 5, 16, 1,
            uhi, ulo, 256, nullptr, 0, nullptr, nullptr, nullptr);
        pack_generic<<<(256 * 128) / 256, 256, 0, stream>>>(
            Wu2 + (size_t)l * 256 * 128, 256, 128, BpU2h, BpU2l);
        gemm16<<<dim3(N / 16, 2), 256, 0, stream>>>(
            uhi, ulo, 256, BpU2h, BpU2l, bu2 + l * 128, 8, 8, 2,
            hhi, hlo, 128, hf, 128, hf, nullptr, nullptr);
    }

    pack_generic<<<(128 * 128) / 256, 256, 0, stream>>>(Wp1, 128, 128, BpP1h, BpP1l);
    gemm16<<<dim3(N / 16, 2), 256, 0, stream>>>(
        hhi, hlo, 128, BpP1h, BpP1l, bp1v, 4, 8, 1,
        t1hi, t1lo, 128, nullptr, 0, nullptr, nullptr, nullptr);
    pack_generic<<<(128 * 128) / 256, 256, 0, stream>>>(Wp2, 128, 128, BpP2h, BpP2l);
    hipMemsetAsync(pooled, 0, (size_t)G * 128 * 4, stream);
    gemm16<<<dim3(N / 16, 2), 256, 0, stream>>>(
        t1hi, t1lo, 128, BpP2h, BpP2l, bp2v, 4, 8, 3,
        nullptr, nullptr, 0, nullptr, 0, nullptr, batch, pooled);
    readout<<<G, 128, 0, stream>>>(pooled, Wr1, br1, Wr2, br2, (float*)d_out);
}

// Round 7
// 3997.132 us; speedup vs baseline: 1.9357x; 1.0567x over previous
//
#include <hip/hip_runtime.h>
#include <hip/hip_bf16.h>
#include <cstdint>
#include <cstddef>

typedef short s16x8 __attribute__((ext_vector_type(8)));
typedef float f32x4 __attribute__((ext_vector_type(4)));
typedef unsigned int u32x4 __attribute__((ext_vector_type(4)));

__device__ __forceinline__ unsigned short f2bf(float f) {
    unsigned int u = __float_as_uint(f);
    unsigned int r = (u + 0x7FFFu + ((u >> 16) & 1u)) >> 16;
    return (unsigned short)r;
}
__device__ __forceinline__ float bf2f(unsigned short s) {
    return __uint_as_float(((unsigned int)s) << 16);
}
__device__ __forceinline__ void splitbf(float v, unsigned short& hi, unsigned short& lo) {
    hi = f2bf(v);
    lo = f2bf(v - bf2f(hi));
}
// fast swish: x * rcp(1+exp(-x)); v_rcp_f32 rel-err ~1e-7 << bf16 ulp
__device__ __forceinline__ float swish_fast(float x) {
    float e = __expf(-x);
    return x * __builtin_amdgcn_rcpf(1.0f + e);
}
// pack 2 f32 -> 2 bf16 (RNE) in one instruction
__device__ __forceinline__ unsigned int cvt_pk_bf16(float lo, float hi) {
    unsigned int r;
    asm("v_cvt_pk_bf16_f32 %0, %1, %2" : "=v"(r) : "v"(lo), "v"(hi));
    return r;
}

// ---------------- init: h = emb[atomic[z]] ----------------
__global__ void init_nodes(const int* __restrict__ z, const float* __restrict__ emb,
                           float* __restrict__ hf, unsigned short* __restrict__ hhi,
                           unsigned short* __restrict__ hlo, int N) {
    int tid = blockIdx.x * 256 + threadIdx.x;
    int n = tid >> 7, f = tid & 127;
    int zv = z[n];
    int idx5 = (zv == 1) ? 0 : (zv - 5);
    float v = emb[idx5 * 128 + f];
    hf[tid] = v;
    unsigned short hi, lo;
    splitbf(v, hi, lo);
    hhi[tid] = hi;
    hlo[tid] = lo;
}

// ---------------- edge preprocessing: counting sort by dst ----------------
__global__ void hist_kernel(const int* __restrict__ dst, int* __restrict__ hist, int E) {
    int e = blockIdx.x * 256 + threadIdx.x;
    if (e < E) atomicAdd(&hist[dst[e]], 1);
}

__global__ void scan_kernel(const int* __restrict__ hist, int* __restrict__ cursor, int N) {
    __shared__ int part[256];
    int t = threadIdx.x;
    int chunk = (N + 255) / 256;
    int base = t * chunk;
    int s = 0;
    for (int i = 0; i < chunk; ++i) {
        int idx = base + i;
        if (idx < N) s += hist[idx];
    }
    part[t] = s;
    __syncthreads();
    for (int d = 1; d < 256; d <<= 1) {
        int v = 0;
        if (t >= d) v = part[t - d];
        __syncthreads();
        part[t] += v;
        __syncthreads();
    }
    int run = part[t] - s;  // exclusive prefix of this thread's chunk
    for (int i = 0; i < chunk; ++i) {
        int idx = base + i;
        if (idx < N) {
            cursor[idx] = run;
            run += hist[idx];
        }
    }
}

__global__ void scatter_kernel(const int* __restrict__ dst, int* __restrict__ cursor,
                               int* __restrict__ perm, int E) {
    int e = blockIdx.x * 256 + threadIdx.x;
    if (e < E) {
        int p = atomicAdd(&cursor[dst[e]], 1);
        perm[p] = e;
    }
}

__global__ void reorder_kernel(const int* __restrict__ perm, const int* __restrict__ src,
                               const int* __restrict__ dst, const float* __restrict__ pos,
                               int* __restrict__ srcS, int* __restrict__ dstS,
                               float* __restrict__ n2S, int E) {
    int i = blockIdx.x * 256 + threadIdx.x;
    if (i >= E) return;
    int e = perm[i];
    int si = src[e], di = dst[e];
    srcS[i] = si;
    dstS[i] = di;
    float dx = pos[si * 3 + 0] - pos[di * 3 + 0];
    float dy = pos[si * 3 + 1] - pos[di * 3 + 1];
    float dz = pos[si * 3 + 2] - pos[di * 3 + 2];
    n2S[i] = dx * dx + dy * dy + dz * dz;
}

// ---------------- pack W_msg1 + W_msg2 for layer l (hi/lo) ----------------
__global__ void pack_msg1(const float* __restrict__ Wm1l, const float* __restrict__ bm1l,
                          const float* __restrict__ Wm2l,
                          unsigned short* __restrict__ Bp1h, unsigned short* __restrict__ Bp1l,
                          float* __restrict__ bias1088, float* __restrict__ w1cf,
                          unsigned short* __restrict__ W2ph, unsigned short* __restrict__ W2pl) {
    int t = blockIdx.x * 256 + threadIdx.x;
    int i = t & 7;
    int lane = (t >> 3) & 63;
    int rest = t >> 9;
    int cb = rest % 68;
    int ks = rest / 68;
    int k = ks * 32 + ((lane >> 4) << 3) + i;  // 0..127
    int ch = cb * 16 + (lane & 15);            // 0..1087
    float val;
    if (ch < 544) {
        val = (ch < 514) ? Wm1l[k * 514 + ch] : 0.f;
    } else {
        int c = ch - 544;
        val = (c < 514) ? Wm1l[(128 + k) * 514 + c] : 0.f;
    }
    unsigned short hi, lo;
    splitbf(val, hi, lo);
    Bp1h[t] = hi;
    Bp1l[t] = lo;
    if (t < 1088) bias1088[t] = (t < 514) ? bm1l[t] : 0.f;
    if (t < 544) w1cf[t] = (t < 514) ? Wm1l[256 * 514 + t] : 0.f;
    if (t < 8704) {
        int i2 = t & 7, lane2 = (t >> 3) & 63, ks2 = t >> 9;
        int k2 = ks2 * 32 + ((lane2 >> 4) << 3) + i2;
        int c2 = lane2 & 15;
        float v2 = (k2 < 514) ? Wm2l[k2 * 16 + c2] : 0.f;
        unsigned short h2, l2;
        splitbf(v2, h2, l2);
        W2ph[t] = h2;
        W2pl[t] = l2;
    }
}

// ---------------- generic B packer: W[K][Nc] fp32 -> frag layout hi/lo ----------------
__global__ void pack_generic(const float* __restrict__ W, int K, int Nc,
                             unsigned short* __restrict__ Bph, unsigned short* __restrict__ Bpl) {
    int t = blockIdx.x * 256 + threadIdx.x;
    int i = t & 7;
    int lane = (t >> 3) & 63;
    int rest = t >> 9;
    int CB = Nc >> 4;
    int cb = rest % CB;
    int ks = rest / CB;
    int k = ks * 32 + ((lane >> 4) << 3) + i;
    int c = cb * 16 + (lane & 15);
    float val = (k < K) ? W[(size_t)k * Nc + c] : 0.f;
    unsigned short hi, lo;
    splitbf(val, hi, lo);
    Bph[t] = hi;
    Bpl[t] = lo;
}

// ---------------- pack x = [agg(16) | h(128) | 0(16)] hi/lo ----------------
__global__ void pack_x(const float* __restrict__ agg, const float* __restrict__ hf,
                       unsigned short* __restrict__ xhi, unsigned short* __restrict__ xlo, int N) {
    int t = blockIdx.x * 256 + threadIdx.x;
    int n = t / 160, c = t % 160;
    float val;
    if (c < 16) val = agg[n * 16 + c];
    else if (c < 144) val = hf[n * 128 + (c - 16)];
    else val = 0.f;
    unsigned short hi, lo;
    splitbf(val, hi, lo);
    xhi[t] = hi;
    xlo[t] = lo;
}

// ---------------- specialized table GEMM: A(K=128) in regs, loop 68 col-blocks ----------------
__global__ __launch_bounds__(256) void tab_gemm(
    const unsigned short* __restrict__ Ahi, const unsigned short* __restrict__ Alo,
    const unsigned short* __restrict__ Bph, const unsigned short* __restrict__ Bpl,
    const float* __restrict__ bias, unsigned short* __restrict__ TAB, int N) {
    int lane = threadIdx.x & 63;
    int wid = threadIdx.x >> 6;
    int row0 = blockIdx.x * 64 + wid * 16;
    if (row0 >= N) return;
    const size_t arow = (size_t)(row0 + (lane & 15)) * 128;
    const int ak = (lane >> 4) * 8;
    s16x8 ah[4], al[4];
#pragma unroll
    for (int ks = 0; ks < 4; ++ks) {
        ah[ks] = *(const s16x8*)(Ahi + arow + ks * 32 + ak);
        al[ks] = *(const s16x8*)(Alo + arow + ks * 32 + ak);
    }
    int col16 = lane & 15;
    int rb = (lane >> 4) * 4;
    for (int cb = 0; cb < 68; ++cb) {
        f32x4 acc = {0.f, 0.f, 0.f, 0.f};
#pragma unroll
        for (int ks = 0; ks < 4; ++ks) {
            size_t bidx = ((size_t)(ks * 68 + cb) * 64 + lane) * 8;
            s16x8 bh = *(const s16x8*)(Bph + bidx);
            s16x8 bl = *(const s16x8*)(Bpl + bidx);
            acc = __builtin_amdgcn_mfma_f32_16x16x32_bf16(ah[ks], bh, acc, 0, 0, 0);
            acc = __builtin_amdgcn_mfma_f32_16x16x32_bf16(al[ks], bh, acc, 0, 0, 0);
            acc = __builtin_amdgcn_mfma_f32_16x16x32_bf16(ah[ks], bl, acc, 0, 0, 0);
        }
        float bv = bias[cb * 16 + col16];
#pragma unroll
        for (int i = 0; i < 4; ++i) {
            TAB[(size_t)(row0 + rb + i) * 1088 + cb * 16 + col16] = f2bf(acc[i] + bv);
        }
    }
}

// ---------------- generic 64-row A-in-regs GEMM, split precision ----------------
// MODE 1: swish(acc+bias) -> outB (hi), outB2 (lo)
// MODE 2: h = acc+bias+resid; outF=h (f32), outB/outB2 = hi/lo
// MODE 3: atomicAdd(pooled[batch[row]*128+col], acc+bias)
template <int KS, int CB, int MODE>
__global__ __launch_bounds__(256) void gemmA(
    const unsigned short* __restrict__ Ahi, const unsigned short* __restrict__ Alo, int lda,
    const unsigned short* __restrict__ Bph, const unsigned short* __restrict__ Bpl,
    const float* __restrict__ bias,
    unsigned short* __restrict__ outB, unsigned short* __restrict__ outB2, int ldoB,
    float* __restrict__ outF, int ldoF, const float* __restrict__ resid,
    const int* __restrict__ batch, float* __restrict__ pooled, int N) {
    int lane = threadIdx.x & 63;
    int wid = threadIdx.x >> 6;
    int row0 = blockIdx.x * 64 + wid * 16;
    if (row0 >= N) return;
    const size_t arow = (size_t)(row0 + (lane & 15)) * lda;
    const int ak = (lane >> 4) * 8;
    s16x8 ah[KS], al[KS];
#pragma unroll
    for (int ks = 0; ks < KS; ++ks) {
        ah[ks] = *(const s16x8*)(Ahi + arow + ks * 32 + ak);
        al[ks] = *(const s16x8*)(Alo + arow + ks * 32 + ak);
    }
    int col16 = lane & 15;
    int rb = (lane >> 4) * 4;
    for (int cb = 0; cb < CB; ++cb) {
        f32x4 acc = {0.f, 0.f, 0.f, 0.f};
#pragma unroll
        for (int ks = 0; ks < KS; ++ks) {
            size_t bidx = ((size_t)(ks * CB + cb) * 64 + lane) * 8;
            s16x8 bh = *(const s16x8*)(Bph + bidx);
            s16x8 bl = *(const s16x8*)(Bpl + bidx);
            acc = __builtin_amdgcn_mfma_f32_16x16x32_bf16(ah[ks], bh, acc, 0, 0, 0);
            acc = __builtin_amdgcn_mfma_f32_16x16x32_bf16(al[ks], bh, acc, 0, 0, 0);
            acc = __builtin_amdgcn_mfma_f32_16x16x32_bf16(ah[ks], bl, acc, 0, 0, 0);
        }
        int col = cb * 16 + col16;
        float bv = bias[col];
#pragma unroll
        for (int i = 0; i < 4; ++i) {
            int row = row0 + rb + i;
            float v = acc[i] + bv;
            if (MODE == 1) {
                float s = swish_fast(v);
                unsigned short hi, lo;
                splitbf(s, hi, lo);
                outB[(size_t)row * ldoB + col] = hi;
                outB2[(size_t)row * ldoB + col] = lo;
            } else if (MODE == 2) {
                float h = v + resid[(size_t)row * ldoF + col];
                outF[(size_t)row * ldoF + col] = h;
                unsigned short hi, lo;
                splitbf(h, hi, lo);
                outB[(size_t)row * ldoB + col] = hi;
                outB2[(size_t)row * ldoB + col] = lo;
            } else {
                unsafeAtomicAdd(&pooled[(size_t)batch[row] * 128 + col], v);
            }
        }
    }
}

// ---------------- edge kernel: LDS-free gather, W2 frags from L1/L2 ----------------
__global__ __launch_bounds__(256) void edge_kernel(
    const unsigned short* __restrict__ TAB, const float* __restrict__ w1cf,
    const unsigned short* __restrict__ W2ph, const unsigned short* __restrict__ W2pl,
    const float* __restrict__ bm2l,
    const int* __restrict__ srcS, const int* __restrict__ dstS,
    const float* __restrict__ n2S, float* __restrict__ agg) {
    __shared__ float sw1[544];
    for (int t = threadIdx.x; t < 544; t += 256) sw1[t] = w1cf[t];
    __syncthreads();

    int lane = threadIdx.x & 63;
    int wid = threadIdx.x >> 6;
    int ebase = blockIdx.x * 64 + wid * 16;
    int er = ebase + (lane & 15);
    int di = dstS[er], si = srcS[er];
    float n2v = n2S[er];
    const int ak = (lane >> 4) * 8;
    const unsigned short* pa = TAB + (size_t)di * 1088 + ak;
    const unsigned short* pb = TAB + (size_t)si * 1088 + 544 + ak;

    f32x4 acc = {0.f, 0.f, 0.f, 0.f};
    for (int ks = 0; ks < 17; ++ks) {
        s16x8 va = *(const s16x8*)(pa + ks * 32);
        s16x8 vb = *(const s16x8*)(pb + ks * 32);
        f32x4 c0 = *(const f32x4*)(sw1 + ks * 32 + ak);
        f32x4 c1 = *(const f32x4*)(sw1 + ks * 32 + ak + 4);
        u32x4 mu;
#pragma unroll
        for (int jj = 0; jj < 4; ++jj) {
            float w0 = (jj < 2) ? c0[2 * jj] : c1[2 * jj - 4];
            float w1 = (jj < 2) ? c0[2 * jj + 1] : c1[2 * jj - 3];
            float x0 = bf2f((unsigned short)va[2 * jj]) + bf2f((unsigned short)vb[2 * jj]) + n2v * w0;
            float x1 = bf2f((unsigned short)va[2 * jj + 1]) + bf2f((unsigned short)vb[2 * jj + 1]) + n2v * w1;
            mu[jj] = cvt_pk_bf16(swish_fast(x0), swish_fast(x1));
        }
        s16x8 m = __builtin_bit_cast(s16x8, mu);
        s16x8 bh = *(const s16x8*)(W2ph + (ks * 64 + lane) * 8);
        s16x8 bl = *(const s16x8*)(W2pl + (ks * 64 + lane) * 8);
        acc = __builtin_amdgcn_mfma_f32_16x16x32_bf16(m, bh, acc, 0, 0, 0);
        acc = __builtin_amdgcn_mfma_f32_16x16x32_bf16(m, bl, acc, 0, 0, 0);
    }

    int col = lane & 15;
    float b2 = bm2l[col];
#pragma unroll
    for (int i = 0; i < 4; ++i) {
        int e = ebase + (lane >> 4) * 4 + i;
        float v = swish_fast(acc[i] + b2);
        unsafeAtomicAdd(&agg[(size_t)dstS[e] * 16 + col], v);
    }
}

// ---------------- readout ----------------
__global__ void readout(const float* __restrict__ pooled, const float* __restrict__ Wr1,
                        const float* __restrict__ br1, const float* __restrict__ Wr2,
                        const float* __restrict__ br2, float* __restrict__ out) {
    __shared__ float row[128];
    __shared__ float tt[128];
    int g = blockIdx.x;
    int t = threadIdx.x;
    row[t] = pooled[g * 128 + t];
    __syncthreads();
    float s = br1[t];
    for (int k = 0; k < 128; ++k) s += row[k] * Wr1[k * 128 + t];
    tt[t] = swish_fast(s);
    __syncthreads();
    if (t < 12) {
        float o = br2[t];
        for (int j = 0; j < 128; ++j) o += tt[j] * Wr2[j * 12 + t];
        out[g * 12 + t] = o;
    }
}

extern "C" void kernel_launch(void* const* d_in, const int* in_sizes, int n_in,
                              void* d_out, int out_size, void* d_ws, size_t ws_size,
                              hipStream_t stream) {
    const float* pos = (const float*)d_in[0];
    const int* z = (const int*)d_in[1];
    const int* ei = (const int*)d_in[2];
    const int* batch = (const int*)d_in[3];
    const float* emb = (const float*)d_in[4];
    const float* Wm1 = (const float*)d_in[5];
    const float* bm1 = (const float*)d_in[6];
    const float* Wm2 = (const float*)d_in[7];
    const float* bm2 = (const float*)d_in[8];
    const float* Wu1 = (const float*)d_in[9];
    const float* bu1 = (const float*)d_in[10];
    const float* Wu2 = (const float*)d_in[11];
    const float* bu2 = (const float*)d_in[12];
    const float* Wp1 = (const float*)d_in[13];
    const float* bp1v = (const float*)d_in[14];
    const float* Wp2 = (const float*)d_in[15];
    const float* bp2v = (const float*)d_in[16];
    const float* Wr1 = (const float*)d_in[17];
    const float* br1 = (const float*)d_in[18];
    const float* Wr2 = (const float*)d_in[19];
    const float* br2 = (const float*)d_in[20];

    const int N = in_sizes[0] / 3;   // 50000
    const int E = in_sizes[2] / 2;   // 800000
    const int G = out_size / 12;     // 1000
    const int* src = ei;
    const int* dstp = ei + E;

    char* ws = (char*)d_ws;
    size_t off = 0;
    auto alloc = [&](size_t bytes) -> char* {
        char* p = ws + off;
        off += (bytes + 255) & ~(size_t)255;
        return p;
    };
    unsigned short* TAB = (unsigned short*)alloc((size_t)N * 1088 * 2);
    float* hf = (float*)alloc((size_t)N * 128 * 4);
    unsigned short* hhi = (unsigned short*)alloc((size_t)N * 128 * 2);
    unsigned short* hlo = (unsigned short*)alloc((size_t)N * 128 * 2);
    float* agg = (float*)alloc((size_t)N * 16 * 4);
    float* pooled = (float*)alloc((size_t)G * 128 * 4);
    int* hist = (int*)alloc((size_t)N * 4);
    int* cursor = (int*)alloc((size_t)N * 4);
    int* perm = (int*)alloc((size_t)E * 4);
    int* srcS = (int*)alloc((size_t)E * 4);
    int* dstS = (int*)alloc((size_t)E * 4);
    float* n2S = (float*)alloc((size_t)E * 4);
    unsigned short* Bp1h = (unsigned short*)alloc(139264 * 2);
    unsigned short* Bp1l = (unsigned short*)alloc(139264 * 2);
    float* bias1088 = (float*)alloc(1088 * 4);
    float* w1cf = (float*)alloc(544 * 4);
    unsigned short* W2ph = (unsigned short*)alloc(8704 * 2);
    unsigned short* W2pl = (unsigned short*)alloc(8704 * 2);
    unsigned short* BpU1h = (unsigned short*)alloc(40960 * 2);
    unsigned short* BpU1l = (unsigned short*)alloc(40960 * 2);
    unsigned short* BpU2h = (unsigned short*)alloc(32768 * 2);
    unsigned short* BpU2l = (unsigned short*)alloc(32768 * 2);
    unsigned short* BpP1h = (unsigned short*)alloc(16384 * 2);
    unsigned short* BpP1l = (unsigned short*)alloc(16384 * 2);
    unsigned short* BpP2h = (unsigned short*)alloc(16384 * 2);
    unsigned short* BpP2l = (unsigned short*)alloc(16384 * 2);

    // Aliases inside the TAB region (dead between edge_kernel and next table GEMM):
    unsigned short* xhi = TAB;
    unsigned short* xlo = TAB + (size_t)N * 160;
    unsigned short* uhi = TAB + (size_t)N * 320;
    unsigned short* ulo = TAB + (size_t)N * 576;
    unsigned short* t1hi = TAB;
    unsigned short* t1lo = TAB + (size_t)N * 128;

    init_nodes<<<(N * 128) / 256, 256, 0, stream>>>(z, emb, hf, hhi, hlo, N);

    // one-time: counting sort of edges by dst
    hipMemsetAsync(hist, 0, (size_t)N * 4, stream);
    hist_kernel<<<(E + 255) / 256, 256, 0, stream>>>(dstp, hist, E);
    scan_kernel<<<1, 256, 0, stream>>>(hist, cursor, N);
    scatter_kernel<<<(E + 255) / 256, 256, 0, stream>>>(dstp, cursor, perm, E);
    reorder_kernel<<<(E + 255) / 256, 256, 0, stream>>>(perm, src, dstp, pos, srcS, dstS, n2S, E);

    const int gA = (N + 63) / 64;
    for (int l = 0; l < 7; ++l) {
        pack_msg1<<<139264 / 256, 256, 0, stream>>>(
            Wm1 + (size_t)l * 257 * 514, bm1 + (size_t)l * 514, Wm2 + (size_t)l * 514 * 16,
            Bp1h, Bp1l, bias1088, w1cf, W2ph, W2pl);
        tab_gemm<<<gA, 256, 0, stream>>>(
            hhi, hlo, Bp1h, Bp1l, bias1088, TAB, N);
        hipMemsetAsync(agg, 0, (size_t)N * 16 * 4, stream);
        edge_kernel<<<E / 64, 256, 0, stream>>>(TAB, w1cf, W2ph, W2pl, bm2 + l * 16,
                                                srcS, dstS, n2S, agg);
        pack_x<<<(N * 160) / 256, 256, 0, stream>>>(agg, hf, xhi, xlo, N);
        pack_generic<<<(160 * 256) / 256, 256, 0, stream>>>(
            Wu1 + (size_t)l * 144 * 256, 144, 256, BpU1h, BpU1l);
        gemmA<5, 16, 1><<<gA, 256, 0, stream>>>(
            xhi, xlo, 160, BpU1h, BpU1l, bu1 + l * 256,
            uhi, ulo, 256, nullptr, 0, nullptr, nullptr, nullptr, N);
        pack_generic<<<(256 * 128) / 256, 256, 0, stream>>>(
            Wu2 + (size_t)l * 256 * 128, 256, 128, BpU2h, BpU2l);
        gemmA<8, 8, 2><<<gA, 256, 0, stream>>>(
            uhi, ulo, 256, BpU2h, BpU2l, bu2 + l * 128,
            hhi, hlo, 128, hf, 128, hf, nullptr, nullptr, N);
    }

    pack_generic<<<(128 * 128) / 256, 256, 0, stream>>>(Wp1, 128, 128, BpP1h, BpP1l);
    gemmA<4, 8, 1><<<gA, 256, 0, stream>>>(
        hhi, hlo, 128, BpP1h, BpP1l, bp1v,
        t1hi, t1lo, 128, nullptr, 0, nullptr, nullptr, nullptr, N);
    pack_generic<<<(128 * 128) / 256, 256, 0, stream>>>(Wp2, 128, 128, BpP2h, BpP2l);
    hipMemsetAsync(pooled, 0, (size_t)G * 128 * 4, stream);
    gemmA<4, 8, 3><<<gA, 256, 0, stream>>>(
        t1hi, t1lo, 128, BpP2h, BpP2l, bp2v,
        nullptr, nullptr, 0, nullptr, 0, nullptr, batch, pooled, N);
    readout<<<G, 128, 0, stream>>>(pooled, Wr1, br1, Wr2, br2, (float*)d_out);
}

// Round 8
// 3610.674 us; speedup vs baseline: 2.1429x; 1.1070x over previous
//
#include <hip/hip_runtime.h>
#include <hip/hip_bf16.h>
#include <cstdint>
#include <cstddef>

typedef short s16x8 __attribute__((ext_vector_type(8)));
typedef float f32x4 __attribute__((ext_vector_type(4)));
typedef unsigned int u32x4 __attribute__((ext_vector_type(4)));

__device__ __forceinline__ unsigned short f2bf(float f) {
    unsigned int u = __float_as_uint(f);
    unsigned int r = (u + 0x7FFFu + ((u >> 16) & 1u)) >> 16;
    return (unsigned short)r;
}
__device__ __forceinline__ float bf2f(unsigned short s) {
    return __uint_as_float(((unsigned int)s) << 16);
}
__device__ __forceinline__ void splitbf(float v, unsigned short& hi, unsigned short& lo) {
    hi = f2bf(v);
    lo = f2bf(v - bf2f(hi));
}
// fast swish: x * rcp(1+exp(-x)); v_rcp_f32 rel-err ~1e-7 << bf16 ulp
__device__ __forceinline__ float swish_fast(float x) {
    float e = __expf(-x);
    return x * __builtin_amdgcn_rcpf(1.0f + e);
}
// pack 2 f32 -> 2 bf16 (RNE) in one instruction
__device__ __forceinline__ unsigned int cvt_pk_bf16(float lo, float hi) {
    unsigned int r;
    asm("v_cvt_pk_bf16_f32 %0, %1, %2" : "=v"(r) : "v"(lo), "v"(hi));
    return r;
}

// ---------------- init: h = emb[atomic[z]] ----------------
__global__ void init_nodes(const int* __restrict__ z, const float* __restrict__ emb,
                           float* __restrict__ hf, unsigned short* __restrict__ hhi,
                           unsigned short* __restrict__ hlo, int N) {
    int tid = blockIdx.x * 256 + threadIdx.x;
    int n = tid >> 7, f = tid & 127;
    int zv = z[n];
    int idx5 = (zv == 1) ? 0 : (zv - 5);
    float v = emb[idx5 * 128 + f];
    hf[tid] = v;
    unsigned short hi, lo;
    splitbf(v, hi, lo);
    hhi[tid] = hi;
    hlo[tid] = lo;
}

// ---------------- edge preprocessing: counting sort by dst ----------------
__global__ void hist_kernel(const int* __restrict__ dst, int* __restrict__ hist, int E) {
    int e = blockIdx.x * 256 + threadIdx.x;
    if (e < E) atomicAdd(&hist[dst[e]], 1);
}

__global__ void scan_kernel(const int* __restrict__ hist, int* __restrict__ cursor, int N) {
    __shared__ int part[256];
    int t = threadIdx.x;
    int chunk = (N + 255) / 256;
    int base = t * chunk;
    int s = 0;
    for (int i = 0; i < chunk; ++i) {
        int idx = base + i;
        if (idx < N) s += hist[idx];
    }
    part[t] = s;
    __syncthreads();
    for (int d = 1; d < 256; d <<= 1) {
        int v = 0;
        if (t >= d) v = part[t - d];
        __syncthreads();
        part[t] += v;
        __syncthreads();
    }
    int run = part[t] - s;  // exclusive prefix of this thread's chunk
    for (int i = 0; i < chunk; ++i) {
        int idx = base + i;
        if (idx < N) {
            cursor[idx] = run;
            run += hist[idx];
        }
    }
}

__global__ void scatter_kernel(const int* __restrict__ dst, int* __restrict__ cursor,
                               int* __restrict__ perm, int E) {
    int e = blockIdx.x * 256 + threadIdx.x;
    if (e < E) {
        int p = atomicAdd(&cursor[dst[e]], 1);
        perm[p] = e;
    }
}

__global__ void reorder_kernel(const int* __restrict__ perm, const int* __restrict__ src,
                               const int* __restrict__ dst, const float* __restrict__ pos,
                               int* __restrict__ srcS, int* __restrict__ dstS,
                               float* __restrict__ n2S, int E) {
    int i = blockIdx.x * 256 + threadIdx.x;
    if (i >= E) return;
    int e = perm[i];
    int si = src[e], di = dst[e];
    srcS[i] = si;
    dstS[i] = di;
    float dx = pos[si * 3 + 0] - pos[di * 3 + 0];
    float dy = pos[si * 3 + 1] - pos[di * 3 + 1];
    float dz = pos[si * 3 + 2] - pos[di * 3 + 2];
    n2S[i] = dx * dx + dy * dy + dz * dz;
}

// ---------------- pack W_msg1 + W_msg2 for layer l (hi/lo) ----------------
__global__ void pack_msg1(const float* __restrict__ Wm1l, const float* __restrict__ bm1l,
                          const float* __restrict__ Wm2l,
                          unsigned short* __restrict__ Bp1h, unsigned short* __restrict__ Bp1l,
                          float* __restrict__ bias1088, float* __restrict__ w1cf,
                          unsigned short* __restrict__ W2ph, unsigned short* __restrict__ W2pl) {
    int t = blockIdx.x * 256 + threadIdx.x;
    int i = t & 7;
    int lane = (t >> 3) & 63;
    int rest = t >> 9;
    int cb = rest % 68;
    int ks = rest / 68;
    int k = ks * 32 + ((lane >> 4) << 3) + i;  // 0..127
    int ch = cb * 16 + (lane & 15);            // 0..1087
    float val;
    if (ch < 544) {
        val = (ch < 514) ? Wm1l[k * 514 + ch] : 0.f;
    } else {
        int c = ch - 544;
        val = (c < 514) ? Wm1l[(128 + k) * 514 + c] : 0.f;
    }
    unsigned short hi, lo;
    splitbf(val, hi, lo);
    Bp1h[t] = hi;
    Bp1l[t] = lo;
    if (t < 1088) bias1088[t] = (t < 514) ? bm1l[t] : 0.f;
    if (t < 544) w1cf[t] = (t < 514) ? Wm1l[256 * 514 + t] : 0.f;
    if (t < 8704) {
        int i2 = t & 7, lane2 = (t >> 3) & 63, ks2 = t >> 9;
        int k2 = ks2 * 32 + ((lane2 >> 4) << 3) + i2;
        int c2 = lane2 & 15;
        float v2 = (k2 < 514) ? Wm2l[k2 * 16 + c2] : 0.f;
        unsigned short h2, l2;
        splitbf(v2, h2, l2);
        W2ph[t] = h2;
        W2pl[t] = l2;
    }
}

// ---------------- generic B packer: W[K][Nc] fp32 -> frag layout hi/lo ----------------
__global__ void pack_generic(const float* __restrict__ W, int K, int Nc,
                             unsigned short* __restrict__ Bph, unsigned short* __restrict__ Bpl) {
    int t = blockIdx.x * 256 + threadIdx.x;
    int i = t & 7;
    int lane = (t >> 3) & 63;
    int rest = t >> 9;
    int CB = Nc >> 4;
    int cb = rest % CB;
    int ks = rest / CB;
    int k = ks * 32 + ((lane >> 4) << 3) + i;
    int c = cb * 16 + (lane & 15);
    float val = (k < K) ? W[(size_t)k * Nc + c] : 0.f;
    unsigned short hi, lo;
    splitbf(val, hi, lo);
    Bph[t] = hi;
    Bpl[t] = lo;
}

// ---------------- specialized table GEMM: A(K=128) in regs, loop 68 col-blocks ----------------
__global__ __launch_bounds__(256) void tab_gemm(
    const unsigned short* __restrict__ Ahi, const unsigned short* __restrict__ Alo,
    const unsigned short* __restrict__ Bph, const unsigned short* __restrict__ Bpl,
    const float* __restrict__ bias, unsigned short* __restrict__ TAB, int N) {
    int lane = threadIdx.x & 63;
    int wid = threadIdx.x >> 6;
    int row0 = blockIdx.x * 64 + wid * 16;
    if (row0 >= N) return;
    const size_t arow = (size_t)(row0 + (lane & 15)) * 128;
    const int ak = (lane >> 4) * 8;
    s16x8 ah[4], al[4];
#pragma unroll
    for (int ks = 0; ks < 4; ++ks) {
        ah[ks] = *(const s16x8*)(Ahi + arow + ks * 32 + ak);
        al[ks] = *(const s16x8*)(Alo + arow + ks * 32 + ak);
    }
    int col16 = lane & 15;
    int rb = (lane >> 4) * 4;
    for (int cb = 0; cb < 68; ++cb) {
        f32x4 acc = {0.f, 0.f, 0.f, 0.f};
#pragma unroll
        for (int ks = 0; ks < 4; ++ks) {
            size_t bidx = ((size_t)(ks * 68 + cb) * 64 + lane) * 8;
            s16x8 bh = *(const s16x8*)(Bph + bidx);
            s16x8 bl = *(const s16x8*)(Bpl + bidx);
            acc = __builtin_amdgcn_mfma_f32_16x16x32_bf16(ah[ks], bh, acc, 0, 0, 0);
            acc = __builtin_amdgcn_mfma_f32_16x16x32_bf16(al[ks], bh, acc, 0, 0, 0);
            acc = __builtin_amdgcn_mfma_f32_16x16x32_bf16(ah[ks], bl, acc, 0, 0, 0);
        }
        float bv = bias[cb * 16 + col16];
#pragma unroll
        for (int i = 0; i < 4; ++i) {
            TAB[(size_t)(row0 + rb + i) * 1088 + cb * 16 + col16] = f2bf(acc[i] + bv);
        }
    }
}

// ---------------- generic 64-row A-in-regs GEMM, split precision ----------------
// MODE 1: swish(acc+bias) -> outB (hi), outB2 (lo)
// MODE 2: h = acc+bias+resid; outF=h (f32), outB/outB2 = hi/lo
// MODE 3: atomicAdd(pooled[batch[row]*128+col], acc+bias)
template <int KS, int CB, int MODE>
__global__ __launch_bounds__(256) void gemmA(
    const unsigned short* __restrict__ Ahi, const unsigned short* __restrict__ Alo, int lda,
    const unsigned short* __restrict__ Bph, const unsigned short* __restrict__ Bpl,
    const float* __restrict__ bias,
    unsigned short* __restrict__ outB, unsigned short* __restrict__ outB2, int ldoB,
    float* __restrict__ outF, int ldoF, const float* __restrict__ resid,
    const int* __restrict__ batch, float* __restrict__ pooled, int N) {
    int lane = threadIdx.x & 63;
    int wid = threadIdx.x >> 6;
    int row0 = blockIdx.x * 64 + wid * 16;
    if (row0 >= N) return;
    const size_t arow = (size_t)(row0 + (lane & 15)) * lda;
    const int ak = (lane >> 4) * 8;
    s16x8 ah[KS], al[KS];
#pragma unroll
    for (int ks = 0; ks < KS; ++ks) {
        ah[ks] = *(const s16x8*)(Ahi + arow + ks * 32 + ak);
        al[ks] = *(const s16x8*)(Alo + arow + ks * 32 + ak);
    }
    int col16 = lane & 15;
    int rb = (lane >> 4) * 4;
    for (int cb = 0; cb < CB; ++cb) {
        f32x4 acc = {0.f, 0.f, 0.f, 0.f};
#pragma unroll
        for (int ks = 0; ks < KS; ++ks) {
            size_t bidx = ((size_t)(ks * CB + cb) * 64 + lane) * 8;
            s16x8 bh = *(const s16x8*)(Bph + bidx);
            s16x8 bl = *(const s16x8*)(Bpl + bidx);
            acc = __builtin_amdgcn_mfma_f32_16x16x32_bf16(ah[ks], bh, acc, 0, 0, 0);
            acc = __builtin_amdgcn_mfma_f32_16x16x32_bf16(al[ks], bh, acc, 0, 0, 0);
            acc = __builtin_amdgcn_mfma_f32_16x16x32_bf16(ah[ks], bl, acc, 0, 0, 0);
        }
        int col = cb * 16 + col16;
        float bv = bias[col];
#pragma unroll
        for (int i = 0; i < 4; ++i) {
            int row = row0 + rb + i;
            float v = acc[i] + bv;
            if (MODE == 1) {
                float s = swish_fast(v);
                unsigned short hi, lo;
                splitbf(s, hi, lo);
                outB[(size_t)row * ldoB + col] = hi;
                outB2[(size_t)row * ldoB + col] = lo;
            } else if (MODE == 2) {
                float h = v + resid[(size_t)row * ldoF + col];
                outF[(size_t)row * ldoF + col] = h;
                unsigned short hi, lo;
                splitbf(h, hi, lo);
                outB[(size_t)row * ldoB + col] = hi;
                outB2[(size_t)row * ldoB + col] = lo;
            } else {
                unsafeAtomicAdd(&pooled[(size_t)batch[row] * 128 + col], v);
            }
        }
    }
}

// ---------------- up1 GEMM: A assembled on the fly from agg(f32)+hf(f32) ----------------
// x = [agg(16) | h(128) | 0(16)], KS=5, CB=16; out = swish -> uhi/ulo
__global__ __launch_bounds__(256) void up1_gemm(
    const float* __restrict__ agg, const float* __restrict__ hf,
    const unsigned short* __restrict__ Bph, const unsigned short* __restrict__ Bpl,
    const float* __restrict__ bias,
    unsigned short* __restrict__ uhi, unsigned short* __restrict__ ulo, int N) {
    int lane = threadIdx.x & 63;
    int wid = threadIdx.x >> 6;
    int row0 = blockIdx.x * 64 + wid * 16;
    if (row0 >= N) return;
    int r = row0 + (lane & 15);
    const int ak = (lane >> 4) * 8;
    s16x8 ah[5], al[5];
#pragma unroll
    for (int ks = 0; ks < 5; ++ks) {
        int c0 = ks * 32 + ak;   // 8-chunk fully inside one region (bounds 16,144 are 8-aligned)
        f32x4 v0, v1;
        if (c0 < 16) {
            v0 = *(const f32x4*)(agg + (size_t)r * 16 + c0);
            v1 = *(const f32x4*)(agg + (size_t)r * 16 + c0 + 4);
        } else if (c0 < 144) {
            v0 = *(const f32x4*)(hf + (size_t)r * 128 + c0 - 16);
            v1 = *(const f32x4*)(hf + (size_t)r * 128 + c0 - 12);
        } else {
            v0 = f32x4{0.f, 0.f, 0.f, 0.f};
            v1 = f32x4{0.f, 0.f, 0.f, 0.f};
        }
        u32x4 hiP, loP;
#pragma unroll
        for (int jj = 0; jj < 4; ++jj) {
            float x0 = (jj < 2) ? v0[2 * jj] : v1[2 * jj - 4];
            float x1 = (jj < 2) ? v0[2 * jj + 1] : v1[2 * jj - 3];
            unsigned short h0, l0, h1, l1;
            splitbf(x0, h0, l0);
            splitbf(x1, h1, l1);
            hiP[jj] = (unsigned int)h0 | ((unsigned int)h1 << 16);
            loP[jj] = (unsigned int)l0 | ((unsigned int)l1 << 16);
        }
        ah[ks] = __builtin_bit_cast(s16x8, hiP);
        al[ks] = __builtin_bit_cast(s16x8, loP);
    }
    int col16 = lane & 15;
    int rb = (lane >> 4) * 4;
    for (int cb = 0; cb < 16; ++cb) {
        f32x4 acc = {0.f, 0.f, 0.f, 0.f};
#pragma unroll
        for (int ks = 0; ks < 5; ++ks) {
            size_t bidx = ((size_t)(ks * 16 + cb) * 64 + lane) * 8;
            s16x8 bh = *(const s16x8*)(Bph + bidx);
            s16x8 bl = *(const s16x8*)(Bpl + bidx);
            acc = __builtin_amdgcn_mfma_f32_16x16x32_bf16(ah[ks], bh, acc, 0, 0, 0);
            acc = __builtin_amdgcn_mfma_f32_16x16x32_bf16(al[ks], bh, acc, 0, 0, 0);
            acc = __builtin_amdgcn_mfma_f32_16x16x32_bf16(ah[ks], bl, acc, 0, 0, 0);
        }
        int col = cb * 16 + col16;
        float bv = bias[col];
#pragma unroll
        for (int i = 0; i < 4; ++i) {
            int row = row0 + rb + i;
            float s = swish_fast(acc[i] + bv);
            unsigned short hi, lo;
            splitbf(s, hi, lo);
            uhi[(size_t)row * 256 + col] = hi;
            ulo[(size_t)row * 256 + col] = lo;
        }
    }
}

// ---------------- edge kernel: 32 edges/wave, 3-deep pipelined gather ----------------
__global__ __launch_bounds__(256) void edge_kernel(
    const unsigned short* __restrict__ TAB, const float* __restrict__ w1cf,
    const unsigned short* __restrict__ W2ph, const unsigned short* __restrict__ W2pl,
    const float* __restrict__ bm2l,
    const int* __restrict__ srcS, const int* __restrict__ dstS,
    const float* __restrict__ n2S, float* __restrict__ agg) {
    __shared__ float sw1[544];
    for (int t = threadIdx.x; t < 544; t += 256) sw1[t] = w1cf[t];
    __syncthreads();

    int lane = threadIdx.x & 63;
    int wid = threadIdx.x >> 6;
    int ebase = blockIdx.x * 128 + wid * 32;
    int rr = lane & 15;
    int e0 = ebase + rr;
    int e1 = ebase + 16 + rr;
    int di0 = dstS[e0], si0 = srcS[e0];
    int di1 = dstS[e1], si1 = srcS[e1];
    float n20 = n2S[e0], n21 = n2S[e1];
    const int ak = (lane >> 4) * 8;
    const unsigned short* pa0 = TAB + (size_t)di0 * 1088 + ak;
    const unsigned short* pb0 = TAB + (size_t)si0 * 1088 + 544 + ak;
    const unsigned short* pa1 = TAB + (size_t)di1 * 1088 + ak;
    const unsigned short* pb1 = TAB + (size_t)si1 * 1088 + 544 + ak;

    s16x8 qa0[3], qb0[3], qa1[3], qb1[3];
#pragma unroll
    for (int p = 0; p < 3; ++p) {
        qa0[p] = *(const s16x8*)(pa0 + p * 32);
        qb0[p] = *(const s16x8*)(pb0 + p * 32);
        qa1[p] = *(const s16x8*)(pa1 + p * 32);
        qb1[p] = *(const s16x8*)(pb1 + p * 32);
    }

    f32x4 acc0 = {0.f, 0.f, 0.f, 0.f};
    f32x4 acc1 = {0.f, 0.f, 0.f, 0.f};
#pragma unroll
    for (int ks = 0; ks < 17; ++ks) {
        const int slot = ks % 3;
        s16x8 va0 = qa0[slot], vb0 = qb0[slot];
        s16x8 va1 = qa1[slot], vb1 = qb1[slot];
        if (ks + 3 < 17) {
            qa0[slot] = *(const s16x8*)(pa0 + (ks + 3) * 32);
            qb0[slot] = *(const s16x8*)(pb0 + (ks + 3) * 32);
            qa1[slot] = *(const s16x8*)(pa1 + (ks + 3) * 32);
            qb1[slot] = *(const s16x8*)(pb1 + (ks + 3) * 32);
        }
        f32x4 c0 = *(const f32x4*)(sw1 + ks * 32 + ak);
        f32x4 c1 = *(const f32x4*)(sw1 + ks * 32 + ak + 4);
        u32x4 mu0, mu1;
#pragma unroll
        for (int jj = 0; jj < 4; ++jj) {
            float w0 = (jj < 2) ? c0[2 * jj] : c1[2 * jj - 4];
            float w1 = (jj < 2) ? c0[2 * jj + 1] : c1[2 * jj - 3];
            float x00 = bf2f((unsigned short)va0[2 * jj]) + bf2f((unsigned short)vb0[2 * jj]) + n20 * w0;
            float x01 = bf2f((unsigned short)va0[2 * jj + 1]) + bf2f((unsigned short)vb0[2 * jj + 1]) + n20 * w1;
            mu0[jj] = cvt_pk_bf16(swish_fast(x00), swish_fast(x01));
            float x10 = bf2f((unsigned short)va1[2 * jj]) + bf2f((unsigned short)vb1[2 * jj]) + n21 * w0;
            float x11 = bf2f((unsigned short)va1[2 * jj + 1]) + bf2f((unsigned short)vb1[2 * jj + 1]) + n21 * w1;
            mu1[jj] = cvt_pk_bf16(swish_fast(x10), swish_fast(x11));
        }
        s16x8 m0 = __builtin_bit_cast(s16x8, mu0);
        s16x8 m1 = __builtin_bit_cast(s16x8, mu1);
        s16x8 bh = *(const s16x8*)(W2ph + (ks * 64 + lane) * 8);
        s16x8 bl = *(const s16x8*)(W2pl + (ks * 64 + lane) * 8);
        acc0 = __builtin_amdgcn_mfma_f32_16x16x32_bf16(m0, bh, acc0, 0, 0, 0);
        acc0 = __builtin_amdgcn_mfma_f32_16x16x32_bf16(m0, bl, acc0, 0, 0, 0);
        acc1 = __builtin_amdgcn_mfma_f32_16x16x32_bf16(m1, bh, acc1, 0, 0, 0);
        acc1 = __builtin_amdgcn_mfma_f32_16x16x32_bf16(m1, bl, acc1, 0, 0, 0);
    }

    int col = lane & 15;
    float b2 = bm2l[col];
#pragma unroll
    for (int i = 0; i < 4; ++i) {
        int ea = ebase + (lane >> 4) * 4 + i;
        float v0 = swish_fast(acc0[i] + b2);
        unsafeAtomicAdd(&agg[(size_t)dstS[ea] * 16 + col], v0);
        int eb = ea + 16;
        float v1 = swish_fast(acc1[i] + b2);
        unsafeAtomicAdd(&agg[(size_t)dstS[eb] * 16 + col], v1);
    }
}

// ---------------- readout ----------------
__global__ void readout(const float* __restrict__ pooled, const float* __restrict__ Wr1,
                        const float* __restrict__ br1, const float* __restrict__ Wr2,
                        const float* __restrict__ br2, float* __restrict__ out) {
    __shared__ float row[128];
    __shared__ float tt[128];
    int g = blockIdx.x;
    int t = threadIdx.x;
    row[t] = pooled[g * 128 + t];
    __syncthreads();
    float s = br1[t];
    for (int k = 0; k < 128; ++k) s += row[k] * Wr1[k * 128 + t];
    tt[t] = swish_fast(s);
    __syncthreads();
    if (t < 12) {
        float o = br2[t];
        for (int j = 0; j < 128; ++j) o += tt[j] * Wr2[j * 12 + t];
        out[g * 12 + t] = o;
    }
}

extern "C" void kernel_launch(void* const* d_in, const int* in_sizes, int n_in,
                              void* d_out, int out_size, void* d_ws, size_t ws_size,
                              hipStream_t stream) {
    const float* pos = (const float*)d_in[0];
    const int* z = (const int*)d_in[1];
    const int* ei = (const int*)d_in[2];
    const int* batch = (const int*)d_in[3];
    const float* emb = (const float*)d_in[4];
    const float* Wm1 = (const float*)d_in[5];
    const float* bm1 = (const float*)d_in[6];
    const float* Wm2 = (const float*)d_in[7];
    const float* bm2 = (const float*)d_in[8];
    const float* Wu1 = (const float*)d_in[9];
    const float* bu1 = (const float*)d_in[10];
    const float* Wu2 = (const float*)d_in[11];
    const float* bu2 = (const float*)d_in[12];
    const float* Wp1 = (const float*)d_in[13];
    const float* bp1v = (const float*)d_in[14];
    const float* Wp2 = (const float*)d_in[15];
    const float* bp2v = (const float*)d_in[16];
    const float* Wr1 = (const float*)d_in[17];
    const float* br1 = (const float*)d_in[18];
    const float* Wr2 = (const float*)d_in[19];
    const float* br2 = (const float*)d_in[20];

    const int N = in_sizes[0] / 3;   // 50000
    const int E = in_sizes[2] / 2;   // 800000
    const int G = out_size / 12;     // 1000
    const int* src = ei;
    const int* dstp = ei + E;

    char* ws = (char*)d_ws;
    size_t off = 0;
    auto alloc = [&](size_t bytes) -> char* {
        char* p = ws + off;
        off += (bytes + 255) & ~(size_t)255;
        return p;
    };
    unsigned short* TAB = (unsigned short*)alloc((size_t)N * 1088 * 2);
    float* hf = (float*)alloc((size_t)N * 128 * 4);
    unsigned short* hhi = (unsigned short*)alloc((size_t)N * 128 * 2);
    unsigned short* hlo = (unsigned short*)alloc((size_t)N * 128 * 2);
    float* agg = (float*)alloc((size_t)N * 16 * 4);
    float* pooled = (float*)alloc((size_t)G * 128 * 4);
    int* hist = (int*)alloc((size_t)N * 4);
    int* cursor = (int*)alloc((size_t)N * 4);
    int* perm = (int*)alloc((size_t)E * 4);
    int* srcS = (int*)alloc((size_t)E * 4);
    int* dstS = (int*)alloc((size_t)E * 4);
    float* n2S = (float*)alloc((size_t)E * 4);
    unsigned short* Bp1h = (unsigned short*)alloc(139264 * 2);
    unsigned short* Bp1l = (unsigned short*)alloc(139264 * 2);
    float* bias1088 = (float*)alloc(1088 * 4);
    float* w1cf = (float*)alloc(544 * 4);
    unsigned short* W2ph = (unsigned short*)alloc(8704 * 2);
    unsigned short* W2pl = (unsigned short*)alloc(8704 * 2);
    unsigned short* BpU1h = (unsigned short*)alloc(40960 * 2);
    unsigned short* BpU1l = (unsigned short*)alloc(40960 * 2);
    unsigned short* BpU2h = (unsigned short*)alloc(32768 * 2);
    unsigned short* BpU2l = (unsigned short*)alloc(32768 * 2);
    unsigned short* BpP1h = (unsigned short*)alloc(16384 * 2);
    unsigned short* BpP1l = (unsigned short*)alloc(16384 * 2);
    unsigned short* BpP2h = (unsigned short*)alloc(16384 * 2);
    unsigned short* BpP2l = (unsigned short*)alloc(16384 * 2);

    // Aliases inside the TAB region (dead between edge_kernel and next table GEMM):
    unsigned short* uhi = TAB + (size_t)N * 320;
    unsigned short* ulo = TAB + (size_t)N * 576;
    unsigned short* t1hi = TAB;
    unsigned short* t1lo = TAB + (size_t)N * 128;

    init_nodes<<<(N * 128) / 256, 256, 0, stream>>>(z, emb, hf, hhi, hlo, N);

    // one-time: counting sort of edges by dst
    hipMemsetAsync(hist, 0, (size_t)N * 4, stream);
    hist_kernel<<<(E + 255) / 256, 256, 0, stream>>>(dstp, hist, E);
    scan_kernel<<<1, 256, 0, stream>>>(hist, cursor, N);
    scatter_kernel<<<(E + 255) / 256, 256, 0, stream>>>(dstp, cursor, perm, E);
    reorder_kernel<<<(E + 255) / 256, 256, 0, stream>>>(perm, src, dstp, pos, srcS, dstS, n2S, E);

    const int gA = (N + 63) / 64;
    for (int l = 0; l < 7; ++l) {
        pack_msg1<<<139264 / 256, 256, 0, stream>>>(
            Wm1 + (size_t)l * 257 * 514, bm1 + (size_t)l * 514, Wm2 + (size_t)l * 514 * 16,
            Bp1h, Bp1l, bias1088, w1cf, W2ph, W2pl);
        tab_gemm<<<gA, 256, 0, stream>>>(
            hhi, hlo, Bp1h, Bp1l, bias1088, TAB, N);
        hipMemsetAsync(agg, 0, (size_t)N * 16 * 4, stream);
        edge_kernel<<<E / 128, 256, 0, stream>>>(TAB, w1cf, W2ph, W2pl, bm2 + l * 16,
                                                 srcS, dstS, n2S, agg);
        pack_generic<<<(160 * 256) / 256, 256, 0, stream>>>(
            Wu1 + (size_t)l * 144 * 256, 144, 256, BpU1h, BpU1l);
        up1_gemm<<<gA, 256, 0, stream>>>(
            agg, hf, BpU1h, BpU1l, bu1 + l * 256, uhi, ulo, N);
        pack_generic<<<(256 * 128) / 256, 256, 0, stream>>>(
            Wu2 + (size_t)l * 256 * 128, 256, 128, BpU2h, BpU2l);
        gemmA<8, 8, 2><<<gA, 256, 0, stream>>>(
            uhi, ulo, 256, BpU2h, BpU2l, bu2 + l * 128,
            hhi, hlo, 128, hf, 128, hf, nullptr, nullptr, N);
    }

    pack_generic<<<(128 * 128) / 256, 256, 0, stream>>>(Wp1, 128, 128, BpP1h, BpP1l);
    gemmA<4, 8, 1><<<gA, 256, 0, stream>>>(
        hhi, hlo, 128, BpP1h, BpP1l, bp1v,
        t1hi, t1lo, 128, nullptr, 0, nullptr, nullptr, nullptr, N);
    pack_generic<<<(128 * 128) / 256, 256, 0, stream>>>(Wp2, 128, 128, BpP2h, BpP2l);
    hipMemsetAsync(pooled, 0, (size_t)G * 128 * 4, stream);
    gemmA<4, 8, 3><<<gA, 256, 0, stream>>>(
        t1hi, t1lo, 128, BpP2h, BpP2l, bp2v,
        nullptr, nullptr, 0, nullptr, 0, nullptr, batch, pooled, N);
    readout<<<G, 128, 0, stream>>>(pooled, Wr1, br1, Wr2, br2, (float*)d_out);
}

// Round 9
// 3430.481 us; speedup vs baseline: 2.2555x; 1.0525x over previous
//
#include <hip/hip_runtime.h>
#include <hip/hip_bf16.h>
#include <cstdint>
#include <cstddef>

typedef short s16x8 __attribute__((ext_vector_type(8)));
typedef float f32x4 __attribute__((ext_vector_type(4)));
typedef unsigned int u32x4 __attribute__((ext_vector_type(4)));

__device__ __forceinline__ unsigned short f2bf(float f) {
    unsigned int u = __float_as_uint(f);
    unsigned int r = (u + 0x7FFFu + ((u >> 16) & 1u)) >> 16;
    return (unsigned short)r;
}
__device__ __forceinline__ float bf2f(unsigned short s) {
    return __uint_as_float(((unsigned int)s) << 16);
}
__device__ __forceinline__ void splitbf(float v, unsigned short& hi, unsigned short& lo) {
    hi = f2bf(v);
    lo = f2bf(v - bf2f(hi));
}
// fast swish: x * rcp(1+exp(-x)); v_rcp_f32 rel-err ~1e-7 << bf16 ulp
__device__ __forceinline__ float swish_fast(float x) {
    float e = __expf(-x);
    return x * __builtin_amdgcn_rcpf(1.0f + e);
}
// pack 2 f32 -> 2 bf16 (RNE) in one instruction
__device__ __forceinline__ unsigned int cvt_pk_bf16(float lo, float hi) {
    unsigned int r;
    asm("v_cvt_pk_bf16_f32 %0, %1, %2" : "=v"(r) : "v"(lo), "v"(hi));
    return r;
}

// ---------------- init: h = emb[atomic[z]] ----------------
__global__ void init_nodes(const int* __restrict__ z, const float* __restrict__ emb,
                           float* __restrict__ hf, unsigned short* __restrict__ hhi,
                           unsigned short* __restrict__ hlo, int N) {
    int tid = blockIdx.x * 256 + threadIdx.x;
    int n = tid >> 7, f = tid & 127;
    int zv = z[n];
    int idx5 = (zv == 1) ? 0 : (zv - 5);
    float v = emb[idx5 * 128 + f];
    hf[tid] = v;
    unsigned short hi, lo;
    splitbf(v, hi, lo);
    hhi[tid] = hi;
    hlo[tid] = lo;
}

// ---------------- edge preprocessing: counting sort by dst ----------------
__global__ void hist_kernel(const int* __restrict__ dst, int* __restrict__ hist, int E) {
    int e = blockIdx.x * 256 + threadIdx.x;
    if (e < E) atomicAdd(&hist[dst[e]], 1);
}

__global__ void scan_kernel(const int* __restrict__ hist, int* __restrict__ cursor, int N) {
    __shared__ int part[256];
    int t = threadIdx.x;
    int chunk = (N + 255) / 256;
    int base = t * chunk;
    int s = 0;
    for (int i = 0; i < chunk; ++i) {
        int idx = base + i;
        if (idx < N) s += hist[idx];
    }
    part[t] = s;
    __syncthreads();
    for (int d = 1; d < 256; d <<= 1) {
        int v = 0;
        if (t >= d) v = part[t - d];
        __syncthreads();
        part[t] += v;
        __syncthreads();
    }
    int run = part[t] - s;  // exclusive prefix of this thread's chunk
    for (int i = 0; i < chunk; ++i) {
        int idx = base + i;
        if (idx < N) {
            cursor[idx] = run;
            run += hist[idx];
        }
    }
}

__global__ void scatter_kernel(const int* __restrict__ dst, int* __restrict__ cursor,
                               int* __restrict__ perm, int E) {
    int e = blockIdx.x * 256 + threadIdx.x;
    if (e < E) {
        int p = atomicAdd(&cursor[dst[e]], 1);
        perm[p] = e;
    }
}

__global__ void reorder_kernel(const int* __restrict__ perm, const int* __restrict__ src,
                               const int* __restrict__ dst, const float* __restrict__ pos,
                               int* __restrict__ srcS, int* __restrict__ dstS,
                               float* __restrict__ n2S, int E) {
    int i = blockIdx.x * 256 + threadIdx.x;
    if (i >= E) return;
    int e = perm[i];
    int si = src[e], di = dst[e];
    srcS[i] = si;
    dstS[i] = di;
    float dx = pos[si * 3 + 0] - pos[di * 3 + 0];
    float dy = pos[si * 3 + 1] - pos[di * 3 + 1];
    float dz = pos[si * 3 + 2] - pos[di * 3 + 2];
    n2S[i] = dx * dx + dy * dy + dz * dz;
}

// ---------------- pack W_msg1 + W_msg2 for layer l (hi/lo) ----------------
__global__ void pack_msg1(const float* __restrict__ Wm1l, const float* __restrict__ bm1l,
                          const float* __restrict__ Wm2l,
                          unsigned short* __restrict__ Bp1h, unsigned short* __restrict__ Bp1l,
                          float* __restrict__ bias1088, float* __restrict__ w1cf,
                          unsigned short* __restrict__ W2ph, unsigned short* __restrict__ W2pl) {
    int t = blockIdx.x * 256 + threadIdx.x;
    int i = t & 7;
    int lane = (t >> 3) & 63;
    int rest = t >> 9;
    int cb = rest % 68;
    int ks = rest / 68;
    int k = ks * 32 + ((lane >> 4) << 3) + i;  // 0..127
    int ch = cb * 16 + (lane & 15);            // 0..1087
    float val;
    if (ch < 544) {
        val = (ch < 514) ? Wm1l[k * 514 + ch] : 0.f;
    } else {
        int c = ch - 544;
        val = (c < 514) ? Wm1l[(128 + k) * 514 + c] : 0.f;
    }
    unsigned short hi, lo;
    splitbf(val, hi, lo);
    Bp1h[t] = hi;
    Bp1l[t] = lo;
    if (t < 1088) bias1088[t] = (t < 514) ? bm1l[t] : 0.f;
    if (t < 544) w1cf[t] = (t < 514) ? Wm1l[256 * 514 + t] : 0.f;
    if (t < 8704) {
        int i2 = t & 7, lane2 = (t >> 3) & 63, ks2 = t >> 9;
        int k2 = ks2 * 32 + ((lane2 >> 4) << 3) + i2;
        int c2 = lane2 & 15;
        float v2 = (k2 < 514) ? Wm2l[k2 * 16 + c2] : 0.f;
        unsigned short h2, l2;
        splitbf(v2, h2, l2);
        W2ph[t] = h2;
        W2pl[t] = l2;
    }
}

// ---------------- generic B packer: W[K][Nc] fp32 -> frag layout hi/lo ----------------
__global__ void pack_generic(const float* __restrict__ W, int K, int Nc,
                             unsigned short* __restrict__ Bph, unsigned short* __restrict__ Bpl) {
    int t = blockIdx.x * 256 + threadIdx.x;
    int i = t & 7;
    int lane = (t >> 3) & 63;
    int rest = t >> 9;
    int CB = Nc >> 4;
    int cb = rest % CB;
    int ks = rest / CB;
    int k = ks * 32 + ((lane >> 4) << 3) + i;
    int c = cb * 16 + (lane & 15);
    float val = (k < K) ? W[(size_t)k * Nc + c] : 0.f;
    unsigned short hi, lo;
    splitbf(val, hi, lo);
    Bph[t] = hi;
    Bpl[t] = lo;
}

// ---------------- specialized table GEMM: A(K=128) in regs, loop 68 col-blocks ----------------
__global__ __launch_bounds__(256) void tab_gemm(
    const unsigned short* __restrict__ Ahi, const unsigned short* __restrict__ Alo,
    const unsigned short* __restrict__ Bph, const unsigned short* __restrict__ Bpl,
    const float* __restrict__ bias, unsigned short* __restrict__ TAB, int N) {
    int lane = threadIdx.x & 63;
    int wid = threadIdx.x >> 6;
    int row0 = blockIdx.x * 64 + wid * 16;
    if (row0 >= N) return;
    const size_t arow = (size_t)(row0 + (lane & 15)) * 128;
    const int ak = (lane >> 4) * 8;
    s16x8 ah[4], al[4];
#pragma unroll
    for (int ks = 0; ks < 4; ++ks) {
        ah[ks] = *(const s16x8*)(Ahi + arow + ks * 32 + ak);
        al[ks] = *(const s16x8*)(Alo + arow + ks * 32 + ak);
    }
    int col16 = lane & 15;
    int rb = (lane >> 4) * 4;
    for (int cb = 0; cb < 68; ++cb) {
        f32x4 acc = {0.f, 0.f, 0.f, 0.f};
#pragma unroll
        for (int ks = 0; ks < 4; ++ks) {
            size_t bidx = ((size_t)(ks * 68 + cb) * 64 + lane) * 8;
            s16x8 bh = *(const s16x8*)(Bph + bidx);
            s16x8 bl = *(const s16x8*)(Bpl + bidx);
            acc = __builtin_amdgcn_mfma_f32_16x16x32_bf16(ah[ks], bh, acc, 0, 0, 0);
            acc = __builtin_amdgcn_mfma_f32_16x16x32_bf16(al[ks], bh, acc, 0, 0, 0);
            acc = __builtin_amdgcn_mfma_f32_16x16x32_bf16(ah[ks], bl, acc, 0, 0, 0);
        }
        float bv = bias[cb * 16 + col16];
#pragma unroll
        for (int i = 0; i < 4; ++i) {
            TAB[(size_t)(row0 + rb + i) * 1088 + cb * 16 + col16] = f2bf(acc[i] + bv);
        }
    }
}

// ---------------- generic 64-row A-in-regs GEMM, split precision ----------------
// MODE 1: swish(acc+bias) -> outB (hi), outB2 (lo)
// MODE 2: h = acc+bias+resid; outF=h (f32), outB/outB2 = hi/lo
// MODE 3: atomicAdd(pooled[batch[row]*128+col], acc+bias)
template <int KS, int CB, int MODE>
__global__ __launch_bounds__(256) void gemmA(
    const unsigned short* __restrict__ Ahi, const unsigned short* __restrict__ Alo, int lda,
    const unsigned short* __restrict__ Bph, const unsigned short* __restrict__ Bpl,
    const float* __restrict__ bias,
    unsigned short* __restrict__ outB, unsigned short* __restrict__ outB2, int ldoB,
    float* __restrict__ outF, int ldoF, const float* __restrict__ resid,
    const int* __restrict__ batch, float* __restrict__ pooled, int N) {
    int lane = threadIdx.x & 63;
    int wid = threadIdx.x >> 6;
    int row0 = blockIdx.x * 64 + wid * 16;
    if (row0 >= N) return;
    const size_t arow = (size_t)(row0 + (lane & 15)) * lda;
    const int ak = (lane >> 4) * 8;
    s16x8 ah[KS], al[KS];
#pragma unroll
    for (int ks = 0; ks < KS; ++ks) {
        ah[ks] = *(const s16x8*)(Ahi + arow + ks * 32 + ak);
        al[ks] = *(const s16x8*)(Alo + arow + ks * 32 + ak);
    }
    int col16 = lane & 15;
    int rb = (lane >> 4) * 4;
    for (int cb = 0; cb < CB; ++cb) {
        f32x4 acc = {0.f, 0.f, 0.f, 0.f};
#pragma unroll
        for (int ks = 0; ks < KS; ++ks) {
            size_t bidx = ((size_t)(ks * CB + cb) * 64 + lane) * 8;
            s16x8 bh = *(const s16x8*)(Bph + bidx);
            s16x8 bl = *(const s16x8*)(Bpl + bidx);
            acc = __builtin_amdgcn_mfma_f32_16x16x32_bf16(ah[ks], bh, acc, 0, 0, 0);
            acc = __builtin_amdgcn_mfma_f32_16x16x32_bf16(al[ks], bh, acc, 0, 0, 0);
            acc = __builtin_amdgcn_mfma_f32_16x16x32_bf16(ah[ks], bl, acc, 0, 0, 0);
        }
        int col = cb * 16 + col16;
        float bv = bias[col];
#pragma unroll
        for (int i = 0; i < 4; ++i) {
            int row = row0 + rb + i;
            float v = acc[i] + bv;
            if (MODE == 1) {
                float s = swish_fast(v);
                unsigned short hi, lo;
                splitbf(s, hi, lo);
                outB[(size_t)row * ldoB + col] = hi;
                outB2[(size_t)row * ldoB + col] = lo;
            } else if (MODE == 2) {
                float h = v + resid[(size_t)row * ldoF + col];
                outF[(size_t)row * ldoF + col] = h;
                unsigned short hi, lo;
                splitbf(h, hi, lo);
                outB[(size_t)row * ldoB + col] = hi;
                outB2[(size_t)row * ldoB + col] = lo;
            } else {
                unsafeAtomicAdd(&pooled[(size_t)batch[row] * 128 + col], v);
            }
        }
    }
}

// ---------------- up1 GEMM: A assembled on the fly from agg(f32)+hf(f32) ----------------
// x = [agg(16) | h(128) | 0(16)], KS=5, CB=16; out = swish -> uhi/ulo
__global__ __launch_bounds__(256) void up1_gemm(
    const float* __restrict__ agg, const float* __restrict__ hf,
    const unsigned short* __restrict__ Bph, const unsigned short* __restrict__ Bpl,
    const float* __restrict__ bias,
    unsigned short* __restrict__ uhi, unsigned short* __restrict__ ulo, int N) {
    int lane = threadIdx.x & 63;
    int wid = threadIdx.x >> 6;
    int row0 = blockIdx.x * 64 + wid * 16;
    if (row0 >= N) return;
    int r = row0 + (lane & 15);
    const int ak = (lane >> 4) * 8;
    s16x8 ah[5], al[5];
#pragma unroll
    for (int ks = 0; ks < 5; ++ks) {
        int c0 = ks * 32 + ak;   // 8-chunk fully inside one region (bounds 16,144 are 8-aligned)
        f32x4 v0, v1;
        if (c0 < 16) {
            v0 = *(const f32x4*)(agg + (size_t)r * 16 + c0);
            v1 = *(const f32x4*)(agg + (size_t)r * 16 + c0 + 4);
        } else if (c0 < 144) {
            v0 = *(const f32x4*)(hf + (size_t)r * 128 + c0 - 16);
            v1 = *(const f32x4*)(hf + (size_t)r * 128 + c0 - 12);
        } else {
            v0 = f32x4{0.f, 0.f, 0.f, 0.f};
            v1 = f32x4{0.f, 0.f, 0.f, 0.f};
        }
        u32x4 hiP, loP;
#pragma unroll
        for (int jj = 0; jj < 4; ++jj) {
            float x0 = (jj < 2) ? v0[2 * jj] : v1[2 * jj - 4];
            float x1 = (jj < 2) ? v0[2 * jj + 1] : v1[2 * jj - 3];
            unsigned short h0, l0, h1, l1;
            splitbf(x0, h0, l0);
            splitbf(x1, h1, l1);
            hiP[jj] = (unsigned int)h0 | ((unsigned int)h1 << 16);
            loP[jj] = (unsigned int)l0 | ((unsigned int)l1 << 16);
        }
        ah[ks] = __builtin_bit_cast(s16x8, hiP);
        al[ks] = __builtin_bit_cast(s16x8, loP);
    }
    int col16 = lane & 15;
    int rb = (lane >> 4) * 4;
    for (int cb = 0; cb < 16; ++cb) {
        f32x4 acc = {0.f, 0.f, 0.f, 0.f};
#pragma unroll
        for (int ks = 0; ks < 5; ++ks) {
            size_t bidx = ((size_t)(ks * 16 + cb) * 64 + lane) * 8;
            s16x8 bh = *(const s16x8*)(Bph + bidx);
            s16x8 bl = *(const s16x8*)(Bpl + bidx);
            acc = __builtin_amdgcn_mfma_f32_16x16x32_bf16(ah[ks], bh, acc, 0, 0, 0);
            acc = __builtin_amdgcn_mfma_f32_16x16x32_bf16(al[ks], bh, acc, 0, 0, 0);
            acc = __builtin_amdgcn_mfma_f32_16x16x32_bf16(ah[ks], bl, acc, 0, 0, 0);
        }
        int col = cb * 16 + col16;
        float bv = bias[col];
#pragma unroll
        for (int i = 0; i < 4; ++i) {
            int row = row0 + rb + i;
            float s = swish_fast(acc[i] + bv);
            unsigned short hi, lo;
            splitbf(s, hi, lo);
            uhi[(size_t)row * 256 + col] = hi;
            ulo[(size_t)row * 256 + col] = lo;
        }
    }
}

// ---------------- edge kernel: 32 edges/wave, 3-deep pipeline, W2 in LDS ----------------
// Key: W2 frags come from LDS (lgkmcnt), so the MFMA operand waits do NOT drain
// the vmcnt-counted TAB prefetch stream.
__global__ __launch_bounds__(256) void edge_kernel(
    const unsigned short* __restrict__ TAB, const float* __restrict__ w1cf,
    const unsigned short* __restrict__ W2ph, const unsigned short* __restrict__ W2pl,
    const float* __restrict__ bm2l,
    const int* __restrict__ srcS, const int* __restrict__ dstS,
    const float* __restrict__ n2S, float* __restrict__ agg) {
    __shared__ unsigned short sWh[8704];
    __shared__ unsigned short sWl[8704];
    __shared__ float sw1[544];
    for (int t = threadIdx.x; t < 1088; t += 256) {
        ((s16x8*)sWh)[t] = ((const s16x8*)W2ph)[t];
        ((s16x8*)sWl)[t] = ((const s16x8*)W2pl)[t];
    }
    for (int t = threadIdx.x; t < 544; t += 256) sw1[t] = w1cf[t];
    __syncthreads();

    int lane = threadIdx.x & 63;
    int wid = threadIdx.x >> 6;
    int ebase = blockIdx.x * 128 + wid * 32;
    int rr = lane & 15;
    int e0 = ebase + rr;
    int e1 = ebase + 16 + rr;
    int di0 = dstS[e0], si0 = srcS[e0];
    int di1 = dstS[e1], si1 = srcS[e1];
    float n20 = n2S[e0], n21 = n2S[e1];
    const int ak = (lane >> 4) * 8;
    const unsigned short* pa0 = TAB + (size_t)di0 * 1088 + ak;
    const unsigned short* pb0 = TAB + (size_t)si0 * 1088 + 544 + ak;
    const unsigned short* pa1 = TAB + (size_t)di1 * 1088 + ak;
    const unsigned short* pb1 = TAB + (size_t)si1 * 1088 + 544 + ak;

    s16x8 qa0[3], qb0[3], qa1[3], qb1[3];
#pragma unroll
    for (int p = 0; p < 3; ++p) {
        qa0[p] = *(const s16x8*)(pa0 + p * 32);
        qb0[p] = *(const s16x8*)(pb0 + p * 32);
        qa1[p] = *(const s16x8*)(pa1 + p * 32);
        qb1[p] = *(const s16x8*)(pb1 + p * 32);
    }

    f32x4 acc0 = {0.f, 0.f, 0.f, 0.f};
    f32x4 acc1 = {0.f, 0.f, 0.f, 0.f};
#pragma unroll
    for (int ks = 0; ks < 17; ++ks) {
        const int slot = ks % 3;
        s16x8 va0 = qa0[slot], vb0 = qb0[slot];
        s16x8 va1 = qa1[slot], vb1 = qb1[slot];
        if (ks + 3 < 17) {
            qa0[slot] = *(const s16x8*)(pa0 + (ks + 3) * 32);
            qb0[slot] = *(const s16x8*)(pb0 + (ks + 3) * 32);
            qa1[slot] = *(const s16x8*)(pa1 + (ks + 3) * 32);
            qb1[slot] = *(const s16x8*)(pb1 + (ks + 3) * 32);
        }
        f32x4 c0 = *(const f32x4*)(sw1 + ks * 32 + ak);
        f32x4 c1 = *(const f32x4*)(sw1 + ks * 32 + ak + 4);
        u32x4 mu0, mu1;
#pragma unroll
        for (int jj = 0; jj < 4; ++jj) {
            float w0 = (jj < 2) ? c0[2 * jj] : c1[2 * jj - 4];
            float w1 = (jj < 2) ? c0[2 * jj + 1] : c1[2 * jj - 3];
            float x00 = bf2f((unsigned short)va0[2 * jj]) + bf2f((unsigned short)vb0[2 * jj]) + n20 * w0;
            float x01 = bf2f((unsigned short)va0[2 * jj + 1]) + bf2f((unsigned short)vb0[2 * jj + 1]) + n20 * w1;
            mu0[jj] = cvt_pk_bf16(swish_fast(x00), swish_fast(x01));
            float x10 = bf2f((unsigned short)va1[2 * jj]) + bf2f((unsigned short)vb1[2 * jj]) + n21 * w0;
            float x11 = bf2f((unsigned short)va1[2 * jj + 1]) + bf2f((unsigned short)vb1[2 * jj + 1]) + n21 * w1;
            mu1[jj] = cvt_pk_bf16(swish_fast(x10), swish_fast(x11));
        }
        s16x8 m0 = __builtin_bit_cast(s16x8, mu0);
        s16x8 m1 = __builtin_bit_cast(s16x8, mu1);
        s16x8 bh = *(const s16x8*)(sWh + (ks * 64 + lane) * 8);
        s16x8 bl = *(const s16x8*)(sWl + (ks * 64 + lane) * 8);
        acc0 = __builtin_amdgcn_mfma_f32_16x16x32_bf16(m0, bh, acc0, 0, 0, 0);
        acc0 = __builtin_amdgcn_mfma_f32_16x16x32_bf16(m0, bl, acc0, 0, 0, 0);
        acc1 = __builtin_amdgcn_mfma_f32_16x16x32_bf16(m1, bh, acc1, 0, 0, 0);
        acc1 = __builtin_amdgcn_mfma_f32_16x16x32_bf16(m1, bl, acc1, 0, 0, 0);
    }

    int col = lane & 15;
    float b2 = bm2l[col];
#pragma unroll
    for (int i = 0; i < 4; ++i) {
        int ea = ebase + (lane >> 4) * 4 + i;
        float v0 = swish_fast(acc0[i] + b2);
        unsafeAtomicAdd(&agg[(size_t)dstS[ea] * 16 + col], v0);
        int eb = ea + 16;
        float v1 = swish_fast(acc1[i] + b2);
        unsafeAtomicAdd(&agg[(size_t)dstS[eb] * 16 + col], v1);
    }
}

// ---------------- readout ----------------
__global__ void readout(const float* __restrict__ pooled, const float* __restrict__ Wr1,
                        const float* __restrict__ br1, const float* __restrict__ Wr2,
                        const float* __restrict__ br2, float* __restrict__ out) {
    __shared__ float row[128];
    __shared__ float tt[128];
    int g = blockIdx.x;
    int t = threadIdx.x;
    row[t] = pooled[g * 128 + t];
    __syncthreads();
    float s = br1[t];
    for (int k = 0; k < 128; ++k) s += row[k] * Wr1[k * 128 + t];
    tt[t] = swish_fast(s);
    __syncthreads();
    if (t < 12) {
        float o = br2[t];
        for (int j = 0; j < 128; ++j) o += tt[j] * Wr2[j * 12 + t];
        out[g * 12 + t] = o;
    }
}

extern "C" void kernel_launch(void* const* d_in, const int* in_sizes, int n_in,
                              void* d_out, int out_size, void* d_ws, size_t ws_size,
                              hipStream_t stream) {
    const float* pos = (const float*)d_in[0];
    const int* z = (const int*)d_in[1];
    const int* ei = (const int*)d_in[2];
    const int* batch = (const int*)d_in[3];
    const float* emb = (const float*)d_in[4];
    const float* Wm1 = (const float*)d_in[5];
    const float* bm1 = (const float*)d_in[6];
    const float* Wm2 = (const float*)d_in[7];
    const float* bm2 = (const float*)d_in[8];
    const float* Wu1 = (const float*)d_in[9];
    const float* bu1 = (const float*)d_in[10];
    const float* Wu2 = (const float*)d_in[11];
    const float* bu2 = (const float*)d_in[12];
    const float* Wp1 = (const float*)d_in[13];
    const float* bp1v = (const float*)d_in[14];
    const float* Wp2 = (const float*)d_in[15];
    const float* bp2v = (const float*)d_in[16];
    const float* Wr1 = (const float*)d_in[17];
    const float* br1 = (const float*)d_in[18];
    const float* Wr2 = (const float*)d_in[19];
    const float* br2 = (const float*)d_in[20];

    const int N = in_sizes[0] / 3;   // 50000
    const int E = in_sizes[2] / 2;   // 800000
    const int G = out_size / 12;     // 1000
    const int* src = ei;
    const int* dstp = ei + E;

    char* ws = (char*)d_ws;
    size_t off = 0;
    auto alloc = [&](size_t bytes) -> char* {
        char* p = ws + off;
        off += (bytes + 255) & ~(size_t)255;
        return p;
    };
    unsigned short* TAB = (unsigned short*)alloc((size_t)N * 1088 * 2);
    float* hf = (float*)alloc((size_t)N * 128 * 4);
    unsigned short* hhi = (unsigned short*)alloc((size_t)N * 128 * 2);
    unsigned short* hlo = (unsigned short*)alloc((size_t)N * 128 * 2);
    float* agg = (float*)alloc((size_t)N * 16 * 4);
    float* pooled = (float*)alloc((size_t)G * 128 * 4);
    int* hist = (int*)alloc((size_t)N * 4);
    int* cursor = (int*)alloc((size_t)N * 4);
    int* perm = (int*)alloc((size_t)E * 4);
    int* srcS = (int*)alloc((size_t)E * 4);
    int* dstS = (int*)alloc((size_t)E * 4);
    float* n2S = (float*)alloc((size_t)E * 4);
    unsigned short* Bp1h = (unsigned short*)alloc(139264 * 2);
    unsigned short* Bp1l = (unsigned short*)alloc(139264 * 2);
    float* bias1088 = (float*)alloc(1088 * 4);
    float* w1cf = (float*)alloc(544 * 4);
    unsigned short* W2ph = (unsigned short*)alloc(8704 * 2);
    unsigned short* W2pl = (unsigned short*)alloc(8704 * 2);
    unsigned short* BpU1h = (unsigned short*)alloc(40960 * 2);
    unsigned short* BpU1l = (unsigned short*)alloc(40960 * 2);
    unsigned short* BpU2h = (unsigned short*)alloc(32768 * 2);
    unsigned short* BpU2l = (unsigned short*)alloc(32768 * 2);
    unsigned short* BpP1h = (unsigned short*)alloc(16384 * 2);
    unsigned short* BpP1l = (unsigned short*)alloc(16384 * 2);
    unsigned short* BpP2h = (unsigned short*)alloc(16384 * 2);
    unsigned short* BpP2l = (unsigned short*)alloc(16384 * 2);

    // Aliases inside the TAB region (dead between edge_kernel and next table GEMM):
    unsigned short* uhi = TAB + (size_t)N * 320;
    unsigned short* ulo = TAB + (size_t)N * 576;
    unsigned short* t1hi = TAB;
    unsigned short* t1lo = TAB + (size_t)N * 128;

    init_nodes<<<(N * 128) / 256, 256, 0, stream>>>(z, emb, hf, hhi, hlo, N);

    // one-time: counting sort of edges by dst
    hipMemsetAsync(hist, 0, (size_t)N * 4, stream);
    hist_kernel<<<(E + 255) / 256, 256, 0, stream>>>(dstp, hist, E);
    scan_kernel<<<1, 256, 0, stream>>>(hist, cursor, N);
    scatter_kernel<<<(E + 255) / 256, 256, 0, stream>>>(dstp, cursor, perm, E);
    reorder_kernel<<<(E + 255) / 256, 256, 0, stream>>>(perm, src, dstp, pos, srcS, dstS, n2S, E);

    const int gA = (N + 63) / 64;
    for (int l = 0; l < 7; ++l) {
        pack_msg1<<<139264 / 256, 256, 0, stream>>>(
            Wm1 + (size_t)l * 257 * 514, bm1 + (size_t)l * 514, Wm2 + (size_t)l * 514 * 16,
            Bp1h, Bp1l, bias1088, w1cf, W2ph, W2pl);
        tab_gemm<<<gA, 256, 0, stream>>>(
            hhi, hlo, Bp1h, Bp1l, bias1088, TAB, N);
        hipMemsetAsync(agg, 0, (size_t)N * 16 * 4, stream);
        edge_kernel<<<E / 128, 256, 0, stream>>>(TAB, w1cf, W2ph, W2pl, bm2 + l * 16,
                                                 srcS, dstS, n2S, agg);
        pack_generic<<<(160 * 256) / 256, 256, 0, stream>>>(
            Wu1 + (size_t)l * 144 * 256, 144, 256, BpU1h, BpU1l);
        up1_gemm<<<gA, 256, 0, stream>>>(
            agg, hf, BpU1h, BpU1l, bu1 + l * 256, uhi, ulo, N);
        pack_generic<<<(256 * 128) / 256, 256, 0, stream>>>(
            Wu2 + (size_t)l * 256 * 128, 256, 128, BpU2h, BpU2l);
        gemmA<8, 8, 2><<<gA, 256, 0, stream>>>(
            uhi, ulo, 256, BpU2h, BpU2l, bu2 + l * 128,
            hhi, hlo, 128, hf, 128, hf, nullptr, nullptr, N);
    }

    pack_generic<<<(128 * 128) / 256, 256, 0, stream>>>(Wp1, 128, 128, BpP1h, BpP1l);
    gemmA<4, 8, 1><<<gA, 256, 0, stream>>>(
        hhi, hlo, 128, BpP1h, BpP1l, bp1v,
        t1hi, t1lo, 128, nullptr, 0, nullptr, nullptr, nullptr, N);
    pack_generic<<<(128 * 128) / 256, 256, 0, stream>>>(Wp2, 128, 128, BpP2h, BpP2l);
    hipMemsetAsync(pooled, 0, (size_t)G * 128 * 4, stream);
    gemmA<4, 8, 3><<<gA, 256, 0, stream>>>(
        t1hi, t1lo, 128, BpP2h, BpP2l, bp2v,
        nullptr, nullptr, 0, nullptr, 0, nullptr, batch, pooled, N);
    readout<<<G, 128, 0, stream>>>(pooled, Wr1, br1, Wr2, br2, (float*)d_out);
}

// Round 10
// 3021.643 us; speedup vs baseline: 2.5607x; 1.1353x over previous
//
#include <hip/hip_runtime.h>
#include <hip/hip_bf16.h>
#include <cstdint>
#include <cstddef>

typedef _Float16 h16x8 __attribute__((ext_vector_type(8)));
typedef float f32x4 __attribute__((ext_vector_type(4)));

__device__ __forceinline__ void splitf16(float v, _Float16& hi, _Float16& lo) {
    hi = (_Float16)v;
    lo = (_Float16)(v - (float)hi);
}
// fast swish: x * rcp(1+exp(-x)); v_rcp_f32 rel-err ~1e-7
__device__ __forceinline__ float swish_fast(float x) {
    float e = __expf(-x);
    return x * __builtin_amdgcn_rcpf(1.0f + e);
}

// ---------------- init: h = emb[atomic[z]] ----------------
__global__ void init_nodes(const int* __restrict__ z, const float* __restrict__ emb,
                           float* __restrict__ hf, _Float16* __restrict__ hhi,
                           _Float16* __restrict__ hlo, int N) {
    int tid = blockIdx.x * 256 + threadIdx.x;
    int n = tid >> 7, f = tid & 127;
    int zv = z[n];
    int idx5 = (zv == 1) ? 0 : (zv - 5);
    float v = emb[idx5 * 128 + f];
    hf[tid] = v;
    _Float16 hi, lo;
    splitf16(v, hi, lo);
    hhi[tid] = hi;
    hlo[tid] = lo;
}

// ---------------- edge preprocessing: counting sort by dst ----------------
__global__ void hist_kernel(const int* __restrict__ dst, int* __restrict__ hist, int E) {
    int e = blockIdx.x * 256 + threadIdx.x;
    if (e < E) atomicAdd(&hist[dst[e]], 1);
}

__global__ void scan_kernel(const int* __restrict__ hist, int* __restrict__ cursor, int N) {
    __shared__ int part[256];
    int t = threadIdx.x;
    int chunk = (N + 255) / 256;
    int base = t * chunk;
    int s = 0;
    for (int i = 0; i < chunk; ++i) {
        int idx = base + i;
        if (idx < N) s += hist[idx];
    }
    part[t] = s;
    __syncthreads();
    for (int d = 1; d < 256; d <<= 1) {
        int v = 0;
        if (t >= d) v = part[t - d];
        __syncthreads();
        part[t] += v;
        __syncthreads();
    }
    int run = part[t] - s;
    for (int i = 0; i < chunk; ++i) {
        int idx = base + i;
        if (idx < N) {
            cursor[idx] = run;
            run += hist[idx];
        }
    }
}

__global__ void scatter_kernel(const int* __restrict__ dst, int* __restrict__ cursor,
                               int* __restrict__ perm, int E) {
    int e = blockIdx.x * 256 + threadIdx.x;
    if (e < E) {
        int p = atomicAdd(&cursor[dst[e]], 1);
        perm[p] = e;
    }
}

__global__ void reorder_kernel(const int* __restrict__ perm, const int* __restrict__ src,
                               const int* __restrict__ dst, const float* __restrict__ pos,
                               int* __restrict__ srcS, int* __restrict__ dstS,
                               float* __restrict__ n2S, int E) {
    int i = blockIdx.x * 256 + threadIdx.x;
    if (i >= E) return;
    int e = perm[i];
    int si = src[e], di = dst[e];
    srcS[i] = si;
    dstS[i] = di;
    float dx = pos[si * 3 + 0] - pos[di * 3 + 0];
    float dy = pos[si * 3 + 1] - pos[di * 3 + 1];
    float dz = pos[si * 3 + 2] - pos[di * 3 + 2];
    n2S[i] = dx * dx + dy * dy + dz * dz;
}

// ---------------- pack W_msg1 + W_msg2 for layer l ----------------
// Bp1: single f16 [ks=4][cb=68][lane=64][i=8]; w1c f16[544]; W2p single f16 [17][64][8]
__global__ void pack_msg1(const float* __restrict__ Wm1l, const float* __restrict__ bm1l,
                          const float* __restrict__ Wm2l,
                          _Float16* __restrict__ Bp1, float* __restrict__ bias1088,
                          _Float16* __restrict__ w1c, _Float16* __restrict__ W2p) {
    int t = blockIdx.x * 256 + threadIdx.x;
    int i = t & 7;
    int lane = (t >> 3) & 63;
    int rest = t >> 9;
    int cb = rest % 68;
    int ks = rest / 68;
    int k = ks * 32 + ((lane >> 4) << 3) + i;
    int ch = cb * 16 + (lane & 15);
    float val;
    if (ch < 544) {
        val = (ch < 514) ? Wm1l[k * 514 + ch] : 0.f;
    } else {
        int c = ch - 544;
        val = (c < 514) ? Wm1l[(128 + k) * 514 + c] : 0.f;
    }
    Bp1[t] = (_Float16)val;
    if (t < 1088) bias1088[t] = (t < 514) ? bm1l[t] : 0.f;
    if (t < 544) w1c[t] = (_Float16)((t < 514) ? Wm1l[256 * 514 + t] : 0.f);
    if (t < 8704) {
        int i2 = t & 7, lane2 = (t >> 3) & 63, ks2 = t >> 9;
        int k2 = ks2 * 32 + ((lane2 >> 4) << 3) + i2;
        int c2 = lane2 & 15;
        W2p[t] = (_Float16)((k2 < 514) ? Wm2l[k2 * 16 + c2] : 0.f);
    }
}

// ---------------- generic B packer: W[K][Nc] fp32 -> single f16 frag layout ----------------
__global__ void pack_generic(const float* __restrict__ W, int K, int Nc,
                             _Float16* __restrict__ Bp) {
    int t = blockIdx.x * 256 + threadIdx.x;
    int i = t & 7;
    int lane = (t >> 3) & 63;
    int rest = t >> 9;
    int CB = Nc >> 4;
    int cb = rest % CB;
    int ks = rest / CB;
    int k = ks * 32 + ((lane >> 4) << 3) + i;
    int c = cb * 16 + (lane & 15);
    float val = (k < K) ? W[(size_t)k * Nc + c] : 0.f;
    Bp[t] = (_Float16)val;
}

// ---------------- table GEMM: A(K=128) hi/lo in regs, B single f16, 2 MFMA/ks ----------------
__global__ __launch_bounds__(256) void tab_gemm(
    const _Float16* __restrict__ Ahi, const _Float16* __restrict__ Alo,
    const _Float16* __restrict__ Bp, const float* __restrict__ bias,
    _Float16* __restrict__ TAB, int N) {
    int lane = threadIdx.x & 63;
    int wid = threadIdx.x >> 6;
    int row0 = blockIdx.x * 64 + wid * 16;
    if (row0 >= N) return;
    const size_t arow = (size_t)(row0 + (lane & 15)) * 128;
    const int ak = (lane >> 4) * 8;
    h16x8 ah[4], al[4];
#pragma unroll
    for (int ks = 0; ks < 4; ++ks) {
        ah[ks] = *(const h16x8*)(Ahi + arow + ks * 32 + ak);
        al[ks] = *(const h16x8*)(Alo + arow + ks * 32 + ak);
    }
    int col16 = lane & 15;
    int rb = (lane >> 4) * 4;
    for (int cb = 0; cb < 68; ++cb) {
        f32x4 acc = {0.f, 0.f, 0.f, 0.f};
#pragma unroll
        for (int ks = 0; ks < 4; ++ks) {
            h16x8 bh = *(const h16x8*)(Bp + ((size_t)(ks * 68 + cb) * 64 + lane) * 8);
            acc = __builtin_amdgcn_mfma_f32_16x16x32_f16(ah[ks], bh, acc, 0, 0, 0);
            acc = __builtin_amdgcn_mfma_f32_16x16x32_f16(al[ks], bh, acc, 0, 0, 0);
        }
        float bv = bias[cb * 16 + col16];
#pragma unroll
        for (int i = 0; i < 4; ++i) {
            TAB[(size_t)(row0 + rb + i) * 1088 + cb * 16 + col16] = (_Float16)(acc[i] + bv);
        }
    }
}

// ---------------- generic 64-row A-in-regs GEMM (A hi/lo f16, B single f16) ----------------
// MODE 1: swish -> outB/outB2 (hi/lo); MODE 2: +resid -> outF f32, outB/outB2; MODE 3: pooled atomic
template <int KS, int CB, int MODE>
__global__ __launch_bounds__(256) void gemmA(
    const _Float16* __restrict__ Ahi, const _Float16* __restrict__ Alo, int lda,
    const _Float16* __restrict__ Bp, const float* __restrict__ bias,
    _Float16* __restrict__ outB, _Float16* __restrict__ outB2, int ldoB,
    float* __restrict__ outF, int ldoF, const float* __restrict__ resid,
    const int* __restrict__ batch, float* __restrict__ pooled, int N) {
    int lane = threadIdx.x & 63;
    int wid = threadIdx.x >> 6;
    int row0 = blockIdx.x * 64 + wid * 16;
    if (row0 >= N) return;
    const size_t arow = (size_t)(row0 + (lane & 15)) * lda;
    const int ak = (lane >> 4) * 8;
    h16x8 ah[KS], al[KS];
#pragma unroll
    for (int ks = 0; ks < KS; ++ks) {
        ah[ks] = *(const h16x8*)(Ahi + arow + ks * 32 + ak);
        al[ks] = *(const h16x8*)(Alo + arow + ks * 32 + ak);
    }
    int col16 = lane & 15;
    int rb = (lane >> 4) * 4;
    for (int cb = 0; cb < CB; ++cb) {
        f32x4 acc = {0.f, 0.f, 0.f, 0.f};
#pragma unroll
        for (int ks = 0; ks < KS; ++ks) {
            h16x8 bh = *(const h16x8*)(Bp + ((size_t)(ks * CB + cb) * 64 + lane) * 8);
            acc = __builtin_amdgcn_mfma_f32_16x16x32_f16(ah[ks], bh, acc, 0, 0, 0);
            acc = __builtin_amdgcn_mfma_f32_16x16x32_f16(al[ks], bh, acc, 0, 0, 0);
        }
        int col = cb * 16 + col16;
        float bv = bias[col];
#pragma unroll
        for (int i = 0; i < 4; ++i) {
            int row = row0 + rb + i;
            float v = acc[i] + bv;
            if (MODE == 1) {
                float s = swish_fast(v);
                _Float16 hi, lo;
                splitf16(s, hi, lo);
                outB[(size_t)row * ldoB + col] = hi;
                outB2[(size_t)row * ldoB + col] = lo;
            } else if (MODE == 2) {
                float h = v + resid[(size_t)row * ldoF + col];
                outF[(size_t)row * ldoF + col] = h;
                _Float16 hi, lo;
                splitf16(h, hi, lo);
                outB[(size_t)row * ldoB + col] = hi;
                outB2[(size_t)row * ldoB + col] = lo;
            } else {
                unsafeAtomicAdd(&pooled[(size_t)batch[row] * 128 + col], v);
            }
        }
    }
}

// ---------------- up1 GEMM: A assembled on the fly from agg(f32)+hf(f32) ----------------
__global__ __launch_bounds__(256) void up1_gemm(
    const float* __restrict__ agg, const float* __restrict__ hf,
    const _Float16* __restrict__ Bp, const float* __restrict__ bias,
    _Float16* __restrict__ uhi, _Float16* __restrict__ ulo, int N) {
    int lane = threadIdx.x & 63;
    int wid = threadIdx.x >> 6;
    int row0 = blockIdx.x * 64 + wid * 16;
    if (row0 >= N) return;
    int r = row0 + (lane & 15);
    const int ak = (lane >> 4) * 8;
    h16x8 ah[5], al[5];
#pragma unroll
    for (int ks = 0; ks < 5; ++ks) {
        int c0 = ks * 32 + ak;
        f32x4 v0, v1;
        if (c0 < 16) {
            v0 = *(const f32x4*)(agg + (size_t)r * 16 + c0);
            v1 = *(const f32x4*)(agg + (size_t)r * 16 + c0 + 4);
        } else if (c0 < 144) {
            v0 = *(const f32x4*)(hf + (size_t)r * 128 + c0 - 16);
            v1 = *(const f32x4*)(hf + (size_t)r * 128 + c0 - 12);
        } else {
            v0 = f32x4{0.f, 0.f, 0.f, 0.f};
            v1 = f32x4{0.f, 0.f, 0.f, 0.f};
        }
        h16x8 hi8, lo8;
#pragma unroll
        for (int jj = 0; jj < 8; ++jj) {
            float x = (jj < 4) ? v0[jj] : v1[jj - 4];
            _Float16 h, l;
            splitf16(x, h, l);
            hi8[jj] = h;
            lo8[jj] = l;
        }
        ah[ks] = hi8;
        al[ks] = lo8;
    }
    int col16 = lane & 15;
    int rb = (lane >> 4) * 4;
    for (int cb = 0; cb < 16; ++cb) {
        f32x4 acc = {0.f, 0.f, 0.f, 0.f};
#pragma unroll
        for (int ks = 0; ks < 5; ++ks) {
            h16x8 bh = *(const h16x8*)(Bp + ((size_t)(ks * 16 + cb) * 64 + lane) * 8);
            acc = __builtin_amdgcn_mfma_f32_16x16x32_f16(ah[ks], bh, acc, 0, 0, 0);
            acc = __builtin_amdgcn_mfma_f32_16x16x32_f16(al[ks], bh, acc, 0, 0, 0);
        }
        int col = cb * 16 + col16;
        float bv = bias[col];
#pragma unroll
        for (int i = 0; i < 4; ++i) {
            int row = row0 + rb + i;
            float s = swish_fast(acc[i] + bv);
            _Float16 hi, lo;
            splitf16(s, hi, lo);
            uhi[(size_t)row * 256 + col] = hi;
            ulo[(size_t)row * 256 + col] = lo;
        }
    }
}

// ---------------- edge kernel: packed-fp16 message MLP, 32 edges/wave, 3-deep pipeline ----------------
__global__ __launch_bounds__(256) void edge_kernel(
    const _Float16* __restrict__ TAB, const _Float16* __restrict__ w1c,
    const _Float16* __restrict__ W2p, const float* __restrict__ bm2l,
    const int* __restrict__ srcS, const int* __restrict__ dstS,
    const float* __restrict__ n2S, float* __restrict__ agg) {
    __shared__ _Float16 sW[8704];
    __shared__ _Float16 sw1[544];
    for (int t = threadIdx.x; t < 1088; t += 256)
        ((h16x8*)sW)[t] = ((const h16x8*)W2p)[t];
    for (int t = threadIdx.x; t < 544; t += 256) sw1[t] = w1c[t];
    __syncthreads();

    int lane = threadIdx.x & 63;
    int wid = threadIdx.x >> 6;
    int ebase = blockIdx.x * 128 + wid * 32;
    int rr = lane & 15;
    int e0 = ebase + rr;
    int e1 = ebase + 16 + rr;
    int di0 = dstS[e0], si0 = srcS[e0];
    int di1 = dstS[e1], si1 = srcS[e1];
    _Float16 n20 = (_Float16)n2S[e0];
    _Float16 n21 = (_Float16)n2S[e1];
    const int ak = (lane >> 4) * 8;
    const _Float16* pa0 = TAB + (size_t)di0 * 1088 + ak;
    const _Float16* pb0 = TAB + (size_t)si0 * 1088 + 544 + ak;
    const _Float16* pa1 = TAB + (size_t)di1 * 1088 + ak;
    const _Float16* pb1 = TAB + (size_t)si1 * 1088 + 544 + ak;

    h16x8 qa0[3], qb0[3], qa1[3], qb1[3];
#pragma unroll
    for (int p = 0; p < 3; ++p) {
        qa0[p] = *(const h16x8*)(pa0 + p * 32);
        qb0[p] = *(const h16x8*)(pb0 + p * 32);
        qa1[p] = *(const h16x8*)(pa1 + p * 32);
        qb1[p] = *(const h16x8*)(pb1 + p * 32);
    }

    const _Float16 nl2e = (_Float16)(-1.44269504f);
    f32x4 acc0 = {0.f, 0.f, 0.f, 0.f};
    f32x4 acc1 = {0.f, 0.f, 0.f, 0.f};
#pragma unroll
    for (int ks = 0; ks < 17; ++ks) {
        const int slot = ks % 3;
        h16x8 va0 = qa0[slot], vb0 = qb0[slot];
        h16x8 va1 = qa1[slot], vb1 = qb1[slot];
        if (ks + 3 < 17) {
            qa0[slot] = *(const h16x8*)(pa0 + (ks + 3) * 32);
            qb0[slot] = *(const h16x8*)(pb0 + (ks + 3) * 32);
            qa1[slot] = *(const h16x8*)(pa1 + (ks + 3) * 32);
            qb1[slot] = *(const h16x8*)(pb1 + (ks + 3) * 32);
        }
        h16x8 wv = *(const h16x8*)(sw1 + ks * 32 + ak);
        // group 0: packed fp16 swish(va+vb+n2*w)
        h16x8 x0 = va0 + vb0 + wv * n20;
        h16x8 e0v = __builtin_elementwise_exp2(x0 * nl2e);
        h16x8 d0 = e0v + (_Float16)1.0f;
        h16x8 r0;
#pragma unroll
        for (int j = 0; j < 8; ++j) r0[j] = __builtin_amdgcn_rcph(d0[j]);
        h16x8 m0 = x0 * r0;
        // group 1
        h16x8 x1 = va1 + vb1 + wv * n21;
        h16x8 e1v = __builtin_elementwise_exp2(x1 * nl2e);
        h16x8 d1 = e1v + (_Float16)1.0f;
        h16x8 r1;
#pragma unroll
        for (int j = 0; j < 8; ++j) r1[j] = __builtin_amdgcn_rcph(d1[j]);
        h16x8 m1 = x1 * r1;

        h16x8 bh = *(const h16x8*)(sW + (ks * 64 + lane) * 8);
        acc0 = __builtin_amdgcn_mfma_f32_16x16x32_f16(m0, bh, acc0, 0, 0, 0);
        acc1 = __builtin_amdgcn_mfma_f32_16x16x32_f16(m1, bh, acc1, 0, 0, 0);
    }

    int col = lane & 15;
    float b2 = bm2l[col];
#pragma unroll
    for (int i = 0; i < 4; ++i) {
        int ea = ebase + (lane >> 4) * 4 + i;
        float v0 = swish_fast(acc0[i] + b2);
        unsafeAtomicAdd(&agg[(size_t)dstS[ea] * 16 + col], v0);
        int eb = ea + 16;
        float v1 = swish_fast(acc1[i] + b2);
        unsafeAtomicAdd(&agg[(size_t)dstS[eb] * 16 + col], v1);
    }
}

// ---------------- readout ----------------
__global__ void readout(const float* __restrict__ pooled, const float* __restrict__ Wr1,
                        const float* __restrict__ br1, const float* __restrict__ Wr2,
                        const float* __restrict__ br2, float* __restrict__ out) {
    __shared__ float row[128];
    __shared__ float tt[128];
    int g = blockIdx.x;
    int t = threadIdx.x;
    row[t] = pooled[g * 128 + t];
    __syncthreads();
    float s = br1[t];
    for (int k = 0; k < 128; ++k) s += row[k] * Wr1[k * 128 + t];
    tt[t] = swish_fast(s);
    __syncthreads();
    if (t < 12) {
        float o = br2[t];
        for (int j = 0; j < 128; ++j) o += tt[j] * Wr2[j * 12 + t];
        out[g * 12 + t] = o;
    }
}

extern "C" void kernel_launch(void* const* d_in, const int* in_sizes, int n_in,
                              void* d_out, int out_size, void* d_ws, size_t ws_size,
                              hipStream_t stream) {
    const float* pos = (const float*)d_in[0];
    const int* z = (const int*)d_in[1];
    const int* ei = (const int*)d_in[2];
    const int* batch = (const int*)d_in[3];
    const float* emb = (const float*)d_in[4];
    const float* Wm1 = (const float*)d_in[5];
    const float* bm1 = (const float*)d_in[6];
    const float* Wm2 = (const float*)d_in[7];
    const float* bm2 = (const float*)d_in[8];
    const float* Wu1 = (const float*)d_in[9];
    const float* bu1 = (const float*)d_in[10];
    const float* Wu2 = (const float*)d_in[11];
    const float* bu2 = (const float*)d_in[12];
    const float* Wp1 = (const float*)d_in[13];
    const float* bp1v = (const float*)d_in[14];
    const float* Wp2 = (const float*)d_in[15];
    const float* bp2v = (const float*)d_in[16];
    const float* Wr1 = (const float*)d_in[17];
    const float* br1 = (const float*)d_in[18];
    const float* Wr2 = (const float*)d_in[19];
    const float* br2 = (const float*)d_in[20];

    const int N = in_sizes[0] / 3;   // 50000
    const int E = in_sizes[2] / 2;   // 800000
    const int G = out_size / 12;     // 1000
    const int* src = ei;
    const int* dstp = ei + E;

    char* ws = (char*)d_ws;
    size_t off = 0;
    auto alloc = [&](size_t bytes) -> char* {
        char* p = ws + off;
        off += (bytes + 255) & ~(size_t)255;
        return p;
    };
    _Float16* TAB = (_Float16*)alloc((size_t)N * 1088 * 2);
    float* hf = (float*)alloc((size_t)N * 128 * 4);
    _Float16* hhi = (_Float16*)alloc((size_t)N * 128 * 2);
    _Float16* hlo = (_Float16*)alloc((size_t)N * 128 * 2);
    float* agg = (float*)alloc((size_t)N * 16 * 4);
    float* pooled = (float*)alloc((size_t)G * 128 * 4);
    int* hist = (int*)alloc((size_t)N * 4);
    int* cursor = (int*)alloc((size_t)N * 4);
    int* perm = (int*)alloc((size_t)E * 4);
    int* srcS = (int*)alloc((size_t)E * 4);
    int* dstS = (int*)alloc((size_t)E * 4);
    float* n2S = (float*)alloc((size_t)E * 4);
    _Float16* Bp1 = (_Float16*)alloc(139264 * 2);
    float* bias1088 = (float*)alloc(1088 * 4);
    _Float16* w1c = (_Float16*)alloc(544 * 2);
    _Float16* W2p = (_Float16*)alloc(8704 * 2);
    _Float16* BpU1 = (_Float16*)alloc(40960 * 2);
    _Float16* BpU2 = (_Float16*)alloc(32768 * 2);
    _Float16* BpP1 = (_Float16*)alloc(16384 * 2);
    _Float16* BpP2 = (_Float16*)alloc(16384 * 2);

    // Aliases inside the TAB region (dead between edge_kernel and next table GEMM):
    _Float16* uhi = TAB + (size_t)N * 320;
    _Float16* ulo = TAB + (size_t)N * 576;
    _Float16* t1hi = TAB;
    _Float16* t1lo = TAB + (size_t)N * 128;

    init_nodes<<<(N * 128) / 256, 256, 0, stream>>>(z, emb, hf, hhi, hlo, N);

    // one-time: counting sort of edges by dst
    hipMemsetAsync(hist, 0, (size_t)N * 4, stream);
    hist_kernel<<<(E + 255) / 256, 256, 0, stream>>>(dstp, hist, E);
    scan_kernel<<<1, 256, 0, stream>>>(hist, cursor, N);
    scatter_kernel<<<(E + 255) / 256, 256, 0, stream>>>(dstp, cursor, perm, E);
    reorder_kernel<<<(E + 255) / 256, 256, 0, stream>>>(perm, src, dstp, pos, srcS, dstS, n2S, E);

    const int gA = (N + 63) / 64;
    for (int l = 0; l < 7; ++l) {
        pack_msg1<<<139264 / 256, 256, 0, stream>>>(
            Wm1 + (size_t)l * 257 * 514, bm1 + (size_t)l * 514, Wm2 + (size_t)l * 514 * 16,
            Bp1, bias1088, w1c, W2p);
        tab_gemm<<<gA, 256, 0, stream>>>(hhi, hlo, Bp1, bias1088, TAB, N);
        hipMemsetAsync(agg, 0, (size_t)N * 16 * 4, stream);
        edge_kernel<<<E / 128, 256, 0, stream>>>(TAB, w1c, W2p, bm2 + l * 16,
                                                 srcS, dstS, n2S, agg);
        pack_generic<<<(160 * 256) / 256, 256, 0, stream>>>(
            Wu1 + (size_t)l * 144 * 256, 144, 256, BpU1);
        up1_gemm<<<gA, 256, 0, stream>>>(agg, hf, BpU1, bu1 + l * 256, uhi, ulo, N);
        pack_generic<<<(256 * 128) / 256, 256, 0, stream>>>(
            Wu2 + (size_t)l * 256 * 128, 256, 128, BpU2);
        gemmA<8, 8, 2><<<gA, 256, 0, stream>>>(
            uhi, ulo, 256, BpU2, bu2 + l * 128,
            hhi, hlo, 128, hf, 128, hf, nullptr, nullptr, N);
    }

    pack_generic<<<(128 * 128) / 256, 256, 0, stream>>>(Wp1, 128, 128, BpP1);
    gemmA<4, 8, 1><<<gA, 256, 0, stream>>>(
        hhi, hlo, 128, BpP1, bp1v,
        t1hi, t1lo, 128, nullptr, 0, nullptr, nullptr, nullptr, N);
    pack_generic<<<(128 * 128) / 256, 256, 0, stream>>>(Wp2, 128, 128, BpP2);
    hipMemsetAsync(pooled, 0, (size_t)G * 128 * 4, stream);
    gemmA<4, 8, 3><<<gA, 256, 0, stream>>>(
        t1hi, t1lo, 128, BpP2, bp2v,
        nullptr, nullptr, 0, nullptr, 0, nullptr, batch, pooled, N);
    readout<<<G, 128, 0, stream>>>(pooled, Wr1, br1, Wr2, br2, (float*)d_out);
}

// Round 11
// 2953.951 us; speedup vs baseline: 2.6193x; 1.0229x over previous
//
#include <hip/hip_runtime.h>
#include <hip/hip_bf16.h>
#include <cstdint>
#include <cstddef>

typedef _Float16 h16x8 __attribute__((ext_vector_type(8)));
typedef float f32x4 __attribute__((ext_vector_type(4)));

__device__ __forceinline__ void splitf16(float v, _Float16& hi, _Float16& lo) {
    hi = (_Float16)v;
    lo = (_Float16)(v - (float)hi);
}
// fast swish: x * rcp(1+exp(-x)); v_rcp_f32 rel-err ~1e-7
__device__ __forceinline__ float swish_fast(float x) {
    float e = __expf(-x);
    return x * __builtin_amdgcn_rcpf(1.0f + e);
}

// ---------------- init: h = emb[atomic[z]] ----------------
__global__ void init_nodes(const int* __restrict__ z, const float* __restrict__ emb,
                           float* __restrict__ hf, _Float16* __restrict__ hhi,
                           _Float16* __restrict__ hlo, int N) {
    int tid = blockIdx.x * 256 + threadIdx.x;
    int n = tid >> 7, f = tid & 127;
    int zv = z[n];
    int idx5 = (zv == 1) ? 0 : (zv - 5);
    float v = emb[idx5 * 128 + f];
    hf[tid] = v;
    _Float16 hi, lo;
    splitf16(v, hi, lo);
    hhi[tid] = hi;
    hlo[tid] = lo;
}

// ---------------- edge preprocessing: counting sort by dst ----------------
__global__ void hist_kernel(const int* __restrict__ dst, int* __restrict__ hist, int E) {
    int e = blockIdx.x * 256 + threadIdx.x;
    if (e < E) atomicAdd(&hist[dst[e]], 1);
}

__global__ void scan_kernel(const int* __restrict__ hist, int* __restrict__ cursor, int N) {
    __shared__ int part[256];
    int t = threadIdx.x;
    int chunk = (N + 255) / 256;
    int base = t * chunk;
    int s = 0;
    for (int i = 0; i < chunk; ++i) {
        int idx = base + i;
        if (idx < N) s += hist[idx];
    }
    part[t] = s;
    __syncthreads();
    for (int d = 1; d < 256; d <<= 1) {
        int v = 0;
        if (t >= d) v = part[t - d];
        __syncthreads();
        part[t] += v;
        __syncthreads();
    }
    int run = part[t] - s;
    for (int i = 0; i < chunk; ++i) {
        int idx = base + i;
        if (idx < N) {
            cursor[idx] = run;
            run += hist[idx];
        }
    }
}

__global__ void scatter_kernel(const int* __restrict__ dst, int* __restrict__ cursor,
                               int* __restrict__ perm, int E) {
    int e = blockIdx.x * 256 + threadIdx.x;
    if (e < E) {
        int p = atomicAdd(&cursor[dst[e]], 1);
        perm[p] = e;
    }
}

__global__ void reorder_kernel(const int* __restrict__ perm, const int* __restrict__ src,
                               const int* __restrict__ dst, const float* __restrict__ pos,
                               int* __restrict__ srcS, int* __restrict__ dstS,
                               float* __restrict__ n2S, int E) {
    int i = blockIdx.x * 256 + threadIdx.x;
    if (i >= E) return;
    int e = perm[i];
    int si = src[e], di = dst[e];
    srcS[i] = si;
    dstS[i] = di;
    float dx = pos[si * 3 + 0] - pos[di * 3 + 0];
    float dy = pos[si * 3 + 1] - pos[di * 3 + 1];
    float dz = pos[si * 3 + 2] - pos[di * 3 + 2];
    n2S[i] = dx * dx + dy * dy + dz * dz;
}

// ---------------- pack W_msg1 + W_msg2 for layer l ----------------
__global__ void pack_msg1(const float* __restrict__ Wm1l, const float* __restrict__ bm1l,
                          const float* __restrict__ Wm2l,
                          _Float16* __restrict__ Bp1, float* __restrict__ bias1088,
                          _Float16* __restrict__ w1c, _Float16* __restrict__ W2p) {
    int t = blockIdx.x * 256 + threadIdx.x;
    int i = t & 7;
    int lane = (t >> 3) & 63;
    int rest = t >> 9;
    int cb = rest % 68;
    int ks = rest / 68;
    int k = ks * 32 + ((lane >> 4) << 3) + i;
    int ch = cb * 16 + (lane & 15);
    float val;
    if (ch < 544) {
        val = (ch < 514) ? Wm1l[k * 514 + ch] : 0.f;
    } else {
        int c = ch - 544;
        val = (c < 514) ? Wm1l[(128 + k) * 514 + c] : 0.f;
    }
    Bp1[t] = (_Float16)val;
    if (t < 1088) bias1088[t] = (t < 514) ? bm1l[t] : 0.f;
    if (t < 544) w1c[t] = (_Float16)((t < 514) ? Wm1l[256 * 514 + t] : 0.f);
    if (t < 8704) {
        int i2 = t & 7, lane2 = (t >> 3) & 63, ks2 = t >> 9;
        int k2 = ks2 * 32 + ((lane2 >> 4) << 3) + i2;
        int c2 = lane2 & 15;
        W2p[t] = (_Float16)((k2 < 514) ? Wm2l[k2 * 16 + c2] : 0.f);
    }
}

// ---------------- generic B packer: W[K][Nc] fp32 -> single f16 frag layout ----------------
__global__ void pack_generic(const float* __restrict__ W, int K, int Nc,
                             _Float16* __restrict__ Bp) {
    int t = blockIdx.x * 256 + threadIdx.x;
    int i = t & 7;
    int lane = (t >> 3) & 63;
    int rest = t >> 9;
    int CB = Nc >> 4;
    int cb = rest % CB;
    int ks = rest / CB;
    int k = ks * 32 + ((lane >> 4) << 3) + i;
    int c = cb * 16 + (lane & 15);
    float val = (k < K) ? W[(size_t)k * Nc + c] : 0.f;
    Bp[t] = (_Float16)val;
}

// ---------------- table GEMM: A(K=128) hi/lo in regs, B single f16, 2 MFMA/ks ----------------
__global__ __launch_bounds__(256) void tab_gemm(
    const _Float16* __restrict__ Ahi, const _Float16* __restrict__ Alo,
    const _Float16* __restrict__ Bp, const float* __restrict__ bias,
    _Float16* __restrict__ TAB, int N) {
    int lane = threadIdx.x & 63;
    int wid = threadIdx.x >> 6;
    int row0 = blockIdx.x * 64 + wid * 16;
    if (row0 >= N) return;
    const size_t arow = (size_t)(row0 + (lane & 15)) * 128;
    const int ak = (lane >> 4) * 8;
    h16x8 ah[4], al[4];
#pragma unroll
    for (int ks = 0; ks < 4; ++ks) {
        ah[ks] = *(const h16x8*)(Ahi + arow + ks * 32 + ak);
        al[ks] = *(const h16x8*)(Alo + arow + ks * 32 + ak);
    }
    int col16 = lane & 15;
    int rb = (lane >> 4) * 4;
    for (int cb = 0; cb < 68; ++cb) {
        f32x4 acc = {0.f, 0.f, 0.f, 0.f};
#pragma unroll
        for (int ks = 0; ks < 4; ++ks) {
            h16x8 bh = *(const h16x8*)(Bp + ((size_t)(ks * 68 + cb) * 64 + lane) * 8);
            acc = __builtin_amdgcn_mfma_f32_16x16x32_f16(ah[ks], bh, acc, 0, 0, 0);
            acc = __builtin_amdgcn_mfma_f32_16x16x32_f16(al[ks], bh, acc, 0, 0, 0);
        }
        float bv = bias[cb * 16 + col16];
#pragma unroll
        for (int i = 0; i < 4; ++i) {
            TAB[(size_t)(row0 + rb + i) * 1088 + cb * 16 + col16] = (_Float16)(acc[i] + bv);
        }
    }
}

// ---------------- generic 64-row A-in-regs GEMM (A hi/lo f16, B single f16) ----------------
template <int KS, int CB, int MODE>
__global__ __launch_bounds__(256) void gemmA(
    const _Float16* __restrict__ Ahi, const _Float16* __restrict__ Alo, int lda,
    const _Float16* __restrict__ Bp, const float* __restrict__ bias,
    _Float16* __restrict__ outB, _Float16* __restrict__ outB2, int ldoB,
    float* __restrict__ outF, int ldoF, const float* __restrict__ resid,
    const int* __restrict__ batch, float* __restrict__ pooled, int N) {
    int lane = threadIdx.x & 63;
    int wid = threadIdx.x >> 6;
    int row0 = blockIdx.x * 64 + wid * 16;
    if (row0 >= N) return;
    const size_t arow = (size_t)(row0 + (lane & 15)) * lda;
    const int ak = (lane >> 4) * 8;
    h16x8 ah[KS], al[KS];
#pragma unroll
    for (int ks = 0; ks < KS; ++ks) {
        ah[ks] = *(const h16x8*)(Ahi + arow + ks * 32 + ak);
        al[ks] = *(const h16x8*)(Alo + arow + ks * 32 + ak);
    }
    int col16 = lane & 15;
    int rb = (lane >> 4) * 4;
    for (int cb = 0; cb < CB; ++cb) {
        f32x4 acc = {0.f, 0.f, 0.f, 0.f};
#pragma unroll
        for (int ks = 0; ks < KS; ++ks) {
            h16x8 bh = *(const h16x8*)(Bp + ((size_t)(ks * CB + cb) * 64 + lane) * 8);
            acc = __builtin_amdgcn_mfma_f32_16x16x32_f16(ah[ks], bh, acc, 0, 0, 0);
            acc = __builtin_amdgcn_mfma_f32_16x16x32_f16(al[ks], bh, acc, 0, 0, 0);
        }
        int col = cb * 16 + col16;
        float bv = bias[col];
#pragma unroll
        for (int i = 0; i < 4; ++i) {
            int row = row0 + rb + i;
            float v = acc[i] + bv;
            if (MODE == 1) {
                float s = swish_fast(v);
                _Float16 hi, lo;
                splitf16(s, hi, lo);
                outB[(size_t)row * ldoB + col] = hi;
                outB2[(size_t)row * ldoB + col] = lo;
            } else if (MODE == 2) {
                float h = v + resid[(size_t)row * ldoF + col];
                outF[(size_t)row * ldoF + col] = h;
                _Float16 hi, lo;
                splitf16(h, hi, lo);
                outB[(size_t)row * ldoB + col] = hi;
                outB2[(size_t)row * ldoB + col] = lo;
            } else {
                unsafeAtomicAdd(&pooled[(size_t)batch[row] * 128 + col], v);
            }
        }
    }
}

// ---------------- up1 GEMM: A assembled on the fly from agg(f32)+hf(f32) ----------------
__global__ __launch_bounds__(256) void up1_gemm(
    const float* __restrict__ agg, const float* __restrict__ hf,
    const _Float16* __restrict__ Bp, const float* __restrict__ bias,
    _Float16* __restrict__ uhi, _Float16* __restrict__ ulo, int N) {
    int lane = threadIdx.x & 63;
    int wid = threadIdx.x >> 6;
    int row0 = blockIdx.x * 64 + wid * 16;
    if (row0 >= N) return;
    int r = row0 + (lane & 15);
    const int ak = (lane >> 4) * 8;
    h16x8 ah[5], al[5];
#pragma unroll
    for (int ks = 0; ks < 5; ++ks) {
        int c0 = ks * 32 + ak;
        f32x4 v0, v1;
        if (c0 < 16) {
            v0 = *(const f32x4*)(agg + (size_t)r * 16 + c0);
            v1 = *(const f32x4*)(agg + (size_t)r * 16 + c0 + 4);
        } else if (c0 < 144) {
            v0 = *(const f32x4*)(hf + (size_t)r * 128 + c0 - 16);
            v1 = *(const f32x4*)(hf + (size_t)r * 128 + c0 - 12);
        } else {
            v0 = f32x4{0.f, 0.f, 0.f, 0.f};
            v1 = f32x4{0.f, 0.f, 0.f, 0.f};
        }
        h16x8 hi8, lo8;
#pragma unroll
        for (int jj = 0; jj < 8; ++jj) {
            float x = (jj < 4) ? v0[jj] : v1[jj - 4];
            _Float16 h, l;
            splitf16(x, h, l);
            hi8[jj] = h;
            lo8[jj] = l;
        }
        ah[ks] = hi8;
        al[ks] = lo8;
    }
    int col16 = lane & 15;
    int rb = (lane >> 4) * 4;
    for (int cb = 0; cb < 16; ++cb) {
        f32x4 acc = {0.f, 0.f, 0.f, 0.f};
#pragma unroll
        for (int ks = 0; ks < 5; ++ks) {
            h16x8 bh = *(const h16x8*)(Bp + ((size_t)(ks * 16 + cb) * 64 + lane) * 8);
            acc = __builtin_amdgcn_mfma_f32_16x16x32_f16(ah[ks], bh, acc, 0, 0, 0);
            acc = __builtin_amdgcn_mfma_f32_16x16x32_f16(al[ks], bh, acc, 0, 0, 0);
        }
        int col = cb * 16 + col16;
        float bv = bias[col];
#pragma unroll
        for (int i = 0; i < 4; ++i) {
            int row = row0 + rb + i;
            float s = swish_fast(acc[i] + bv);
            _Float16 hi, lo;
            splitf16(s, hi, lo);
            uhi[(size_t)row * 256 + col] = hi;
            ulo[(size_t)row * 256 + col] = lo;
        }
    }
}

// ---------------- edge kernel: chunk-4 double-buffered gathers, forced-live pipeline ----------------
__global__ __launch_bounds__(256) void edge_kernel(
    const _Float16* __restrict__ TAB, const _Float16* __restrict__ w1c,
    const _Float16* __restrict__ W2p, const float* __restrict__ bm2l,
    const int* __restrict__ srcS, const int* __restrict__ dstS,
    const float* __restrict__ n2S, float* __restrict__ agg) {
    __shared__ _Float16 sW[8704];
    __shared__ _Float16 sw1[544];
    for (int t = threadIdx.x; t < 1088; t += 256)
        ((h16x8*)sW)[t] = ((const h16x8*)W2p)[t];
    for (int t = threadIdx.x; t < 544; t += 256) sw1[t] = w1c[t];
    __syncthreads();

    int lane = threadIdx.x & 63;
    int wid = threadIdx.x >> 6;
    int ebase = blockIdx.x * 128 + wid * 32;
    int rr = lane & 15;
    int e0 = ebase + rr;
    int e1 = ebase + 16 + rr;
    int di0 = dstS[e0], si0 = srcS[e0];
    int di1 = dstS[e1], si1 = srcS[e1];
    _Float16 n20 = (_Float16)n2S[e0];
    _Float16 n21 = (_Float16)n2S[e1];
    const int ak = (lane >> 4) * 8;
    const _Float16* pa0 = TAB + (size_t)di0 * 1088 + ak;
    const _Float16* pb0 = TAB + (size_t)si0 * 1088 + 544 + ak;
    const _Float16* pa1 = TAB + (size_t)di1 * 1088 + ak;
    const _Float16* pb1 = TAB + (size_t)si1 * 1088 + 544 + ak;

    const _Float16 nl2e = (_Float16)(-1.44269504f);
    f32x4 acc0 = {0.f, 0.f, 0.f, 0.f};
    f32x4 acc1 = {0.f, 0.f, 0.f, 0.f};

    h16x8 bufA[16], bufB[16], bufT[4];

    auto issue4 = [&](h16x8* buf, int K) {
#pragma unroll
        for (int q = 0; q < 4; ++q) {
            buf[q * 4 + 0] = *(const h16x8*)(pa0 + (K + q) * 32);
            buf[q * 4 + 1] = *(const h16x8*)(pb0 + (K + q) * 32);
            buf[q * 4 + 2] = *(const h16x8*)(pa1 + (K + q) * 32);
            buf[q * 4 + 3] = *(const h16x8*)(pb1 + (K + q) * 32);
        }
    };
    auto step = [&](const h16x8* buf, int q, int ks) {
        h16x8 va0 = buf[q * 4 + 0], vb0 = buf[q * 4 + 1];
        h16x8 va1 = buf[q * 4 + 2], vb1 = buf[q * 4 + 3];
        h16x8 wv = *(const h16x8*)(sw1 + ks * 32 + ak);
        h16x8 x0 = va0 + vb0 + wv * n20;
        h16x8 ev0 = __builtin_elementwise_exp2(x0 * nl2e);
        h16x8 d0 = ev0 + (_Float16)1.0f;
        h16x8 r0;
#pragma unroll
        for (int j = 0; j < 8; ++j) r0[j] = __builtin_amdgcn_rcph(d0[j]);
        h16x8 m0 = x0 * r0;
        h16x8 x1 = va1 + vb1 + wv * n21;
        h16x8 ev1 = __builtin_elementwise_exp2(x1 * nl2e);
        h16x8 d1 = ev1 + (_Float16)1.0f;
        h16x8 r1;
#pragma unroll
        for (int j = 0; j < 8; ++j) r1[j] = __builtin_amdgcn_rcph(d1[j]);
        h16x8 m1 = x1 * r1;
        h16x8 bh = *(const h16x8*)(sW + (ks * 64 + lane) * 8);
        acc0 = __builtin_amdgcn_mfma_f32_16x16x32_f16(m0, bh, acc0, 0, 0, 0);
        acc1 = __builtin_amdgcn_mfma_f32_16x16x32_f16(m1, bh, acc1, 0, 0, 0);
    };

    issue4(bufA, 0);
    __builtin_amdgcn_sched_barrier(0);
    issue4(bufB, 4);
    __builtin_amdgcn_sched_barrier(0);
#pragma unroll
    for (int q = 0; q < 4; ++q) step(bufA, q, q);
    issue4(bufA, 8);
    __builtin_amdgcn_sched_barrier(0);
#pragma unroll
    for (int q = 0; q < 4; ++q) step(bufB, q, 4 + q);
    issue4(bufB, 12);
    __builtin_amdgcn_sched_barrier(0);
#pragma unroll
    for (int q = 0; q < 4; ++q) step(bufA, q, 8 + q);
    bufT[0] = *(const h16x8*)(pa0 + 16 * 32);
    bufT[1] = *(const h16x8*)(pb0 + 16 * 32);
    bufT[2] = *(const h16x8*)(pa1 + 16 * 32);
    bufT[3] = *(const h16x8*)(pb1 + 16 * 32);
    __builtin_amdgcn_sched_barrier(0);
#pragma unroll
    for (int q = 0; q < 4; ++q) step(bufB, q, 12 + q);
    step(bufT, 0, 16);

    int col = lane & 15;
    float b2 = bm2l[col];
#pragma unroll
    for (int i = 0; i < 4; ++i) {
        int ea = ebase + (lane >> 4) * 4 + i;
        float v0 = swish_fast(acc0[i] + b2);
        unsafeAtomicAdd(&agg[(size_t)dstS[ea] * 16 + col], v0);
        int eb = ea + 16;
        float v1 = swish_fast(acc1[i] + b2);
        unsafeAtomicAdd(&agg[(size_t)dstS[eb] * 16 + col], v1);
    }
}

// ---------------- readout ----------------
__global__ void readout(const float* __restrict__ pooled, const float* __restrict__ Wr1,
                        const float* __restrict__ br1, const float* __restrict__ Wr2,
                        const float* __restrict__ br2, float* __restrict__ out) {
    __shared__ float row[128];
    __shared__ float tt[128];
    int g = blockIdx.x;
    int t = threadIdx.x;
    row[t] = pooled[g * 128 + t];
    __syncthreads();
    float s = br1[t];
    for (int k = 0; k < 128; ++k) s += row[k] * Wr1[k * 128 + t];
    tt[t] = swish_fast(s);
    __syncthreads();
    if (t < 12) {
        float o = br2[t];
        for (int j = 0; j < 128; ++j) o += tt[j] * Wr2[j * 12 + t];
        out[g * 12 + t] = o;
    }
}

extern "C" void kernel_launch(void* const* d_in, const int* in_sizes, int n_in,
                              void* d_out, int out_size, void* d_ws, size_t ws_size,
                              hipStream_t stream) {
    const float* pos = (const float*)d_in[0];
    const int* z = (const int*)d_in[1];
    const int* ei = (const int*)d_in[2];
    const int* batch = (const int*)d_in[3];
    const float* emb = (const float*)d_in[4];
    const float* Wm1 = (const float*)d_in[5];
    const float* bm1 = (const float*)d_in[6];
    const float* Wm2 = (const float*)d_in[7];
    const float* bm2 = (const float*)d_in[8];
    const float* Wu1 = (const float*)d_in[9];
    const float* bu1 = (const float*)d_in[10];
    const float* Wu2 = (const float*)d_in[11];
    const float* bu2 = (const float*)d_in[12];
    const float* Wp1 = (const float*)d_in[13];
    const float* bp1v = (const float*)d_in[14];
    const float* Wp2 = (const float*)d_in[15];
    const float* bp2v = (const float*)d_in[16];
    const float* Wr1 = (const float*)d_in[17];
    const float* br1 = (const float*)d_in[18];
    const float* Wr2 = (const float*)d_in[19];
    const float* br2 = (const float*)d_in[20];

    const int N = in_sizes[0] / 3;   // 50000
    const int E = in_sizes[2] / 2;   // 800000
    const int G = out_size / 12;     // 1000
    const int* src = ei;
    const int* dstp = ei + E;

    char* ws = (char*)d_ws;
    size_t off = 0;
    auto alloc = [&](size_t bytes) -> char* {
        char* p = ws + off;
        off += (bytes + 255) & ~(size_t)255;
        return p;
    };
    _Float16* TAB = (_Float16*)alloc((size_t)N * 1088 * 2);
    float* hf = (float*)alloc((size_t)N * 128 * 4);
    _Float16* hhi = (_Float16*)alloc((size_t)N * 128 * 2);
    _Float16* hlo = (_Float16*)alloc((size_t)N * 128 * 2);
    float* agg = (float*)alloc((size_t)N * 16 * 4);
    float* pooled = (float*)alloc((size_t)G * 128 * 4);
    int* hist = (int*)alloc((size_t)N * 4);
    int* cursor = (int*)alloc((size_t)N * 4);
    int* perm = (int*)alloc((size_t)E * 4);
    int* srcS = (int*)alloc((size_t)E * 4);
    int* dstS = (int*)alloc((size_t)E * 4);
    float* n2S = (float*)alloc((size_t)E * 4);
    _Float16* Bp1 = (_Float16*)alloc(139264 * 2);
    float* bias1088 = (float*)alloc(1088 * 4);
    _Float16* w1c = (_Float16*)alloc(544 * 2);
    _Float16* W2p = (_Float16*)alloc(8704 * 2);
    _Float16* BpU1 = (_Float16*)alloc(40960 * 2);
    _Float16* BpU2 = (_Float16*)alloc(32768 * 2);
    _Float16* BpP1 = (_Float16*)alloc(16384 * 2);
    _Float16* BpP2 = (_Float16*)alloc(16384 * 2);

    // Aliases inside the TAB region (dead between edge_kernel and next table GEMM):
    _Float16* uhi = TAB + (size_t)N * 320;
    _Float16* ulo = TAB + (size_t)N * 576;
    _Float16* t1hi = TAB;
    _Float16* t1lo = TAB + (size_t)N * 128;

    init_nodes<<<(N * 128) / 256, 256, 0, stream>>>(z, emb, hf, hhi, hlo, N);

    // one-time: counting sort of edges by dst
    hipMemsetAsync(hist, 0, (size_t)N * 4, stream);
    hist_kernel<<<(E + 255) / 256, 256, 0, stream>>>(dstp, hist, E);
    scan_kernel<<<1, 256, 0, stream>>>(hist, cursor, N);
    scatter_kernel<<<(E + 255) / 256, 256, 0, stream>>>(dstp, cursor, perm, E);
    reorder_kernel<<<(E + 255) / 256, 256, 0, stream>>>(perm, src, dstp, pos, srcS, dstS, n2S, E);

    const int gA = (N + 63) / 64;
    for (int l = 0; l < 7; ++l) {
        pack_msg1<<<139264 / 256, 256, 0, stream>>>(
            Wm1 + (size_t)l * 257 * 514, bm1 + (size_t)l * 514, Wm2 + (size_t)l * 514 * 16,
            Bp1, bias1088, w1c, W2p);
        tab_gemm<<<gA, 256, 0, stream>>>(hhi, hlo, Bp1, bias1088, TAB, N);
        hipMemsetAsync(agg, 0, (size_t)N * 16 * 4, stream);
        edge_kernel<<<E / 128, 256, 0, stream>>>(TAB, w1c, W2p, bm2 + l * 16,
                                                 srcS, dstS, n2S, agg);
        pack_generic<<<(160 * 256) / 256, 256, 0, stream>>>(
            Wu1 + (size_t)l * 144 * 256, 144, 256, BpU1);
        up1_gemm<<<gA, 256, 0, stream>>>(agg, hf, BpU1, bu1 + l * 256, uhi, ulo, N);
        pack_generic<<<(256 * 128) / 256, 256, 0, stream>>>(
            Wu2 + (size_t)l * 256 * 128, 256, 128, BpU2);
        gemmA<8, 8, 2><<<gA, 256, 0, stream>>>(
            uhi, ulo, 256, BpU2, bu2 + l * 128,
            hhi, hlo, 128, hf, 128, hf, nullptr, nullptr, N);
    }

    pack_generic<<<(128 * 128) / 256, 256, 0, stream>>>(Wp1, 128, 128, BpP1);
    gemmA<4, 8, 1><<<gA, 256, 0, stream>>>(
        hhi, hlo, 128, BpP1, bp1v,
        t1hi, t1lo, 128, nullptr, 0, nullptr, nullptr, nullptr, N);
    pack_generic<<<(128 * 128) / 256, 256, 0, stream>>>(Wp2, 128, 128, BpP2);
    hipMemsetAsync(pooled, 0, (size_t)G * 128 * 4, stream);
    gemmA<4, 8, 3><<<gA, 256, 0, stream>>>(
        t1hi, t1lo, 128, BpP2, bp2v,
        nullptr, nullptr, 0, nullptr, 0, nullptr, batch, pooled, N);
    readout<<<G, 128, 0, stream>>>(pooled, Wr1, br1, Wr2, br2, (float*)d_out);
}